// Round 1
// baseline (1193.318 us; speedup 1.0000x reference)
//
#include <hip/hip_runtime.h>
#include <math.h>

#define BB 4
#define TT 512
#define MM 77
#define HH 10
#define DD 64
#define LATD 640
#define EE 8
#define FFND 256
#define NS 685     // 512 + 48 + 48 + 77
#define NCH 11     // ceil(685/64)
#define TOKB 32

__device__ __forceinline__ float geluf(float x){
    const float c0 = 0.7978845608028654f;
    return 0.5f*x*(1.0f + tanhf(c0*(x + 0.044715f*x*x*x)));
}
__device__ __forceinline__ float siluf(float x){
    return x / (1.0f + expf(-x));
}
__device__ __forceinline__ float dot4f(float4 a, float4 b){
    return a.x*b.x + a.y*b.y + a.z*b.z + a.w*b.w;
}

// ---------------- LayerNorm (rows of 640), optional additive emb (T,640) ----------------
__global__ __launch_bounds__(256) void ln_kernel(
    const float* __restrict__ in, const float* __restrict__ g, const float* __restrict__ bb,
    const float* __restrict__ addv, float* __restrict__ out, int seqLen)
{
    int row = blockIdx.x, tid = threadIdx.x;
    __shared__ float xsr[LATD];
    __shared__ float red[256];
    const float* rp = in + (size_t)row*LATD;
    float s = 0.f;
    for (int i=tid;i<LATD;i+=256){ float v = rp[i]; xsr[i]=v; s+=v; }
    red[tid]=s; __syncthreads();
    for (int k=128;k>0;k>>=1){ if (tid<k) red[tid]+=red[tid+k]; __syncthreads(); }
    float mean = red[0]*(1.0f/LATD);
    __syncthreads();
    float vs=0.f;
    for (int i=tid;i<LATD;i+=256){ float d=xsr[i]-mean; vs+=d*d; }
    red[tid]=vs; __syncthreads();
    for (int k=128;k>0;k>>=1){ if (tid<k) red[tid]+=red[tid+k]; __syncthreads(); }
    float rstd = rsqrtf(red[0]*(1.0f/LATD)+1e-5f);
    int t = row % seqLen;
    const float* ap = addv ? (addv + (size_t)t*LATD) : nullptr;
    float* op = out + (size_t)row*LATD;
    for (int i=tid;i<LATD;i+=256){
        float v = (xsr[i]-mean)*rstd*g[i] + bb[i];
        if (ap) v += ap[i];
        op[i] = v;
    }
}

// ---------------- MoE (top-2 of 8) + gelu + projection ----------------
// xin: (nTok, 64). Writes proj output columns: j in [0,64)->out0, [64,128)->out1, [128,192)->out2
// out layout: (B, H, seqLen, 64)
template<int NPROJ>
__global__ __launch_bounds__(256) void moe_kernel(
    const float* __restrict__ xin,
    const float* __restrict__ wg,    // (64,8)
    const float* __restrict__ w1g,   // (8,64,256)
    const float* __restrict__ b1g,   // (8,256)
    const float* __restrict__ w2g,   // (8,256,64)
    const float* __restrict__ b2g,   // (8,64)
    const float* __restrict__ pwg,   // (64, pwld)
    const float* __restrict__ pbg,
    int pwld, int nTok, int seqLen,
    float* __restrict__ out0, float* __restrict__ out1, float* __restrict__ out2)
{
    __shared__ __align__(16) float wbuf[FFND*68];   // w1 transposed [f][d] / w2 [f][d] / proj [j][d]
    __shared__ __align__(16) float xs[TOKB*DD];
    __shared__ __align__(16) float ys[TOKB*DD];
    __shared__ float hsA[TOKB*FFND];
    __shared__ int   lcnt[EE];
    __shared__ int   llist[EE][TOKB];
    __shared__ float lwt[EE][TOKB];
    __shared__ int   te0[TOKB], te1[TOKB];
    __shared__ float tw0s[TOKB], tw1s[TOKB];

    const int tid = threadIdx.x;
    const int base = blockIdx.x * TOKB;
    const int nb = min(TOKB, nTok - base);

    for (int i = tid; i < nb*DD; i += 256) xs[i] = xin[(size_t)base*DD + i];
    for (int i = tid; i < TOKB*DD; i += 256) ys[i] = 0.f;
    if (tid < EE) lcnt[tid] = 0;
    __syncthreads();

    // routing (one thread per token)
    if (tid < nb){
        float lg[EE];
        #pragma unroll
        for (int e=0;e<EE;e++) lg[e]=0.f;
        for (int d=0; d<DD; ++d){
            float xv = xs[tid*DD+d];
            #pragma unroll
            for (int e=0;e<EE;e++) lg[e] += xv * wg[d*EE+e];
        }
        float mx = lg[0];
        #pragma unroll
        for (int e=1;e<EE;e++) mx = fmaxf(mx, lg[e]);
        float sum = 0.f;
        #pragma unroll
        for (int e=0;e<EE;e++){ lg[e] = expf(lg[e]-mx); sum += lg[e]; }
        float inv = 1.0f/sum;
        #pragma unroll
        for (int e=0;e<EE;e++) lg[e] *= inv;
        int e0=0; float v0=lg[0];
        #pragma unroll
        for (int e=1;e<EE;e++){ if (lg[e] > v0){ v0 = lg[e]; e0 = e; } }
        int e1=0; float v1=-1e30f;
        #pragma unroll
        for (int e=0;e<EE;e++){ if (e==e0) continue; if (lg[e] > v1){ v1 = lg[e]; e1 = e; } }
        te0[tid]=e0; te1[tid]=e1; tw0s[tid]=v0; tw1s[tid]=v1;
    }
    __syncthreads();
    if (tid < EE){
        int c = 0;
        for (int t2=0; t2<nb; ++t2){
            if (te0[t2]==tid){ llist[tid][c]=t2; lwt[tid][c]=tw0s[t2]; ++c; }
            else if (te1[t2]==tid){ llist[tid][c]=t2; lwt[tid][c]=tw1s[t2]; ++c; }
        }
        lcnt[tid]=c;
    }
    __syncthreads();

    for (int e=0; e<EE; ++e){
        const int c = lcnt[e];
        if (c == 0) continue;
        // stage w1[e] transposed: wbuf[f*68+d] = w1[e][d][f]
        for (int i = tid; i < DD*FFND; i += 256){
            int d = i >> 8, f = i & 255;
            wbuf[f*68 + d] = w1g[((size_t)e*DD + d)*FFND + f];
        }
        __syncthreads();
        const float bb1 = b1g[e*FFND + tid];   // thread f = tid
        for (int ii=0; ii<c; ii+=4){
            int tk[4];
            #pragma unroll
            for (int u=0;u<4;++u) tk[u] = llist[e][min(ii+u, c-1)];
            float a0=bb1, a1=bb1, a2=bb1, a3=bb1;
            const float4* w4 = (const float4*)(&wbuf[tid*68]);
            const float4* x0 = (const float4*)(&xs[tk[0]*DD]);
            const float4* x1 = (const float4*)(&xs[tk[1]*DD]);
            const float4* x2 = (const float4*)(&xs[tk[2]*DD]);
            const float4* x3 = (const float4*)(&xs[tk[3]*DD]);
            #pragma unroll
            for (int dq=0; dq<16; ++dq){
                float4 wv = w4[dq];
                a0 += dot4f(x0[dq], wv);
                a1 += dot4f(x1[dq], wv);
                a2 += dot4f(x2[dq], wv);
                a3 += dot4f(x3[dq], wv);
            }
            hsA[tk[0]*FFND + tid] = geluf(a0);
            hsA[tk[1]*FFND + tid] = geluf(a1);
            hsA[tk[2]*FFND + tid] = geluf(a2);
            hsA[tk[3]*FFND + tid] = geluf(a3);
        }
        __syncthreads();
        // stage w2[e]: wbuf[f*68+d] = w2[e][f][d]
        for (int i = tid; i < FFND*DD; i += 256){
            int f = i >> 6, d = i & 63;
            wbuf[f*68 + d] = w2g[((size_t)e*FFND + f)*DD + d];
        }
        __syncthreads();
        const int dq = tid >> 4, part = tid & 15;
        for (int ii=0; ii<c; ii+=4){
            int tk[4]; float gw[4];
            #pragma unroll
            for (int u=0;u<4;++u){
                int jj = ii+u;
                tk[u] = llist[e][min(jj, c-1)];
                gw[u] = (jj < c) ? lwt[e][jj] : 0.f;
            }
            float ya[4][4] = {};
            #pragma unroll
            for (int i2=0; i2<16; ++i2){
                int f = i2*16 + part;
                float4 wv = *(const float4*)(&wbuf[f*68 + dq*4]);
                #pragma unroll
                for (int u=0;u<4;++u){
                    float hv = hsA[tk[u]*FFND + f];
                    ya[u][0] += hv*wv.x; ya[u][1] += hv*wv.y;
                    ya[u][2] += hv*wv.z; ya[u][3] += hv*wv.w;
                }
            }
            #pragma unroll
            for (int m2=1; m2<16; m2<<=1){
                #pragma unroll
                for (int u=0;u<4;++u){
                    ya[u][0] += __shfl_xor(ya[u][0], m2);
                    ya[u][1] += __shfl_xor(ya[u][1], m2);
                    ya[u][2] += __shfl_xor(ya[u][2], m2);
                    ya[u][3] += __shfl_xor(ya[u][3], m2);
                }
            }
            if (part == 0){
                #pragma unroll
                for (int u=0;u<4;++u){
                    float* yp = &ys[tk[u]*DD + dq*4];
                    yp[0] += gw[u]*(ya[u][0] + b2g[e*DD + dq*4 + 0]);
                    yp[1] += gw[u]*(ya[u][1] + b2g[e*DD + dq*4 + 1]);
                    yp[2] += gw[u]*(ya[u][2] + b2g[e*DD + dq*4 + 2]);
                    yp[3] += gw[u]*(ya[u][3] + b2g[e*DD + dq*4 + 3]);
                }
            }
        }
        __syncthreads();
    }

    // gelu(ys) -> xs
    for (int i = tid; i < nb*DD; i += 256) xs[i] = geluf(ys[i]);
    // stage proj weights: wbuf[j*68+d] = pw[d][j] (first NPROJ cols)
    for (int i = tid; i < DD*NPROJ; i += 256){
        int d = i / NPROJ, j = i % NPROJ;
        wbuf[j*68 + d] = pwg[(size_t)d*pwld + j];
    }
    __syncthreads();
    for (int o = tid; o < nb*NPROJ; o += 256){
        int tok = o / NPROJ, j = o % NPROJ;
        float acc = pbg[j];
        const float4* gp = (const float4*)(&xs[tok*DD]);
        const float4* wp = (const float4*)(&wbuf[j*68]);
        #pragma unroll
        for (int dq2=0; dq2<16; ++dq2) acc += dot4f(gp[dq2], wp[dq2]);
        int n = base + tok;
        int b = n / (seqLen*HH);
        int r = n % (seqLen*HH);
        int sr = r / HH, h = r % HH;
        int bufi = j >> 6, jd = j & 63;
        float* dst = (bufi==0) ? out0 : (bufi==1) ? out1 : out2;
        dst[(((size_t)b*HH + h)*seqLen + sr)*DD + jd] = acc;
    }
}

// ---------------- Attention: per (b,h,32-row t-tile) ----------------
__global__ __launch_bounds__(256) void attn_kernel(
    const float* __restrict__ qb,   // (B,H,T,64)
    const float* __restrict__ kmb,  // (B,H,T,64)
    const float* __restrict__ vmb,
    const float* __restrict__ ktb,  // (B,H,M,64)
    const float* __restrict__ vtb,
    const float* __restrict__ kd,   // (NDS,48,H,64) -> use [0]
    const float* __restrict__ vd,
    const float* __restrict__ kr,   // (48,H,64)
    const float* __restrict__ vr,
    const int*   __restrict__ smask, // (B,T)
    const float* __restrict__ tcond, // (B,1)
    const float* __restrict__ kms_p, const float* __restrict__ kds_p,
    const float* __restrict__ krs_p, const float* __restrict__ kts_p,
    const float* __restrict__ sigma_p,
    float* __restrict__ outb)        // (B,T,640)
{
    __shared__ __align__(16) float qs[32*68];
    __shared__ __align__(16) float ks[64*68];
    __shared__ float ls[32*689];
    int tid = threadIdx.x;
    int bid = blockIdx.x;
    int ttile = bid & 15;
    int bh = bid >> 4;
    int b = bh / HH, h = bh % HH;
    int t0 = ttile * 32;
    const float sc = 0.125f;
    float kms = kms_p[0]*sc, kds = kds_p[0]*sc, krs = krs_p[0]*sc, kts = kts_p[0]*sc;
    float sg = sigma_p[0];
    float inv2s = 1.0f/(2.0f*sg*sg);
    bool text_on = tcond[b] > 0.f;

    const float* qsrc = qb + (((size_t)bh)*TT + t0)*DD;
    for (int i=tid; i<32*64; i+=256){
        int r = i>>6, d = i&63;
        qs[r*68+d] = qsrc[r*64+d];
    }
    int tp = tid >> 4;   // 0..15
    int sq = tid & 15;   // 0..15

    for (int ch=0; ch<NCH; ++ch){
        __syncthreads();
        for (int i=tid; i<64*64; i+=256){
            int r = i>>6, d = i&63;
            int s = ch*64 + r;
            float v = 0.f;
            if (s < TT)            v = kmb[(((size_t)bh)*TT + s)*DD + d] * kms;
            else if (s < TT+48)    v = kd[((size_t)(s-TT)*HH + h)*DD + d] * kds;
            else if (s < TT+96)    v = kr[((size_t)(s-TT-48)*HH + h)*DD + d] * krs;
            else if (s < NS)       v = ktb[(((size_t)bh)*MM + (s-TT-96))*DD + d] * kts;
            ks[r*68+d] = v;
        }
        __syncthreads();
        float acc[2][4] = {};
        const float4* q0 = (const float4*)(&qs[(tp*2+0)*68]);
        const float4* q1 = (const float4*)(&qs[(tp*2+1)*68]);
        #pragma unroll 4
        for (int dq=0; dq<16; ++dq){
            float4 qa = q0[dq], qb4 = q1[dq];
            #pragma unroll
            for (int j=0;j<4;++j){
                float4 kv = *(const float4*)(&ks[(sq + 16*j)*68 + dq*4]);
                acc[0][j] += dot4f(qa, kv);
                acc[1][j] += dot4f(qb4, kv);
            }
        }
        #pragma unroll
        for (int i=0;i<2;++i){
            int t = t0 + tp*2 + i;
            #pragma unroll
            for (int j=0;j<4;++j){
                int sl = sq + 16*j;
                int s = ch*64 + sl;
                float lg;
                if (s < TT){
                    float dt = (float)(t - s);
                    lg = acc[i][j] - dt*dt*inv2s;
                    if (smask[b*TT + s] == 0) lg = -1e9f;
                } else if (s < TT+96){
                    lg = acc[i][j];
                } else if (s < NS){
                    lg = text_on ? acc[i][j] : -1e9f;
                } else lg = -1e30f;
                ls[(tp*2+i)*689 + ch*64 + sl] = lg;
            }
        }
    }
    __syncthreads();
    // softmax: 8 lanes per row
    {
        int row = tid >> 3, sub = tid & 7;
        float* lp = &ls[row*689];
        float mx = -1e30f;
        for (int s=sub; s<NS; s+=8) mx = fmaxf(mx, lp[s]);
        for (int m2=1;m2<8;m2<<=1) mx = fmaxf(mx, __shfl_xor(mx, m2));
        float sum = 0.f;
        for (int s=sub; s<NS; s+=8){ float e2 = expf(lp[s]-mx); lp[s]=e2; sum += e2; }
        for (int m2=1;m2<8;m2<<=1) sum += __shfl_xor(sum, m2);
        float inv = 1.0f/sum;
        for (int s=sub; s<NS; s+=8) lp[s] *= inv;
    }
    // PV
    float oacc[2][4] = {};
    int dq = sq;
    for (int ch=0; ch<NCH; ++ch){
        __syncthreads();
        for (int i=tid; i<64*64; i+=256){
            int r = i>>6, d = i&63;
            int s = ch*64 + r;
            float v = 0.f;
            if (s < TT)            v = vmb[(((size_t)bh)*TT + s)*DD + d];
            else if (s < TT+48)    v = vd[((size_t)(s-TT)*HH + h)*DD + d];
            else if (s < TT+96)    v = vr[((size_t)(s-TT-48)*HH + h)*DD + d];
            else if (s < NS)       v = vtb[(((size_t)bh)*MM + (s-TT-96))*DD + d];
            ks[r*68+d] = v;
        }
        __syncthreads();
        int smax = min(64, NS - ch*64);
        for (int sl=0; sl<smax; ++sl){
            float p0 = ls[(tp*2+0)*689 + ch*64 + sl];
            float p1 = ls[(tp*2+1)*689 + ch*64 + sl];
            float4 vv = *(const float4*)(&ks[sl*68 + dq*4]);
            oacc[0][0] += p0*vv.x; oacc[0][1] += p0*vv.y; oacc[0][2] += p0*vv.z; oacc[0][3] += p0*vv.w;
            oacc[1][0] += p1*vv.x; oacc[1][1] += p1*vv.y; oacc[1][2] += p1*vv.z; oacc[1][3] += p1*vv.w;
        }
    }
    #pragma unroll
    for (int i=0;i<2;++i){
        int t = t0 + tp*2 + i;
        float4 o4 = make_float4(oacc[i][0], oacc[i][1], oacc[i][2], oacc[i][3]);
        *(float4*)(&outb[((size_t)(b*TT + t))*LATD + h*64 + dq*4]) = o4;
    }
}

// ---------------- generic tiled GEMM: C = act(A) @ W + bias (+res) ----------------
template<bool ACT_SILU>
__global__ __launch_bounds__(256) void gemm_kernel(
    const float* __restrict__ A, const float* __restrict__ W,
    const float* __restrict__ bias, const float* __restrict__ res,
    float* __restrict__ C, int Mr, int Nr, int Kr)
{
    __shared__ __align__(16) float As[32*68];   // [k][m]
    __shared__ __align__(16) float Ws[32*68];   // [k][n]
    int tid = threadIdx.x;
    int row0 = blockIdx.x*64, col0 = blockIdx.y*64;
    int tr = tid >> 4, tc = tid & 15;
    float acc[4][4] = {};
    for (int k0=0; k0<Kr; k0+=32){
        __syncthreads();
        for (int i=tid; i<64*32; i+=256){
            int m2 = i>>5, k = i&31;
            float v = A[((size_t)(row0+m2))*Kr + k0 + k];
            if (ACT_SILU) v = siluf(v);
            As[k*68 + m2] = v;
        }
        for (int i=tid; i<32*64; i+=256){
            int k = i>>6, n = i&63;
            Ws[k*68 + n] = W[((size_t)(k0+k))*Nr + col0 + n];
        }
        __syncthreads();
        #pragma unroll 8
        for (int k=0;k<32;++k){
            float4 av = *(const float4*)(&As[k*68 + tr*4]);
            float4 wv = *(const float4*)(&Ws[k*68 + tc*4]);
            float a4[4] = {av.x, av.y, av.z, av.w};
            float w4[4] = {wv.x, wv.y, wv.z, wv.w};
            #pragma unroll
            for (int i=0;i<4;++i)
                #pragma unroll
                for (int j=0;j<4;++j) acc[i][j] += a4[i]*w4[j];
        }
    }
    #pragma unroll
    for (int i=0;i<4;++i){
        int r = row0 + tr*4 + i;
        size_t off = (size_t)r*Nr + col0 + tc*4;
        float4 bv = *(const float4*)(&bias[col0 + tc*4]);
        float4 o = make_float4(acc[i][0]+bv.x, acc[i][1]+bv.y, acc[i][2]+bv.z, acc[i][3]+bv.w);
        if (res){
            float4 rv = *(const float4*)(&res[off]);
            o.x += rv.x; o.y += rv.y; o.z += rv.z; o.w += rv.w;
        }
        *(float4*)(&C[off]) = o;
    }
}

// ---------------- modulated LN + silu: out = silu(LN(in)*(1+eo[:640]) + eo[640:]) ----------------
__global__ __launch_bounds__(256) void lnmod_kernel(
    const float* __restrict__ in, const float* __restrict__ g, const float* __restrict__ bb,
    const float* __restrict__ eo, float* __restrict__ out)
{
    int row = blockIdx.x, tid = threadIdx.x;
    __shared__ float xsr[LATD];
    __shared__ float red[256];
    const float* rp = in + (size_t)row*LATD;
    float s = 0.f;
    for (int i=tid;i<LATD;i+=256){ float v = rp[i]; xsr[i]=v; s+=v; }
    red[tid]=s; __syncthreads();
    for (int k=128;k>0;k>>=1){ if (tid<k) red[tid]+=red[tid+k]; __syncthreads(); }
    float mean = red[0]*(1.0f/LATD);
    __syncthreads();
    float vs=0.f;
    for (int i=tid;i<LATD;i+=256){ float d=xsr[i]-mean; vs+=d*d; }
    red[tid]=vs; __syncthreads();
    for (int k=128;k>0;k>>=1){ if (tid<k) red[tid]+=red[tid+k]; __syncthreads(); }
    float rstd = rsqrtf(red[0]*(1.0f/LATD)+1e-5f);
    const float* ep = eo + (size_t)row*(2*LATD);
    float* op = out + (size_t)row*LATD;
    for (int i=tid;i<LATD;i+=256){
        float v = (xsr[i]-mean)*rstd*g[i] + bb[i];
        v = v*(1.0f + ep[i]) + ep[LATD+i];
        op[i] = siluf(v);
    }
}

extern "C" void kernel_launch(void* const* d_in, const int* in_sizes, int n_in,
                              void* d_out, int out_size, void* d_ws, size_t ws_size,
                              hipStream_t stream)
{
    (void)in_sizes; (void)n_in; (void)out_size; (void)ws_size;
    const float* x     = (const float*)d_in[0];
    const float* emb   = (const float*)d_in[1];
    const int*   smask = (const int*)d_in[2];
    const float* tcond = (const float*)d_in[5];
    const float* two   = (const float*)d_in[6];
    const float* ng    = (const float*)d_in[7];
    const float* nb    = (const float*)d_in[8];
    const float* memb  = (const float*)d_in[9];
    const float* m_wg  = (const float*)d_in[10];
    const float* m_w1  = (const float*)d_in[11];
    const float* m_b1  = (const float*)d_in[12];
    const float* m_w2  = (const float*)d_in[13];
    const float* m_b2  = (const float*)d_in[14];
    const float* m_pw  = (const float*)d_in[15];
    const float* m_pb  = (const float*)d_in[16];
    const float* kms   = (const float*)d_in[17];
    const float* sigma = (const float*)d_in[18];
    const float* kdat  = (const float*)d_in[19];
    const float* kds   = (const float*)d_in[20];
    const float* vdat  = (const float*)d_in[21];
    const float* krot  = (const float*)d_in[22];
    const float* krs   = (const float*)d_in[23];
    const float* vrot  = (const float*)d_in[24];
    const float* ntg   = (const float*)d_in[25];
    const float* ntb   = (const float*)d_in[26];
    const float* c_wg  = (const float*)d_in[27];
    const float* c_w1  = (const float*)d_in[28];
    const float* c_b1  = (const float*)d_in[29];
    const float* c_w2  = (const float*)d_in[30];
    const float* c_b2  = (const float*)d_in[31];
    const float* c_pw  = (const float*)d_in[32];
    const float* c_pb  = (const float*)d_in[33];
    const float* kts   = (const float*)d_in[34];
    const float* st_ew = (const float*)d_in[35];
    const float* st_eb = (const float*)d_in[36];
    const float* st_ng = (const float*)d_in[37];
    const float* st_nb = (const float*)d_in[38];
    const float* st_ow = (const float*)d_in[39];
    const float* st_ob = (const float*)d_in[40];

    float* ws = (float*)d_ws;
    float* xh   = ws;                    // 1310720
    float* qB   = xh  + 1310720;         // 1310720
    float* kmB  = qB  + 1310720;         // 1310720
    float* vmB  = kmB + 1310720;         // 1310720
    float* ctB  = vmB + 1310720;         // 197120
    float* ktB  = ctB + 197120;          // 197120
    float* vtB  = ktB + 197120;          // 197120
    float* aout = vtB + 197120;          // 1310720
    float* eoB  = aout + 1310720;        // 2621440
    float* shB  = eoB + 2621440;         // 1310720

    // 1. LN(x) + moe_emb -> xh ; LN(text) -> ctB
    ln_kernel<<<BB*TT, 256, 0, stream>>>(x, ng, nb, memb, xh, TT);
    ln_kernel<<<BB*MM, 256, 0, stream>>>(two, ntg, ntb, nullptr, ctB, MM);
    // 2. MoE + proj
    moe_kernel<192><<<(BB*TT*HH)/TOKB, 256, 0, stream>>>(
        xh, m_wg, m_w1, m_b1, m_w2, m_b2, m_pw, m_pb, 5*DD, BB*TT*HH, TT, qB, kmB, vmB);
    moe_kernel<128><<<(BB*MM*HH + TOKB - 1)/TOKB, 256, 0, stream>>>(
        ctB, c_wg, c_w1, c_b1, c_w2, c_b2, c_pw, c_pb, 2*DD, BB*MM*HH, MM, ktB, vtB, nullptr);
    // 3. attention
    attn_kernel<<<BB*HH*16, 256, 0, stream>>>(
        qB, kmB, vmB, ktB, vtB, kdat, vdat, krot, vrot, smask, tcond,
        kms, kds, krs, kts, sigma, aout);
    // 4. eo = silu(emb) @ st_emb_w + st_emb_b
    {
        dim3 g1(2048/64, 1280/64);
        gemm_kernel<true><<<g1, 256, 0, stream>>>(emb, st_ew, st_eb, nullptr, eoB, 2048, 1280, 512);
    }
    // 5. hh = LN(aout)*(1+eo[:640]) + eo[640:]; sh = silu(hh)
    lnmod_kernel<<<BB*TT, 256, 0, stream>>>(aout, st_ng, st_nb, eoB, shB);
    // 6. out = x + sh @ st_out_w + st_out_b
    {
        dim3 g2(2048/64, 640/64);
        gemm_kernel<false><<<g2, 256, 0, stream>>>(shB, st_ow, st_ob, x, (float*)d_out, 2048, 640, 640);
    }
}

// Round 2
// 815.681 us; speedup vs baseline: 1.4630x; 1.4630x over previous
//
#include <hip/hip_runtime.h>
#include <math.h>

#define BB 4
#define TT 512
#define MM 77
#define HH 10
#define DD 64
#define LATD 640
#define EE 8
#define FFND 256
#define NS 685     // 512 + 48 + 48 + 77
#define NCH 11     // ceil(685/64)
#define TOKB 32

__device__ __forceinline__ float geluf(float x){
    const float c0 = 0.7978845608028654f;
    return 0.5f*x*(1.0f + tanhf(c0*(x + 0.044715f*x*x*x)));
}
__device__ __forceinline__ float siluf(float x){
    return x / (1.0f + expf(-x));
}
__device__ __forceinline__ float dot4f(float4 a, float4 b){
    return a.x*b.x + a.y*b.y + a.z*b.z + a.w*b.w;
}

// ---------------- LayerNorm (rows of 640), optional additive emb (T,640) ----------------
__global__ __launch_bounds__(256) void ln_kernel(
    const float* __restrict__ in, const float* __restrict__ g, const float* __restrict__ bb,
    const float* __restrict__ addv, float* __restrict__ out, int seqLen)
{
    int row = blockIdx.x, tid = threadIdx.x;
    __shared__ float xsr[LATD];
    __shared__ float red[256];
    const float* rp = in + (size_t)row*LATD;
    float s = 0.f;
    for (int i=tid;i<LATD;i+=256){ float v = rp[i]; xsr[i]=v; s+=v; }
    red[tid]=s; __syncthreads();
    for (int k=128;k>0;k>>=1){ if (tid<k) red[tid]+=red[tid+k]; __syncthreads(); }
    float mean = red[0]*(1.0f/LATD);
    __syncthreads();
    float vs=0.f;
    for (int i=tid;i<LATD;i+=256){ float d=xsr[i]-mean; vs+=d*d; }
    red[tid]=vs; __syncthreads();
    for (int k=128;k>0;k>>=1){ if (tid<k) red[tid]+=red[tid+k]; __syncthreads(); }
    float rstd = rsqrtf(red[0]*(1.0f/LATD)+1e-5f);
    int t = row % seqLen;
    const float* ap = addv ? (addv + (size_t)t*LATD) : nullptr;
    float* op = out + (size_t)row*LATD;
    for (int i=tid;i<LATD;i+=256){
        float v = (xsr[i]-mean)*rstd*g[i] + bb[i];
        if (ap) v += ap[i];
        op[i] = v;
    }
}

// ---------------- MoE (top-2 of 8) + gelu + projection ----------------
template<int NPROJ>
__global__ __launch_bounds__(256) void moe_kernel(
    const float* __restrict__ xin,
    const float* __restrict__ wg,    // (64,8)
    const float* __restrict__ w1g,   // (8,64,256)
    const float* __restrict__ b1g,   // (8,256)
    const float* __restrict__ w2g,   // (8,256,64)
    const float* __restrict__ b2g,   // (8,64)
    const float* __restrict__ pwg,   // (64, pwld)
    const float* __restrict__ pbg,
    int pwld, int nTok, int seqLen,
    float* __restrict__ out0, float* __restrict__ out1, float* __restrict__ out2)
{
    __shared__ __align__(16) float wbuf[FFND*68];
    __shared__ __align__(16) float xs[TOKB*DD];
    __shared__ __align__(16) float ys[TOKB*DD];
    __shared__ float hsA[TOKB*FFND];
    __shared__ int   lcnt[EE];
    __shared__ int   llist[EE][TOKB];
    __shared__ float lwt[EE][TOKB];
    __shared__ int   te0[TOKB], te1[TOKB];
    __shared__ float tw0s[TOKB], tw1s[TOKB];

    const int tid = threadIdx.x;
    const int base = blockIdx.x * TOKB;
    const int nb = min(TOKB, nTok - base);

    for (int i = tid; i < nb*DD; i += 256) xs[i] = xin[(size_t)base*DD + i];
    for (int i = tid; i < TOKB*DD; i += 256) ys[i] = 0.f;
    if (tid < EE) lcnt[tid] = 0;
    __syncthreads();

    if (tid < nb){
        float lg[EE];
        #pragma unroll
        for (int e=0;e<EE;e++) lg[e]=0.f;
        for (int d=0; d<DD; ++d){
            float xv = xs[tid*DD+d];
            #pragma unroll
            for (int e=0;e<EE;e++) lg[e] += xv * wg[d*EE+e];
        }
        float mx = lg[0];
        #pragma unroll
        for (int e=1;e<EE;e++) mx = fmaxf(mx, lg[e]);
        float sum = 0.f;
        #pragma unroll
        for (int e=0;e<EE;e++){ lg[e] = expf(lg[e]-mx); sum += lg[e]; }
        float inv = 1.0f/sum;
        #pragma unroll
        for (int e=0;e<EE;e++) lg[e] *= inv;
        int e0=0; float v0=lg[0];
        #pragma unroll
        for (int e=1;e<EE;e++){ if (lg[e] > v0){ v0 = lg[e]; e0 = e; } }
        int e1=0; float v1=-1e30f;
        #pragma unroll
        for (int e=0;e<EE;e++){ if (e==e0) continue; if (lg[e] > v1){ v1 = lg[e]; e1 = e; } }
        te0[tid]=e0; te1[tid]=e1; tw0s[tid]=v0; tw1s[tid]=v1;
    }
    __syncthreads();
    if (tid < EE){
        int c = 0;
        for (int t2=0; t2<nb; ++t2){
            if (te0[t2]==tid){ llist[tid][c]=t2; lwt[tid][c]=tw0s[t2]; ++c; }
            else if (te1[t2]==tid){ llist[tid][c]=t2; lwt[tid][c]=tw1s[t2]; ++c; }
        }
        lcnt[tid]=c;
    }
    __syncthreads();

    for (int e=0; e<EE; ++e){
        const int c = lcnt[e];
        if (c == 0) continue;
        for (int i = tid; i < DD*FFND; i += 256){
            int d = i >> 8, f = i & 255;
            wbuf[f*68 + d] = w1g[((size_t)e*DD + d)*FFND + f];
        }
        __syncthreads();
        const float bb1 = b1g[e*FFND + tid];
        for (int ii=0; ii<c; ii+=4){
            int tk[4];
            #pragma unroll
            for (int u=0;u<4;++u) tk[u] = llist[e][min(ii+u, c-1)];
            float a0=bb1, a1=bb1, a2=bb1, a3=bb1;
            const float4* w4 = (const float4*)(&wbuf[tid*68]);
            const float4* x0 = (const float4*)(&xs[tk[0]*DD]);
            const float4* x1 = (const float4*)(&xs[tk[1]*DD]);
            const float4* x2 = (const float4*)(&xs[tk[2]*DD]);
            const float4* x3 = (const float4*)(&xs[tk[3]*DD]);
            #pragma unroll
            for (int dq=0; dq<16; ++dq){
                float4 wv = w4[dq];
                a0 += dot4f(x0[dq], wv);
                a1 += dot4f(x1[dq], wv);
                a2 += dot4f(x2[dq], wv);
                a3 += dot4f(x3[dq], wv);
            }
            hsA[tk[0]*FFND + tid] = geluf(a0);
            hsA[tk[1]*FFND + tid] = geluf(a1);
            hsA[tk[2]*FFND + tid] = geluf(a2);
            hsA[tk[3]*FFND + tid] = geluf(a3);
        }
        __syncthreads();
        for (int i = tid; i < FFND*DD; i += 256){
            int f = i >> 6, d = i & 63;
            wbuf[f*68 + d] = w2g[((size_t)e*FFND + f)*DD + d];
        }
        __syncthreads();
        const int dq = tid >> 4, part = tid & 15;
        for (int ii=0; ii<c; ii+=4){
            int tk[4]; float gw[4];
            #pragma unroll
            for (int u=0;u<4;++u){
                int jj = ii+u;
                tk[u] = llist[e][min(jj, c-1)];
                gw[u] = (jj < c) ? lwt[e][jj] : 0.f;
            }
            float ya[4][4] = {};
            #pragma unroll
            for (int i2=0; i2<16; ++i2){
                int f = i2*16 + part;
                float4 wv = *(const float4*)(&wbuf[f*68 + dq*4]);
                #pragma unroll
                for (int u=0;u<4;++u){
                    float hv = hsA[tk[u]*FFND + f];
                    ya[u][0] += hv*wv.x; ya[u][1] += hv*wv.y;
                    ya[u][2] += hv*wv.z; ya[u][3] += hv*wv.w;
                }
            }
            #pragma unroll
            for (int m2=1; m2<16; m2<<=1){
                #pragma unroll
                for (int u=0;u<4;++u){
                    ya[u][0] += __shfl_xor(ya[u][0], m2);
                    ya[u][1] += __shfl_xor(ya[u][1], m2);
                    ya[u][2] += __shfl_xor(ya[u][2], m2);
                    ya[u][3] += __shfl_xor(ya[u][3], m2);
                }
            }
            if (part == 0){
                #pragma unroll
                for (int u=0;u<4;++u){
                    float* yp = &ys[tk[u]*DD + dq*4];
                    yp[0] += gw[u]*(ya[u][0] + b2g[e*DD + dq*4 + 0]);
                    yp[1] += gw[u]*(ya[u][1] + b2g[e*DD + dq*4 + 1]);
                    yp[2] += gw[u]*(ya[u][2] + b2g[e*DD + dq*4 + 2]);
                    yp[3] += gw[u]*(ya[u][3] + b2g[e*DD + dq*4 + 3]);
                }
            }
        }
        __syncthreads();
    }

    for (int i = tid; i < nb*DD; i += 256) xs[i] = geluf(ys[i]);
    for (int i = tid; i < DD*NPROJ; i += 256){
        int d = i / NPROJ, j = i % NPROJ;
        wbuf[j*68 + d] = pwg[(size_t)d*pwld + j];
    }
    __syncthreads();
    for (int o = tid; o < nb*NPROJ; o += 256){
        int tok = o / NPROJ, j = o % NPROJ;
        float acc = pbg[j];
        const float4* gp = (const float4*)(&xs[tok*DD]);
        const float4* wp = (const float4*)(&wbuf[j*68]);
        #pragma unroll
        for (int dq2=0; dq2<16; ++dq2) acc += dot4f(gp[dq2], wp[dq2]);
        int n = base + tok;
        int b = n / (seqLen*HH);
        int r = n % (seqLen*HH);
        int sr = r / HH, h = r % HH;
        int bufi = j >> 6, jd = j & 63;
        float* dst = (bufi==0) ? out0 : (bufi==1) ? out1 : out2;
        dst[(((size_t)b*HH + h)*seqLen + sr)*DD + jd] = acc;
    }
}

// ---------------- Flash attention: per (b,h,32-row t-tile), online softmax ----------------
__global__ __launch_bounds__(256) void attn_kernel(
    const float* __restrict__ qb,   // (B,H,T,64)
    const float* __restrict__ kmb,  // (B,H,T,64)
    const float* __restrict__ vmb,
    const float* __restrict__ ktb,  // (B,H,M,64)
    const float* __restrict__ vtb,
    const float* __restrict__ kd,   // (NDS,48,H,64) -> [0]
    const float* __restrict__ vd,
    const float* __restrict__ kr,   // (48,H,64)
    const float* __restrict__ vr,
    const int*   __restrict__ smask, // (B,T)
    const float* __restrict__ tcond, // (B,1)
    const float* __restrict__ kms_p, const float* __restrict__ kds_p,
    const float* __restrict__ krs_p, const float* __restrict__ kts_p,
    const float* __restrict__ sigma_p,
    float* __restrict__ outb)        // (B,T,640)
{
    __shared__ __align__(16) float qs[32*68];
    __shared__ __align__(16) float ks[64*68];
    __shared__ __align__(16) float vs[64*68];
    __shared__ __align__(16) float ps_l[32*68];
    __shared__ float madd[64];

    int tid = threadIdx.x;
    int bid = blockIdx.x;
    int ttile = bid & 15;
    int bh = bid >> 4;
    int b = bh / HH, h = bh % HH;
    int t0 = ttile * 32;
    const float sc = 0.125f;
    float kms = kms_p[0]*sc, kds = kds_p[0]*sc, krs = krs_p[0]*sc, kts = kts_p[0]*sc;
    float sg = sigma_p[0];
    float inv2s = 1.0f/(2.0f*sg*sg);
    bool text_on = tcond[b] > 0.f;

    const float* qsrc = qb + (((size_t)bh)*TT + t0)*DD;
    for (int i=tid; i<32*16; i+=256){
        int r = i>>4, dq = i&15;
        *(float4*)(&qs[r*68+dq*4]) = *(const float4*)(&qsrc[r*64+dq*4]);
    }
    int tp = tid >> 4;   // 0..15 -> rows tp*2, tp*2+1
    int sq = tid & 15;   // 0..15

    float m_r[2] = {-1e30f, -1e30f};
    float l_r[2] = {0.f, 0.f};
    float oacc[2][4] = {};

    for (int ch=0; ch<NCH; ++ch){
        __syncthreads();
        // stage K & V chunk (scales folded into K), pad with zeros
        for (int i=tid; i<64*16; i+=256){
            int r = i>>4, dq = i&15;
            int s = ch*64 + r;
            float4 kv = make_float4(0,0,0,0), vv = make_float4(0,0,0,0);
            if (s < TT){
                kv = *(const float4*)(&kmb[(((size_t)bh)*TT + s)*DD + dq*4]);
                kv.x*=kms; kv.y*=kms; kv.z*=kms; kv.w*=kms;
                vv = *(const float4*)(&vmb[(((size_t)bh)*TT + s)*DD + dq*4]);
            } else if (s < TT+48){
                kv = *(const float4*)(&kd[((size_t)(s-TT)*HH + h)*DD + dq*4]);
                kv.x*=kds; kv.y*=kds; kv.z*=kds; kv.w*=kds;
                vv = *(const float4*)(&vd[((size_t)(s-TT)*HH + h)*DD + dq*4]);
            } else if (s < TT+96){
                kv = *(const float4*)(&kr[((size_t)(s-TT-48)*HH + h)*DD + dq*4]);
                kv.x*=krs; kv.y*=krs; kv.z*=krs; kv.w*=krs;
                vv = *(const float4*)(&vr[((size_t)(s-TT-48)*HH + h)*DD + dq*4]);
            } else if (s < NS){
                kv = *(const float4*)(&ktb[(((size_t)bh)*MM + (s-TT-96))*DD + dq*4]);
                kv.x*=kts; kv.y*=kts; kv.z*=kts; kv.w*=kts;
                vv = *(const float4*)(&vtb[(((size_t)bh)*MM + (s-TT-96))*DD + dq*4]);
            }
            *(float4*)(&ks[r*68+dq*4]) = kv;
            *(float4*)(&vs[r*68+dq*4]) = vv;
        }
        if (tid < 64){
            int s = ch*64 + tid;
            float a;
            if (s < TT)            a = (smask[b*TT + s] == 0) ? -1e9f : 0.f;
            else if (s < TT+96)    a = 0.f;
            else if (s < NS)       a = text_on ? 0.f : -1e9f;
            else                   a = -1e30f;
            madd[tid] = a;
        }
        __syncthreads();

        // S tile: rows tp*2+{0,1}, cols sq+16j
        float acc[2][4] = {};
        const float4* q0 = (const float4*)(&qs[(tp*2+0)*68]);
        const float4* q1 = (const float4*)(&qs[(tp*2+1)*68]);
        #pragma unroll 4
        for (int dq=0; dq<16; ++dq){
            float4 qa = q0[dq], qb4 = q1[dq];
            #pragma unroll
            for (int j=0;j<4;++j){
                float4 kv = *(const float4*)(&ks[(sq + 16*j)*68 + dq*4]);
                acc[0][j] += dot4f(qa, kv);
                acc[1][j] += dot4f(qb4, kv);
            }
        }
        // add bias/mask
        #pragma unroll
        for (int i=0;i<2;++i){
            int t = t0 + tp*2 + i;
            #pragma unroll
            for (int j=0;j<4;++j){
                int sl = sq + 16*j;
                int s = ch*64 + sl;
                float a = madd[sl];
                if (s < TT){ float dt = (float)(t - s); a -= dt*dt*inv2s; }
                acc[i][j] += a;
            }
        }
        // online softmax update
        float pm[2], mn[2], scl[2], ps[2];
        #pragma unroll
        for (int i=0;i<2;++i)
            pm[i] = fmaxf(fmaxf(acc[i][0], acc[i][1]), fmaxf(acc[i][2], acc[i][3]));
        #pragma unroll
        for (int m2=1; m2<16; m2<<=1){
            pm[0] = fmaxf(pm[0], __shfl_xor(pm[0], m2));
            pm[1] = fmaxf(pm[1], __shfl_xor(pm[1], m2));
        }
        #pragma unroll
        for (int i=0;i<2;++i){
            mn[i] = fmaxf(m_r[i], pm[i]);
            scl[i] = __expf(m_r[i] - mn[i]);
            m_r[i] = mn[i];
            ps[i] = 0.f;
            #pragma unroll
            for (int j=0;j<4;++j){
                acc[i][j] = __expf(acc[i][j] - mn[i]);
                ps[i] += acc[i][j];
            }
        }
        #pragma unroll
        for (int m2=1; m2<16; m2<<=1){
            ps[0] += __shfl_xor(ps[0], m2);
            ps[1] += __shfl_xor(ps[1], m2);
        }
        #pragma unroll
        for (int i=0;i<2;++i){
            l_r[i] = l_r[i]*scl[i] + ps[i];
            #pragma unroll
            for (int j=0;j<4;++j) oacc[i][j] *= scl[i];
        }
        // write P tile
        #pragma unroll
        for (int i=0;i<2;++i)
            #pragma unroll
            for (int j=0;j<4;++j)
                ps_l[(tp*2+i)*68 + sq + 16*j] = acc[i][j];
        __syncthreads();
        // PV: rows tp*2+{0,1}, dims sq*4..sq*4+3
        const float* p0r = &ps_l[(tp*2+0)*68];
        const float* p1r = &ps_l[(tp*2+1)*68];
        #pragma unroll 8
        for (int sl=0; sl<64; ++sl){
            float p0 = p0r[sl], p1 = p1r[sl];
            float4 vv = *(const float4*)(&vs[sl*68 + sq*4]);
            oacc[0][0] += p0*vv.x; oacc[0][1] += p0*vv.y; oacc[0][2] += p0*vv.z; oacc[0][3] += p0*vv.w;
            oacc[1][0] += p1*vv.x; oacc[1][1] += p1*vv.y; oacc[1][2] += p1*vv.z; oacc[1][3] += p1*vv.w;
        }
    }
    #pragma unroll
    for (int i=0;i<2;++i){
        int t = t0 + tp*2 + i;
        float inv = 1.0f / l_r[i];
        float4 o4 = make_float4(oacc[i][0]*inv, oacc[i][1]*inv, oacc[i][2]*inv, oacc[i][3]*inv);
        *(float4*)(&outb[((size_t)(b*TT + t))*LATD + h*64 + sq*4]) = o4;
    }
}

// ---------------- generic tiled GEMM: C = act(A) @ W + bias (+res) ----------------
template<bool ACT_SILU>
__global__ __launch_bounds__(256) void gemm_kernel(
    const float* __restrict__ A, const float* __restrict__ W,
    const float* __restrict__ bias, const float* __restrict__ res,
    float* __restrict__ C, int Mr, int Nr, int Kr)
{
    __shared__ __align__(16) float As[32*68];   // [k][m]
    __shared__ __align__(16) float Ws[32*68];   // [k][n]
    int tid = threadIdx.x;
    int row0 = blockIdx.x*64, col0 = blockIdx.y*64;
    int tr = tid >> 4, tc = tid & 15;
    float acc[4][4] = {};
    for (int k0=0; k0<Kr; k0+=32){
        __syncthreads();
        for (int i=tid; i<64*32; i+=256){
            int m2 = i>>5, k = i&31;
            float v = A[((size_t)(row0+m2))*Kr + k0 + k];
            if (ACT_SILU) v = siluf(v);
            As[k*68 + m2] = v;
        }
        for (int i=tid; i<32*64; i+=256){
            int k = i>>6, n = i&63;
            Ws[k*68 + n] = W[((size_t)(k0+k))*Nr + col0 + n];
        }
        __syncthreads();
        #pragma unroll 8
        for (int k=0;k<32;++k){
            float4 av = *(const float4*)(&As[k*68 + tr*4]);
            float4 wv = *(const float4*)(&Ws[k*68 + tc*4]);
            float a4[4] = {av.x, av.y, av.z, av.w};
            float w4[4] = {wv.x, wv.y, wv.z, wv.w};
            #pragma unroll
            for (int i=0;i<4;++i)
                #pragma unroll
                for (int j=0;j<4;++j) acc[i][j] += a4[i]*w4[j];
        }
    }
    #pragma unroll
    for (int i=0;i<4;++i){
        int r = row0 + tr*4 + i;
        size_t off = (size_t)r*Nr + col0 + tc*4;
        float4 bv = *(const float4*)(&bias[col0 + tc*4]);
        float4 o = make_float4(acc[i][0]+bv.x, acc[i][1]+bv.y, acc[i][2]+bv.z, acc[i][3]+bv.w);
        if (res){
            float4 rv = *(const float4*)(&res[off]);
            o.x += rv.x; o.y += rv.y; o.z += rv.z; o.w += rv.w;
        }
        *(float4*)(&C[off]) = o;
    }
}

// ---------------- modulated LN + silu ----------------
__global__ __launch_bounds__(256) void lnmod_kernel(
    const float* __restrict__ in, const float* __restrict__ g, const float* __restrict__ bb,
    const float* __restrict__ eo, float* __restrict__ out)
{
    int row = blockIdx.x, tid = threadIdx.x;
    __shared__ float xsr[LATD];
    __shared__ float red[256];
    const float* rp = in + (size_t)row*LATD;
    float s = 0.f;
    for (int i=tid;i<LATD;i+=256){ float v = rp[i]; xsr[i]=v; s+=v; }
    red[tid]=s; __syncthreads();
    for (int k=128;k>0;k>>=1){ if (tid<k) red[tid]+=red[tid+k]; __syncthreads(); }
    float mean = red[0]*(1.0f/LATD);
    __syncthreads();
    float vs=0.f;
    for (int i=tid;i<LATD;i+=256){ float d=xsr[i]-mean; vs+=d*d; }
    red[tid]=vs; __syncthreads();
    for (int k=128;k>0;k>>=1){ if (tid<k) red[tid]+=red[tid+k]; __syncthreads(); }
    float rstd = rsqrtf(red[0]*(1.0f/LATD)+1e-5f);
    const float* ep = eo + (size_t)row*(2*LATD);
    float* op = out + (size_t)row*LATD;
    for (int i=tid;i<LATD;i+=256){
        float v = (xsr[i]-mean)*rstd*g[i] + bb[i];
        v = v*(1.0f + ep[i]) + ep[LATD+i];
        op[i] = siluf(v);
    }
}

extern "C" void kernel_launch(void* const* d_in, const int* in_sizes, int n_in,
                              void* d_out, int out_size, void* d_ws, size_t ws_size,
                              hipStream_t stream)
{
    (void)in_sizes; (void)n_in; (void)out_size; (void)ws_size;
    const float* x     = (const float*)d_in[0];
    const float* emb   = (const float*)d_in[1];
    const int*   smask = (const int*)d_in[2];
    const float* tcond = (const float*)d_in[5];
    const float* two   = (const float*)d_in[6];
    const float* ng    = (const float*)d_in[7];
    const float* nb    = (const float*)d_in[8];
    const float* memb  = (const float*)d_in[9];
    const float* m_wg  = (const float*)d_in[10];
    const float* m_w1  = (const float*)d_in[11];
    const float* m_b1  = (const float*)d_in[12];
    const float* m_w2  = (const float*)d_in[13];
    const float* m_b2  = (const float*)d_in[14];
    const float* m_pw  = (const float*)d_in[15];
    const float* m_pb  = (const float*)d_in[16];
    const float* kms   = (const float*)d_in[17];
    const float* sigma = (const float*)d_in[18];
    const float* kdat  = (const float*)d_in[19];
    const float* kds   = (const float*)d_in[20];
    const float* vdat  = (const float*)d_in[21];
    const float* krot  = (const float*)d_in[22];
    const float* krs   = (const float*)d_in[23];
    const float* vrot  = (const float*)d_in[24];
    const float* ntg   = (const float*)d_in[25];
    const float* ntb   = (const float*)d_in[26];
    const float* c_wg  = (const float*)d_in[27];
    const float* c_w1  = (const float*)d_in[28];
    const float* c_b1  = (const float*)d_in[29];
    const float* c_w2  = (const float*)d_in[30];
    const float* c_b2  = (const float*)d_in[31];
    const float* c_pw  = (const float*)d_in[32];
    const float* c_pb  = (const float*)d_in[33];
    const float* kts   = (const float*)d_in[34];
    const float* st_ew = (const float*)d_in[35];
    const float* st_eb = (const float*)d_in[36];
    const float* st_ng = (const float*)d_in[37];
    const float* st_nb = (const float*)d_in[38];
    const float* st_ow = (const float*)d_in[39];
    const float* st_ob = (const float*)d_in[40];

    float* ws = (float*)d_ws;
    float* xh   = ws;                    // 1310720
    float* qB   = xh  + 1310720;         // 1310720
    float* kmB  = qB  + 1310720;         // 1310720
    float* vmB  = kmB + 1310720;         // 1310720
    float* ctB  = vmB + 1310720;         // 197120
    float* ktB  = ctB + 197120;          // 197120
    float* vtB  = ktB + 197120;          // 197120
    float* aout = vtB + 197120;          // 1310720
    float* eoB  = aout + 1310720;        // 2621440
    float* shB  = eoB + 2621440;         // 1310720

    ln_kernel<<<BB*TT, 256, 0, stream>>>(x, ng, nb, memb, xh, TT);
    ln_kernel<<<BB*MM, 256, 0, stream>>>(two, ntg, ntb, nullptr, ctB, MM);
    moe_kernel<192><<<(BB*TT*HH)/TOKB, 256, 0, stream>>>(
        xh, m_wg, m_w1, m_b1, m_w2, m_b2, m_pw, m_pb, 5*DD, BB*TT*HH, TT, qB, kmB, vmB);
    moe_kernel<128><<<(BB*MM*HH + TOKB - 1)/TOKB, 256, 0, stream>>>(
        ctB, c_wg, c_w1, c_b1, c_w2, c_b2, c_pw, c_pb, 2*DD, BB*MM*HH, MM, ktB, vtB, nullptr);
    attn_kernel<<<BB*HH*16, 256, 0, stream>>>(
        qB, kmB, vmB, ktB, vtB, kdat, vdat, krot, vrot, smask, tcond,
        kms, kds, krs, kts, sigma, aout);
    {
        dim3 g1(2048/64, 1280/64);
        gemm_kernel<true><<<g1, 256, 0, stream>>>(emb, st_ew, st_eb, nullptr, eoB, 2048, 1280, 512);
    }
    lnmod_kernel<<<BB*TT, 256, 0, stream>>>(aout, st_ng, st_nb, eoB, shB);
    {
        dim3 g2(2048/64, 640/64);
        gemm_kernel<false><<<g2, 256, 0, stream>>>(shB, st_ow, st_ob, x, (float*)d_out, 2048, 640, 640);
    }
}

// Round 3
// 701.905 us; speedup vs baseline: 1.7001x; 1.1621x over previous
//
#include <hip/hip_runtime.h>
#include <math.h>

#define BB 4
#define TT 512
#define MM 77
#define HH 10
#define DD 64
#define LATD 640
#define EE 8
#define FFND 256
#define NS 685     // 512 + 48 + 48 + 77
#define NCH 11     // ceil(685/64)

#define NTOK_M (BB*TT*HH)   // 20480
#define NTOK_T (BB*MM*HH)   // 3080
#define MAXB_M 647          // sum_e ceil(c_e/64) <= 40960/64 + 7
#define MAXB_T 103

__device__ __forceinline__ float geluf(float x){
    // tanh-approx gelu with tanh(u) = (e^{2u}-1)/(e^{2u}+1), clamped for overflow
    float u = 0.7978845608028654f*(x + 0.044715f*x*x*x);
    u = fminf(fmaxf(u, -15.f), 15.f);
    float e = __expf(2.f*u);
    return 0.5f*x*(1.f + (e-1.f)/(e+1.f));
}
__device__ __forceinline__ float siluf(float x){
    return x / (1.0f + __expf(-x));
}
__device__ __forceinline__ float dot4f(float4 a, float4 b){
    return a.x*b.x + a.y*b.y + a.z*b.z + a.w*b.w;
}

// ---------------- LayerNorm (rows of 640), optional additive emb (T,640) ----------------
__global__ __launch_bounds__(256) void ln_kernel(
    const float* __restrict__ in, const float* __restrict__ g, const float* __restrict__ bb,
    const float* __restrict__ addv, float* __restrict__ out, int seqLen)
{
    int row = blockIdx.x, tid = threadIdx.x;
    __shared__ float xsr[LATD];
    __shared__ float red[256];
    const float* rp = in + (size_t)row*LATD;
    float s = 0.f;
    for (int i=tid;i<LATD;i+=256){ float v = rp[i]; xsr[i]=v; s+=v; }
    red[tid]=s; __syncthreads();
    for (int k=128;k>0;k>>=1){ if (tid<k) red[tid]+=red[tid+k]; __syncthreads(); }
    float mean = red[0]*(1.0f/LATD);
    __syncthreads();
    float vs=0.f;
    for (int i=tid;i<LATD;i+=256){ float d=xsr[i]-mean; vs+=d*d; }
    red[tid]=vs; __syncthreads();
    for (int k=128;k>0;k>>=1){ if (tid<k) red[tid]+=red[tid+k]; __syncthreads(); }
    float rstd = rsqrtf(red[0]*(1.0f/LATD)+1e-5f);
    int t = row % seqLen;
    const float* ap = addv ? (addv + (size_t)t*LATD) : nullptr;
    float* op = out + (size_t)row*LATD;
    for (int i=tid;i<LATD;i+=256){
        float v = (xsr[i]-mean)*rstd*g[i] + bb[i];
        if (ap) v += ap[i];
        op[i] = v;
    }
}

// ---------------- MoE routing ----------------
__global__ void zero_counts_kernel(int* __restrict__ c){
    if (threadIdx.x < 16) c[threadIdx.x] = 0;
}

__global__ __launch_bounds__(256) void route_kernel(
    const float* __restrict__ xin, const float* __restrict__ wg, int nTok,
    int* __restrict__ counts, int* __restrict__ list, float* __restrict__ wA)
{
    int t = blockIdx.x*256 + threadIdx.x;
    if (t >= nTok) return;
    float lg[EE];
    #pragma unroll
    for (int e=0;e<EE;e++) lg[e]=0.f;
    const float4* xp = (const float4*)(xin + (size_t)t*DD);
    #pragma unroll 4
    for (int dq=0; dq<16; ++dq){
        float4 xv = xp[dq];
        const float* w0 = wg + (dq*4+0)*EE;
        const float* w1 = wg + (dq*4+1)*EE;
        const float* w2 = wg + (dq*4+2)*EE;
        const float* w3 = wg + (dq*4+3)*EE;
        #pragma unroll
        for (int e=0;e<EE;e++)
            lg[e] += xv.x*w0[e] + xv.y*w1[e] + xv.z*w2[e] + xv.w*w3[e];
    }
    float mx = lg[0];
    #pragma unroll
    for (int e=1;e<EE;e++) mx = fmaxf(mx, lg[e]);
    float sum = 0.f;
    #pragma unroll
    for (int e=0;e<EE;e++){ lg[e] = __expf(lg[e]-mx); sum += lg[e]; }
    float inv = 1.0f/sum;
    #pragma unroll
    for (int e=0;e<EE;e++) lg[e] *= inv;
    int e0=0; float v0=lg[0];
    #pragma unroll
    for (int e=1;e<EE;e++){ if (lg[e] > v0){ v0 = lg[e]; e0 = e; } }
    int e1=-1; float v1=-1e30f;
    #pragma unroll
    for (int e=0;e<EE;e++){ if (e==e0) continue; if (lg[e] > v1){ v1 = lg[e]; e1 = e; } }
    wA[t*2+0]=v0; wA[t*2+1]=v1;
    int p0 = atomicAdd(&counts[e0],1); list[(size_t)e0*nTok + p0] = t*2;
    int p1 = atomicAdd(&counts[e1],1); list[(size_t)e1*nTok + p1] = t*2+1;
}

// ---------------- grouped expert FFN: block = (expert, 64-token tile) ----------------
__global__ __launch_bounds__(256) void moe_ffn_kernel(
    const float* __restrict__ xin,
    const float* __restrict__ w1g,   // (E,64,256)
    const float* __restrict__ b1g,   // (E,256)
    const float* __restrict__ w2g,   // (E,256,64)
    const float* __restrict__ b2g,   // (E,64)
    const int* __restrict__ counts, const int* __restrict__ list,
    const float* __restrict__ wA, int nTok,
    float* __restrict__ yslot)       // (nTok,2,64)
{
    __shared__ __align__(16) float xs_t[DD][68];  // [d][token]
    __shared__ __align__(16) float hs[64][68];    // [token][f within chunk]
    __shared__ int sCnt[EE];
    __shared__ int encs[64];
    __shared__ float wgts[64];
    const int tid = threadIdx.x;
    if (tid < EE) sCnt[tid] = counts[tid];
    __syncthreads();
    int e = -1, tile = 0;
    {
        int acc = 0, bid = blockIdx.x;
        #pragma unroll
        for (int i=0;i<EE;++i){
            int tc = (sCnt[i]+63)>>6;
            if (e < 0 && bid < acc + tc){ e = i; tile = bid - acc; }
            acc += tc;
        }
    }
    if (e < 0) return;
    const int cnt = sCnt[e];
    if (tid < 64){
        int idx = tile*64 + tid;
        int enc = (idx < cnt) ? list[(size_t)e*nTok + idx] : -1;
        encs[tid] = enc;
        wgts[tid] = (enc >= 0) ? wA[enc] : 0.f;
    }
    __syncthreads();
    // stage x transposed
    for (int i=tid; i<64*16; i+=256){
        int c = i>>4, dq = i&15;
        int enc = encs[c];
        float4 xv = make_float4(0.f,0.f,0.f,0.f);
        if (enc >= 0) xv = *(const float4*)(xin + (size_t)(enc>>1)*DD + dq*4);
        xs_t[dq*4+0][c]=xv.x; xs_t[dq*4+1][c]=xv.y; xs_t[dq*4+2][c]=xv.z; xs_t[dq*4+3][c]=xv.w;
    }
    __syncthreads();

    const int tf = tid & 15;   // f-quad / d-quad
    const int tm = tid >> 4;   // token-quad (0..15)
    float yacc[4][4] = {};
    const float* w1e = w1g + (size_t)e*DD*FFND;
    const float* w2e = w2g + (size_t)e*FFND*DD;

    for (int fc=0; fc<4; ++fc){
        // GEMM1 chunk: h[64 tok][64 f] = x @ w1[:, fc*64:...]
        float acc1[4][4] = {};
        #pragma unroll 8
        for (int d=0; d<DD; ++d){
            float4 wv = *(const float4*)(w1e + d*FFND + fc*64 + tf*4);
            float4 xv = *(const float4*)(&xs_t[d][tm*4]);
            float xa[4] = {xv.x, xv.y, xv.z, xv.w};
            #pragma unroll
            for (int u=0;u<4;++u){
                acc1[u][0] += xa[u]*wv.x;
                acc1[u][1] += xa[u]*wv.y;
                acc1[u][2] += xa[u]*wv.z;
                acc1[u][3] += xa[u]*wv.w;
            }
        }
        float4 b1v = *(const float4*)(b1g + e*FFND + fc*64 + tf*4);
        #pragma unroll
        for (int u=0;u<4;++u){
            float4 hv;
            hv.x = geluf(acc1[u][0]+b1v.x);
            hv.y = geluf(acc1[u][1]+b1v.y);
            hv.z = geluf(acc1[u][2]+b1v.z);
            hv.w = geluf(acc1[u][3]+b1v.w);
            *(float4*)(&hs[tm*4+u][tf*4]) = hv;
        }
        __syncthreads();
        // GEMM2 chunk: y[64 tok][64 d] += h_chunk @ w2[fc*64:...,:]
        #pragma unroll 8
        for (int fp=0; fp<64; ++fp){
            float4 wv = *(const float4*)(w2e + (size_t)(fc*64+fp)*DD + tf*4);
            float hv0 = hs[tm*4+0][fp];
            float hv1 = hs[tm*4+1][fp];
            float hv2 = hs[tm*4+2][fp];
            float hv3 = hs[tm*4+3][fp];
            yacc[0][0]+=hv0*wv.x; yacc[0][1]+=hv0*wv.y; yacc[0][2]+=hv0*wv.z; yacc[0][3]+=hv0*wv.w;
            yacc[1][0]+=hv1*wv.x; yacc[1][1]+=hv1*wv.y; yacc[1][2]+=hv1*wv.z; yacc[1][3]+=hv1*wv.w;
            yacc[2][0]+=hv2*wv.x; yacc[2][1]+=hv2*wv.y; yacc[2][2]+=hv2*wv.z; yacc[2][3]+=hv2*wv.w;
            yacc[3][0]+=hv3*wv.x; yacc[3][1]+=hv3*wv.y; yacc[3][2]+=hv3*wv.z; yacc[3][3]+=hv3*wv.w;
        }
        __syncthreads();
    }
    float4 b2v = *(const float4*)(b2g + e*DD + tf*4);
    #pragma unroll
    for (int u=0;u<4;++u){
        int enc = encs[tm*4+u];
        if (enc >= 0){
            float w = wgts[tm*4+u];
            float4 o;
            o.x = w*(yacc[u][0]+b2v.x);
            o.y = w*(yacc[u][1]+b2v.y);
            o.z = w*(yacc[u][2]+b2v.z);
            o.w = w*(yacc[u][3]+b2v.w);
            *(float4*)(yslot + (size_t)enc*DD + tf*4) = o;
        }
    }
}

// ---------------- combine slots + gelu + projection + scatter ----------------
template<int NPROJ>
__global__ __launch_bounds__(256) void moe_proj_kernel(
    const float* __restrict__ yslot, const float* __restrict__ pwg, const float* __restrict__ pbg,
    int pwld, int nTok, int seqLen,
    float* __restrict__ out0, float* __restrict__ out1, float* __restrict__ out2)
{
    __shared__ __align__(16) float gs[64][68];
    __shared__ __align__(16) float wb[NPROJ*68];
    int tid = threadIdx.x;
    int base = blockIdx.x*64;
    for (int i=tid; i<64*16; i+=256){
        int c = i>>4, dq = i&15;
        int tok = base + c;
        float4 g4 = make_float4(0.f,0.f,0.f,0.f);
        if (tok < nTok){
            float4 a = *(const float4*)(yslot + (size_t)tok*128 + dq*4);
            float4 b = *(const float4*)(yslot + (size_t)tok*128 + 64 + dq*4);
            g4.x = geluf(a.x+b.x); g4.y = geluf(a.y+b.y);
            g4.z = geluf(a.z+b.z); g4.w = geluf(a.w+b.w);
        }
        *(float4*)(&gs[c][dq*4]) = g4;
    }
    for (int i=tid; i<DD*NPROJ; i+=256){
        int d = i / NPROJ, j = i % NPROJ;
        wb[j*68+d] = pwg[(size_t)d*pwld + j];
    }
    __syncthreads();
    for (int o=tid; o<64*NPROJ; o+=256){
        int c = o / NPROJ, j = o % NPROJ;
        int n = base + c;
        if (n >= nTok) continue;
        float acc = pbg[j];
        const float4* gp = (const float4*)(&gs[c][0]);
        const float4* wp = (const float4*)(&wb[j*68]);
        #pragma unroll
        for (int dq=0; dq<16; ++dq) acc += dot4f(gp[dq], wp[dq]);
        int b = n / (seqLen*HH);
        int r = n % (seqLen*HH);
        int sr = r / HH, h = r % HH;
        int bufi = j >> 6, jd = j & 63;
        float* dst = (bufi==0) ? out0 : (bufi==1) ? out1 : out2;
        dst[(((size_t)b*HH + h)*seqLen + sr)*DD + jd] = acc;
    }
}

// ---------------- Flash attention: per (b,h,32-row t-tile), online softmax ----------------
__global__ __launch_bounds__(256) void attn_kernel(
    const float* __restrict__ qb,   // (B,H,T,64)
    const float* __restrict__ kmb,  // (B,H,T,64)
    const float* __restrict__ vmb,
    const float* __restrict__ ktb,  // (B,H,M,64)
    const float* __restrict__ vtb,
    const float* __restrict__ kd,   // (NDS,48,H,64) -> [0]
    const float* __restrict__ vd,
    const float* __restrict__ kr,   // (48,H,64)
    const float* __restrict__ vr,
    const int*   __restrict__ smask, // (B,T)
    const float* __restrict__ tcond, // (B,1)
    const float* __restrict__ kms_p, const float* __restrict__ kds_p,
    const float* __restrict__ krs_p, const float* __restrict__ kts_p,
    const float* __restrict__ sigma_p,
    float* __restrict__ outb)        // (B,T,640)
{
    __shared__ __align__(16) float qs[32*68];
    __shared__ __align__(16) float ks[64*68];
    __shared__ __align__(16) float vs[64*68];
    __shared__ __align__(16) float ps_l[32*68];
    __shared__ float madd[64];

    int tid = threadIdx.x;
    int bid = blockIdx.x;
    int ttile = bid & 15;
    int bh = bid >> 4;
    int b = bh / HH, h = bh % HH;
    int t0 = ttile * 32;
    const float sc = 0.125f;
    float kms = kms_p[0]*sc, kds = kds_p[0]*sc, krs = krs_p[0]*sc, kts = kts_p[0]*sc;
    float sg = sigma_p[0];
    float inv2s = 1.0f/(2.0f*sg*sg);
    bool text_on = tcond[b] > 0.f;

    const float* qsrc = qb + (((size_t)bh)*TT + t0)*DD;
    for (int i=tid; i<32*16; i+=256){
        int r = i>>4, dq = i&15;
        *(float4*)(&qs[r*68+dq*4]) = *(const float4*)(&qsrc[r*64+dq*4]);
    }
    int tp = tid >> 4;   // 0..15 -> rows tp*2, tp*2+1
    int sq = tid & 15;   // 0..15

    float m_r[2] = {-1e30f, -1e30f};
    float l_r[2] = {0.f, 0.f};
    float oacc[2][4] = {};

    for (int ch=0; ch<NCH; ++ch){
        __syncthreads();
        for (int i=tid; i<64*16; i+=256){
            int r = i>>4, dq = i&15;
            int s = ch*64 + r;
            float4 kv = make_float4(0,0,0,0), vv = make_float4(0,0,0,0);
            if (s < TT){
                kv = *(const float4*)(&kmb[(((size_t)bh)*TT + s)*DD + dq*4]);
                kv.x*=kms; kv.y*=kms; kv.z*=kms; kv.w*=kms;
                vv = *(const float4*)(&vmb[(((size_t)bh)*TT + s)*DD + dq*4]);
            } else if (s < TT+48){
                kv = *(const float4*)(&kd[((size_t)(s-TT)*HH + h)*DD + dq*4]);
                kv.x*=kds; kv.y*=kds; kv.z*=kds; kv.w*=kds;
                vv = *(const float4*)(&vd[((size_t)(s-TT)*HH + h)*DD + dq*4]);
            } else if (s < TT+96){
                kv = *(const float4*)(&kr[((size_t)(s-TT-48)*HH + h)*DD + dq*4]);
                kv.x*=krs; kv.y*=krs; kv.z*=krs; kv.w*=krs;
                vv = *(const float4*)(&vr[((size_t)(s-TT-48)*HH + h)*DD + dq*4]);
            } else if (s < NS){
                kv = *(const float4*)(&ktb[(((size_t)bh)*MM + (s-TT-96))*DD + dq*4]);
                kv.x*=kts; kv.y*=kts; kv.z*=kts; kv.w*=kts;
                vv = *(const float4*)(&vtb[(((size_t)bh)*MM + (s-TT-96))*DD + dq*4]);
            }
            *(float4*)(&ks[r*68+dq*4]) = kv;
            *(float4*)(&vs[r*68+dq*4]) = vv;
        }
        if (tid < 64){
            int s = ch*64 + tid;
            float a;
            if (s < TT)            a = (smask[b*TT + s] == 0) ? -1e9f : 0.f;
            else if (s < TT+96)    a = 0.f;
            else if (s < NS)       a = text_on ? 0.f : -1e9f;
            else                   a = -1e30f;
            madd[tid] = a;
        }
        __syncthreads();

        float acc[2][4] = {};
        const float4* q0 = (const float4*)(&qs[(tp*2+0)*68]);
        const float4* q1 = (const float4*)(&qs[(tp*2+1)*68]);
        #pragma unroll 4
        for (int dq=0; dq<16; ++dq){
            float4 qa = q0[dq], qb4 = q1[dq];
            #pragma unroll
            for (int j=0;j<4;++j){
                float4 kv = *(const float4*)(&ks[(sq + 16*j)*68 + dq*4]);
                acc[0][j] += dot4f(qa, kv);
                acc[1][j] += dot4f(qb4, kv);
            }
        }
        #pragma unroll
        for (int i=0;i<2;++i){
            int t = t0 + tp*2 + i;
            #pragma unroll
            for (int j=0;j<4;++j){
                int sl = sq + 16*j;
                int s = ch*64 + sl;
                float a = madd[sl];
                if (s < TT){ float dt = (float)(t - s); a -= dt*dt*inv2s; }
                acc[i][j] += a;
            }
        }
        float pm[2], mn[2], scl[2], ps[2];
        #pragma unroll
        for (int i=0;i<2;++i)
            pm[i] = fmaxf(fmaxf(acc[i][0], acc[i][1]), fmaxf(acc[i][2], acc[i][3]));
        #pragma unroll
        for (int m2=1; m2<16; m2<<=1){
            pm[0] = fmaxf(pm[0], __shfl_xor(pm[0], m2));
            pm[1] = fmaxf(pm[1], __shfl_xor(pm[1], m2));
        }
        #pragma unroll
        for (int i=0;i<2;++i){
            mn[i] = fmaxf(m_r[i], pm[i]);
            scl[i] = __expf(m_r[i] - mn[i]);
            m_r[i] = mn[i];
            ps[i] = 0.f;
            #pragma unroll
            for (int j=0;j<4;++j){
                acc[i][j] = __expf(acc[i][j] - mn[i]);
                ps[i] += acc[i][j];
            }
        }
        #pragma unroll
        for (int m2=1; m2<16; m2<<=1){
            ps[0] += __shfl_xor(ps[0], m2);
            ps[1] += __shfl_xor(ps[1], m2);
        }
        #pragma unroll
        for (int i=0;i<2;++i){
            l_r[i] = l_r[i]*scl[i] + ps[i];
            #pragma unroll
            for (int j=0;j<4;++j) oacc[i][j] *= scl[i];
        }
        #pragma unroll
        for (int i=0;i<2;++i)
            #pragma unroll
            for (int j=0;j<4;++j)
                ps_l[(tp*2+i)*68 + sq + 16*j] = acc[i][j];
        __syncthreads();
        const float* p0r = &ps_l[(tp*2+0)*68];
        const float* p1r = &ps_l[(tp*2+1)*68];
        #pragma unroll 8
        for (int sl=0; sl<64; ++sl){
            float p0 = p0r[sl], p1 = p1r[sl];
            float4 vv = *(const float4*)(&vs[sl*68 + sq*4]);
            oacc[0][0] += p0*vv.x; oacc[0][1] += p0*vv.y; oacc[0][2] += p0*vv.z; oacc[0][3] += p0*vv.w;
            oacc[1][0] += p1*vv.x; oacc[1][1] += p1*vv.y; oacc[1][2] += p1*vv.z; oacc[1][3] += p1*vv.w;
        }
    }
    #pragma unroll
    for (int i=0;i<2;++i){
        int t = t0 + tp*2 + i;
        float inv = 1.0f / l_r[i];
        float4 o4 = make_float4(oacc[i][0]*inv, oacc[i][1]*inv, oacc[i][2]*inv, oacc[i][3]*inv);
        *(float4*)(&outb[((size_t)(b*TT + t))*LATD + h*64 + sq*4]) = o4;
    }
}

// ---------------- generic tiled GEMM: C = act(A) @ W + bias (+res) ----------------
template<bool ACT_SILU>
__global__ __launch_bounds__(256) void gemm_kernel(
    const float* __restrict__ A, const float* __restrict__ W,
    const float* __restrict__ bias, const float* __restrict__ res,
    float* __restrict__ C, int Mr, int Nr, int Kr)
{
    __shared__ __align__(16) float As[32*68];   // [k][m]
    __shared__ __align__(16) float Ws[32*68];   // [k][n]
    int tid = threadIdx.x;
    int row0 = blockIdx.x*64, col0 = blockIdx.y*64;
    int tr = tid >> 4, tc = tid & 15;
    float acc[4][4] = {};
    for (int k0=0; k0<Kr; k0+=32){
        __syncthreads();
        for (int i=tid; i<64*32; i+=256){
            int m2 = i>>5, k = i&31;
            float v = A[((size_t)(row0+m2))*Kr + k0 + k];
            if (ACT_SILU) v = siluf(v);
            As[k*68 + m2] = v;
        }
        for (int i=tid; i<32*64; i+=256){
            int k = i>>6, n = i&63;
            Ws[k*68 + n] = W[((size_t)(k0+k))*Nr + col0 + n];
        }
        __syncthreads();
        #pragma unroll 8
        for (int k=0;k<32;++k){
            float4 av = *(const float4*)(&As[k*68 + tr*4]);
            float4 wv = *(const float4*)(&Ws[k*68 + tc*4]);
            float a4[4] = {av.x, av.y, av.z, av.w};
            float w4[4] = {wv.x, wv.y, wv.z, wv.w};
            #pragma unroll
            for (int i=0;i<4;++i)
                #pragma unroll
                for (int j=0;j<4;++j) acc[i][j] += a4[i]*w4[j];
        }
    }
    #pragma unroll
    for (int i=0;i<4;++i){
        int r = row0 + tr*4 + i;
        size_t off = (size_t)r*Nr + col0 + tc*4;
        float4 bv = *(const float4*)(&bias[col0 + tc*4]);
        float4 o = make_float4(acc[i][0]+bv.x, acc[i][1]+bv.y, acc[i][2]+bv.z, acc[i][3]+bv.w);
        if (res){
            float4 rv = *(const float4*)(&res[off]);
            o.x += rv.x; o.y += rv.y; o.z += rv.z; o.w += rv.w;
        }
        *(float4*)(&C[off]) = o;
    }
}

// ---------------- modulated LN + silu ----------------
__global__ __launch_bounds__(256) void lnmod_kernel(
    const float* __restrict__ in, const float* __restrict__ g, const float* __restrict__ bb,
    const float* __restrict__ eo, float* __restrict__ out)
{
    int row = blockIdx.x, tid = threadIdx.x;
    __shared__ float xsr[LATD];
    __shared__ float red[256];
    const float* rp = in + (size_t)row*LATD;
    float s = 0.f;
    for (int i=tid;i<LATD;i+=256){ float v = rp[i]; xsr[i]=v; s+=v; }
    red[tid]=s; __syncthreads();
    for (int k=128;k>0;k>>=1){ if (tid<k) red[tid]+=red[tid+k]; __syncthreads(); }
    float mean = red[0]*(1.0f/LATD);
    __syncthreads();
    float vs=0.f;
    for (int i=tid;i<LATD;i+=256){ float d=xsr[i]-mean; vs+=d*d; }
    red[tid]=vs; __syncthreads();
    for (int k=128;k>0;k>>=1){ if (tid<k) red[tid]+=red[tid+k]; __syncthreads(); }
    float rstd = rsqrtf(red[0]*(1.0f/LATD)+1e-5f);
    const float* ep = eo + (size_t)row*(2*LATD);
    float* op = out + (size_t)row*LATD;
    for (int i=tid;i<LATD;i+=256){
        float v = (xsr[i]-mean)*rstd*g[i] + bb[i];
        v = v*(1.0f + ep[i]) + ep[LATD+i];
        op[i] = siluf(v);
    }
}

extern "C" void kernel_launch(void* const* d_in, const int* in_sizes, int n_in,
                              void* d_out, int out_size, void* d_ws, size_t ws_size,
                              hipStream_t stream)
{
    (void)in_sizes; (void)n_in; (void)out_size; (void)ws_size;
    const float* x     = (const float*)d_in[0];
    const float* emb   = (const float*)d_in[1];
    const int*   smask = (const int*)d_in[2];
    const float* tcond = (const float*)d_in[5];
    const float* two   = (const float*)d_in[6];
    const float* ng    = (const float*)d_in[7];
    const float* nb    = (const float*)d_in[8];
    const float* memb  = (const float*)d_in[9];
    const float* m_wg  = (const float*)d_in[10];
    const float* m_w1  = (const float*)d_in[11];
    const float* m_b1  = (const float*)d_in[12];
    const float* m_w2  = (const float*)d_in[13];
    const float* m_b2  = (const float*)d_in[14];
    const float* m_pw  = (const float*)d_in[15];
    const float* m_pb  = (const float*)d_in[16];
    const float* kms   = (const float*)d_in[17];
    const float* sigma = (const float*)d_in[18];
    const float* kdat  = (const float*)d_in[19];
    const float* kds   = (const float*)d_in[20];
    const float* vdat  = (const float*)d_in[21];
    const float* krot  = (const float*)d_in[22];
    const float* krs   = (const float*)d_in[23];
    const float* vrot  = (const float*)d_in[24];
    const float* ntg   = (const float*)d_in[25];
    const float* ntb   = (const float*)d_in[26];
    const float* c_wg  = (const float*)d_in[27];
    const float* c_w1  = (const float*)d_in[28];
    const float* c_b1  = (const float*)d_in[29];
    const float* c_w2  = (const float*)d_in[30];
    const float* c_b2  = (const float*)d_in[31];
    const float* c_pw  = (const float*)d_in[32];
    const float* c_pb  = (const float*)d_in[33];
    const float* kts   = (const float*)d_in[34];
    const float* st_ew = (const float*)d_in[35];
    const float* st_eb = (const float*)d_in[36];
    const float* st_ng = (const float*)d_in[37];
    const float* st_nb = (const float*)d_in[38];
    const float* st_ow = (const float*)d_in[39];
    const float* st_ob = (const float*)d_in[40];

    float* ws = (float*)d_ws;
    float* xh   = ws;                    // 1310720
    float* qB   = xh  + 1310720;         // 1310720
    float* kmB  = qB  + 1310720;         // 1310720
    float* vmB  = kmB + 1310720;         // 1310720
    float* ctB  = vmB + 1310720;         // 197120
    float* ktB  = ctB + 197120;          // 197120
    float* vtB  = ktB + 197120;          // 197120
    float* aout = vtB + 197120;          // 1310720
    float* eoB  = aout + 1310720;        // 2621440
    float* shB  = eoB + 2621440;         // 1310720

    // aliases (safe by stream order):
    float* yslotM = eoB;                 // 20480*128 = 2621440 (dead until gemm<true>)
    float* yslotT = shB;                 // 3080*128  = 394240  (dead until lnmod)
    // routing scratch inside aout (dead until attn writes it):
    float* wAm   = aout;                       // 40960
    float* wAt   = wAm + NTOK_M*2;             // 6160
    int*   cntA  = (int*)(wAt + NTOK_T*2);     // 16 ints (motion: [0..8), text: [8..16))
    int*   listM = cntA + 16;                  // 8*20480
    int*   listT = listM + EE*NTOK_M;          // 8*3080

    // 1. LN(x)+moe_emb -> xh ; LN(text) -> ctB
    ln_kernel<<<BB*TT, 256, 0, stream>>>(x, ng, nb, memb, xh, TT);
    ln_kernel<<<BB*MM, 256, 0, stream>>>(two, ntg, ntb, nullptr, ctB, MM);
    // 2. MoE: route -> grouped FFN -> combine+proj
    zero_counts_kernel<<<1, 64, 0, stream>>>(cntA);
    route_kernel<<<(NTOK_M+255)/256, 256, 0, stream>>>(xh, m_wg, NTOK_M, cntA, listM, wAm);
    route_kernel<<<(NTOK_T+255)/256, 256, 0, stream>>>(ctB, c_wg, NTOK_T, cntA+8, listT, wAt);
    moe_ffn_kernel<<<MAXB_M, 256, 0, stream>>>(
        xh, m_w1, m_b1, m_w2, m_b2, cntA, listM, wAm, NTOK_M, yslotM);
    moe_ffn_kernel<<<MAXB_T, 256, 0, stream>>>(
        ctB, c_w1, c_b1, c_w2, c_b2, cntA+8, listT, wAt, NTOK_T, yslotT);
    moe_proj_kernel<192><<<(NTOK_M+63)/64, 256, 0, stream>>>(
        yslotM, m_pw, m_pb, 5*DD, NTOK_M, TT, qB, kmB, vmB);
    moe_proj_kernel<128><<<(NTOK_T+63)/64, 256, 0, stream>>>(
        yslotT, c_pw, c_pb, 2*DD, NTOK_T, MM, ktB, vtB, nullptr);
    // 3. attention
    attn_kernel<<<BB*HH*16, 256, 0, stream>>>(
        qB, kmB, vmB, ktB, vtB, kdat, vdat, krot, vrot, smask, tcond,
        kms, kds, krs, kts, sigma, aout);
    // 4. eo = silu(emb) @ st_emb_w + st_emb_b
    {
        dim3 g1(2048/64, 1280/64);
        gemm_kernel<true><<<g1, 256, 0, stream>>>(emb, st_ew, st_eb, nullptr, eoB, 2048, 1280, 512);
    }
    // 5. sh = silu(LN(aout)*(1+eo[:640]) + eo[640:])
    lnmod_kernel<<<BB*TT, 256, 0, stream>>>(aout, st_ng, st_nb, eoB, shB);
    // 6. out = x + sh @ st_out_w + st_out_b
    {
        dim3 g2(2048/64, 640/64);
        gemm_kernel<false><<<g2, 256, 0, stream>>>(shB, st_ow, st_ob, x, (float*)d_out, 2048, 640, 640);
    }
}

// Round 4
// 529.844 us; speedup vs baseline: 2.2522x; 1.3247x over previous
//
#include <hip/hip_runtime.h>
#include <math.h>

#define BB 4
#define TT 512
#define MM 77
#define HH 10
#define DD 64
#define LATD 640
#define EE 8
#define FFND 256
#define NS 685     // 512 + 48 + 48 + 77
#define NCH 11     // ceil(685/64)

#define NTOK_M (BB*TT*HH)   // 20480
#define NTOK_T (BB*MM*HH)   // 3080
#define MAXB_M 647          // sum_e ceil(c_e/64) <= 40960/64 + 7
#define MAXB_T 103

__device__ __forceinline__ float geluf(float x){
    float u = 0.7978845608028654f*(x + 0.044715f*x*x*x);
    u = fminf(fmaxf(u, -15.f), 15.f);
    float e = __expf(2.f*u);
    return 0.5f*x*(1.f + (e-1.f)/(e+1.f));
}
__device__ __forceinline__ float siluf(float x){
    return x / (1.0f + __expf(-x));
}
__device__ __forceinline__ float dot4f(float4 a, float4 b){
    return a.x*b.x + a.y*b.y + a.z*b.z + a.w*b.w;
}

// ---------------- LayerNorm (rows of 640), optional additive emb (T,640) ----------------
__global__ __launch_bounds__(256) void ln_kernel(
    const float* __restrict__ in, const float* __restrict__ g, const float* __restrict__ bb,
    const float* __restrict__ addv, float* __restrict__ out, int seqLen)
{
    int row = blockIdx.x, tid = threadIdx.x;
    __shared__ float xsr[LATD];
    __shared__ float red[256];
    const float* rp = in + (size_t)row*LATD;
    float s = 0.f;
    for (int i=tid;i<LATD;i+=256){ float v = rp[i]; xsr[i]=v; s+=v; }
    red[tid]=s; __syncthreads();
    for (int k=128;k>0;k>>=1){ if (tid<k) red[tid]+=red[tid+k]; __syncthreads(); }
    float mean = red[0]*(1.0f/LATD);
    __syncthreads();
    float vs=0.f;
    for (int i=tid;i<LATD;i+=256){ float d=xsr[i]-mean; vs+=d*d; }
    red[tid]=vs; __syncthreads();
    for (int k=128;k>0;k>>=1){ if (tid<k) red[tid]+=red[tid+k]; __syncthreads(); }
    float rstd = rsqrtf(red[0]*(1.0f/LATD)+1e-5f);
    int t = row % seqLen;
    const float* ap = addv ? (addv + (size_t)t*LATD) : nullptr;
    float* op = out + (size_t)row*LATD;
    for (int i=tid;i<LATD;i+=256){
        float v = (xsr[i]-mean)*rstd*g[i] + bb[i];
        if (ap) v += ap[i];
        op[i] = v;
    }
}

// ---------------- MoE routing (block-aggregated atomics) ----------------
__global__ void zero_counts_kernel(int* __restrict__ c){
    if (threadIdx.x < 16) c[threadIdx.x] = 0;
}

__global__ __launch_bounds__(256) void route_kernel(
    const float* __restrict__ xin, const float* __restrict__ wg, int nTok,
    int* __restrict__ counts, int* __restrict__ list, float* __restrict__ wA)
{
    __shared__ int bcnt[EE];
    __shared__ int bbase[EE];
    const int tid = threadIdx.x;
    const int t = blockIdx.x*256 + tid;
    if (tid < EE) bcnt[tid] = 0;
    __syncthreads();

    int e0 = 0, e1 = 0, p0 = 0, p1 = 0;
    bool act = (t < nTok);
    if (act){
        float lg[EE];
        #pragma unroll
        for (int e=0;e<EE;e++) lg[e]=0.f;
        const float4* xp = (const float4*)(xin + (size_t)t*DD);
        #pragma unroll 4
        for (int dq=0; dq<16; ++dq){
            float4 xv = xp[dq];
            const float* w0 = wg + (dq*4+0)*EE;
            const float* w1 = wg + (dq*4+1)*EE;
            const float* w2 = wg + (dq*4+2)*EE;
            const float* w3 = wg + (dq*4+3)*EE;
            #pragma unroll
            for (int e=0;e<EE;e++)
                lg[e] += xv.x*w0[e] + xv.y*w1[e] + xv.z*w2[e] + xv.w*w3[e];
        }
        float mx = lg[0];
        #pragma unroll
        for (int e=1;e<EE;e++) mx = fmaxf(mx, lg[e]);
        float sum = 0.f;
        #pragma unroll
        for (int e=0;e<EE;e++){ lg[e] = __expf(lg[e]-mx); sum += lg[e]; }
        float inv = 1.0f/sum;
        #pragma unroll
        for (int e=0;e<EE;e++) lg[e] *= inv;
        float v0=lg[0];
        #pragma unroll
        for (int e=1;e<EE;e++){ if (lg[e] > v0){ v0 = lg[e]; e0 = e; } }
        float v1=-1e30f; e1 = (e0==0) ? 1 : 0;
        #pragma unroll
        for (int e=0;e<EE;e++){ if (e==e0) continue; if (lg[e] > v1){ v1 = lg[e]; e1 = e; } }
        wA[t*2+0]=v0; wA[t*2+1]=v1;
        p0 = atomicAdd(&bcnt[e0], 1);
        p1 = atomicAdd(&bcnt[e1], 1);
    }
    __syncthreads();
    if (tid < EE){
        bbase[tid] = (bcnt[tid] > 0) ? atomicAdd(&counts[tid], bcnt[tid]) : 0;
    }
    __syncthreads();
    if (act){
        list[(size_t)e0*nTok + bbase[e0] + p0] = t*2;
        list[(size_t)e1*nTok + bbase[e1] + p1] = t*2+1;
    }
}

// ---------------- grouped expert FFN: block = (expert, 64-token tile) ----------------
__global__ __launch_bounds__(256) void moe_ffn_kernel(
    const float* __restrict__ xin,
    const float* __restrict__ w1g,   // (E,64,256)
    const float* __restrict__ b1g,   // (E,256)
    const float* __restrict__ w2g,   // (E,256,64)
    const float* __restrict__ b2g,   // (E,64)
    const int* __restrict__ counts, const int* __restrict__ list,
    const float* __restrict__ wA, int nTok,
    float* __restrict__ yslot)       // (nTok,2,64)
{
    __shared__ __align__(16) float xs_t[DD][68];  // [d][token]
    __shared__ __align__(16) float hs[64][68];    // [token][f within chunk]
    __shared__ int sCnt[EE];
    __shared__ int encs[64];
    __shared__ float wgts[64];
    const int tid = threadIdx.x;
    if (tid < EE) sCnt[tid] = counts[tid];
    __syncthreads();
    int e = -1, tile = 0;
    {
        int acc = 0, bid = blockIdx.x;
        #pragma unroll
        for (int i=0;i<EE;++i){
            int tc = (sCnt[i]+63)>>6;
            if (e < 0 && bid < acc + tc){ e = i; tile = bid - acc; }
            acc += tc;
        }
    }
    if (e < 0) return;
    const int cnt = sCnt[e];
    if (tid < 64){
        int idx = tile*64 + tid;
        int enc = (idx < cnt) ? list[(size_t)e*nTok + idx] : -1;
        encs[tid] = enc;
        wgts[tid] = (enc >= 0) ? wA[enc] : 0.f;
    }
    __syncthreads();
    for (int i=tid; i<64*16; i+=256){
        int c = i>>4, dq = i&15;
        int enc = encs[c];
        float4 xv = make_float4(0.f,0.f,0.f,0.f);
        if (enc >= 0) xv = *(const float4*)(xin + (size_t)(enc>>1)*DD + dq*4);
        xs_t[dq*4+0][c]=xv.x; xs_t[dq*4+1][c]=xv.y; xs_t[dq*4+2][c]=xv.z; xs_t[dq*4+3][c]=xv.w;
    }
    __syncthreads();

    const int tf = tid & 15;   // f-quad / d-quad
    const int tm = tid >> 4;   // token-quad (0..15)
    float yacc[4][4] = {};
    const float* w1e = w1g + (size_t)e*DD*FFND;
    const float* w2e = w2g + (size_t)e*FFND*DD;

    for (int fc=0; fc<4; ++fc){
        float acc1[4][4] = {};
        #pragma unroll 8
        for (int d=0; d<DD; ++d){
            float4 wv = *(const float4*)(w1e + d*FFND + fc*64 + tf*4);
            float4 xv = *(const float4*)(&xs_t[d][tm*4]);
            float xa[4] = {xv.x, xv.y, xv.z, xv.w};
            #pragma unroll
            for (int u=0;u<4;++u){
                acc1[u][0] += xa[u]*wv.x;
                acc1[u][1] += xa[u]*wv.y;
                acc1[u][2] += xa[u]*wv.z;
                acc1[u][3] += xa[u]*wv.w;
            }
        }
        float4 b1v = *(const float4*)(b1g + e*FFND + fc*64 + tf*4);
        #pragma unroll
        for (int u=0;u<4;++u){
            float4 hv;
            hv.x = geluf(acc1[u][0]+b1v.x);
            hv.y = geluf(acc1[u][1]+b1v.y);
            hv.z = geluf(acc1[u][2]+b1v.z);
            hv.w = geluf(acc1[u][3]+b1v.w);
            *(float4*)(&hs[tm*4+u][tf*4]) = hv;
        }
        __syncthreads();
        #pragma unroll 8
        for (int fp=0; fp<64; ++fp){
            float4 wv = *(const float4*)(w2e + (size_t)(fc*64+fp)*DD + tf*4);
            float hv0 = hs[tm*4+0][fp];
            float hv1 = hs[tm*4+1][fp];
            float hv2 = hs[tm*4+2][fp];
            float hv3 = hs[tm*4+3][fp];
            yacc[0][0]+=hv0*wv.x; yacc[0][1]+=hv0*wv.y; yacc[0][2]+=hv0*wv.z; yacc[0][3]+=hv0*wv.w;
            yacc[1][0]+=hv1*wv.x; yacc[1][1]+=hv1*wv.y; yacc[1][2]+=hv1*wv.z; yacc[1][3]+=hv1*wv.w;
            yacc[2][0]+=hv2*wv.x; yacc[2][1]+=hv2*wv.y; yacc[2][2]+=hv2*wv.z; yacc[2][3]+=hv2*wv.w;
            yacc[3][0]+=hv3*wv.x; yacc[3][1]+=hv3*wv.y; yacc[3][2]+=hv3*wv.z; yacc[3][3]+=hv3*wv.w;
        }
        __syncthreads();
    }
    float4 b2v = *(const float4*)(b2g + e*DD + tf*4);
    #pragma unroll
    for (int u=0;u<4;++u){
        int enc = encs[tm*4+u];
        if (enc >= 0){
            float w = wgts[tm*4+u];
            float4 o;
            o.x = w*(yacc[u][0]+b2v.x);
            o.y = w*(yacc[u][1]+b2v.y);
            o.z = w*(yacc[u][2]+b2v.z);
            o.w = w*(yacc[u][3]+b2v.w);
            *(float4*)(yslot + (size_t)enc*DD + tf*4) = o;
        }
    }
}

// ---------------- combine slots + gelu + projection + scatter ----------------
template<int NPROJ>
__global__ __launch_bounds__(256) void moe_proj_kernel(
    const float* __restrict__ yslot, const float* __restrict__ pwg, const float* __restrict__ pbg,
    int pwld, int nTok, int seqLen,
    float* __restrict__ out0, float* __restrict__ out1, float* __restrict__ out2)
{
    __shared__ __align__(16) float gs[64][68];
    __shared__ __align__(16) float wb[NPROJ*68];
    int tid = threadIdx.x;
    int base = blockIdx.x*64;
    for (int i=tid; i<64*16; i+=256){
        int c = i>>4, dq = i&15;
        int tok = base + c;
        float4 g4 = make_float4(0.f,0.f,0.f,0.f);
        if (tok < nTok){
            float4 a = *(const float4*)(yslot + (size_t)tok*128 + dq*4);
            float4 b = *(const float4*)(yslot + (size_t)tok*128 + 64 + dq*4);
            g4.x = geluf(a.x+b.x); g4.y = geluf(a.y+b.y);
            g4.z = geluf(a.z+b.z); g4.w = geluf(a.w+b.w);
        }
        *(float4*)(&gs[c][dq*4]) = g4;
    }
    for (int i=tid; i<DD*NPROJ; i+=256){
        int d = i / NPROJ, j = i % NPROJ;
        wb[j*68+d] = pwg[(size_t)d*pwld + j];
    }
    __syncthreads();
    for (int o=tid; o<64*NPROJ; o+=256){
        int c = o / NPROJ, j = o % NPROJ;
        int n = base + c;
        if (n >= nTok) continue;
        float acc = pbg[j];
        const float4* gp = (const float4*)(&gs[c][0]);
        const float4* wp = (const float4*)(&wb[j*68]);
        #pragma unroll
        for (int dq=0; dq<16; ++dq) acc += dot4f(gp[dq], wp[dq]);
        int b = n / (seqLen*HH);
        int r = n % (seqLen*HH);
        int sr = r / HH, h = r % HH;
        int bufi = j >> 6, jd = j & 63;
        float* dst = (bufi==0) ? out0 : (bufi==1) ? out1 : out2;
        dst[(((size_t)b*HH + h)*seqLen + sr)*DD + jd] = acc;
    }
}

// ---------------- Flash attention: per (b,h,32-row t-tile), online softmax ----------------
__global__ __launch_bounds__(256) void attn_kernel(
    const float* __restrict__ qb,   // (B,H,T,64)
    const float* __restrict__ kmb,  // (B,H,T,64)
    const float* __restrict__ vmb,
    const float* __restrict__ ktb,  // (B,H,M,64)
    const float* __restrict__ vtb,
    const float* __restrict__ kd,   // (NDS,48,H,64) -> [0]
    const float* __restrict__ vd,
    const float* __restrict__ kr,   // (48,H,64)
    const float* __restrict__ vr,
    const int*   __restrict__ smask, // (B,T)
    const float* __restrict__ tcond, // (B,1)
    const float* __restrict__ kms_p, const float* __restrict__ kds_p,
    const float* __restrict__ krs_p, const float* __restrict__ kts_p,
    const float* __restrict__ sigma_p,
    float* __restrict__ outb)        // (B,T,640)
{
    __shared__ __align__(16) float qs[32*68];
    __shared__ __align__(16) float ks[64*68];
    __shared__ __align__(16) float vs[64*68];
    __shared__ __align__(16) float ps_l[32*68];
    __shared__ float madd[64];

    int tid = threadIdx.x;
    int bid = blockIdx.x;
    int ttile = bid & 15;
    int bh = bid >> 4;
    int b = bh / HH, h = bh % HH;
    int t0 = ttile * 32;
    const float sc = 0.125f;
    float kms = kms_p[0]*sc, kds = kds_p[0]*sc, krs = krs_p[0]*sc, kts = kts_p[0]*sc;
    float sg = sigma_p[0];
    float inv2s = 1.0f/(2.0f*sg*sg);
    bool text_on = tcond[b] > 0.f;

    const float* qsrc = qb + (((size_t)bh)*TT + t0)*DD;
    for (int i=tid; i<32*16; i+=256){
        int r = i>>4, dq = i&15;
        *(float4*)(&qs[r*68+dq*4]) = *(const float4*)(&qsrc[r*64+dq*4]);
    }
    int tp = tid >> 4;   // 0..15 -> rows tp*2, tp*2+1
    int sq = tid & 15;   // 0..15

    float m_r[2] = {-1e30f, -1e30f};
    float l_r[2] = {0.f, 0.f};
    float oacc[2][4] = {};

    for (int ch=0; ch<NCH; ++ch){
        __syncthreads();
        for (int i=tid; i<64*16; i+=256){
            int r = i>>4, dq = i&15;
            int s = ch*64 + r;
            float4 kv = make_float4(0,0,0,0), vv = make_float4(0,0,0,0);
            if (s < TT){
                kv = *(const float4*)(&kmb[(((size_t)bh)*TT + s)*DD + dq*4]);
                kv.x*=kms; kv.y*=kms; kv.z*=kms; kv.w*=kms;
                vv = *(const float4*)(&vmb[(((size_t)bh)*TT + s)*DD + dq*4]);
            } else if (s < TT+48){
                kv = *(const float4*)(&kd[((size_t)(s-TT)*HH + h)*DD + dq*4]);
                kv.x*=kds; kv.y*=kds; kv.z*=kds; kv.w*=kds;
                vv = *(const float4*)(&vd[((size_t)(s-TT)*HH + h)*DD + dq*4]);
            } else if (s < TT+96){
                kv = *(const float4*)(&kr[((size_t)(s-TT-48)*HH + h)*DD + dq*4]);
                kv.x*=krs; kv.y*=krs; kv.z*=krs; kv.w*=krs;
                vv = *(const float4*)(&vr[((size_t)(s-TT-48)*HH + h)*DD + dq*4]);
            } else if (s < NS){
                kv = *(const float4*)(&ktb[(((size_t)bh)*MM + (s-TT-96))*DD + dq*4]);
                kv.x*=kts; kv.y*=kts; kv.z*=kts; kv.w*=kts;
                vv = *(const float4*)(&vtb[(((size_t)bh)*MM + (s-TT-96))*DD + dq*4]);
            }
            *(float4*)(&ks[r*68+dq*4]) = kv;
            *(float4*)(&vs[r*68+dq*4]) = vv;
        }
        if (tid < 64){
            int s = ch*64 + tid;
            float a;
            if (s < TT)            a = (smask[b*TT + s] == 0) ? -1e9f : 0.f;
            else if (s < TT+96)    a = 0.f;
            else if (s < NS)       a = text_on ? 0.f : -1e9f;
            else                   a = -1e30f;
            madd[tid] = a;
        }
        __syncthreads();

        float acc[2][4] = {};
        const float4* q0 = (const float4*)(&qs[(tp*2+0)*68]);
        const float4* q1 = (const float4*)(&qs[(tp*2+1)*68]);
        #pragma unroll 4
        for (int dq=0; dq<16; ++dq){
            float4 qa = q0[dq], qb4 = q1[dq];
            #pragma unroll
            for (int j=0;j<4;++j){
                float4 kv = *(const float4*)(&ks[(sq + 16*j)*68 + dq*4]);
                acc[0][j] += dot4f(qa, kv);
                acc[1][j] += dot4f(qb4, kv);
            }
        }
        #pragma unroll
        for (int i=0;i<2;++i){
            int t = t0 + tp*2 + i;
            #pragma unroll
            for (int j=0;j<4;++j){
                int sl = sq + 16*j;
                int s = ch*64 + sl;
                float a = madd[sl];
                if (s < TT){ float dt = (float)(t - s); a -= dt*dt*inv2s; }
                acc[i][j] += a;
            }
        }
        float pm[2], mn[2], scl[2], ps[2];
        #pragma unroll
        for (int i=0;i<2;++i)
            pm[i] = fmaxf(fmaxf(acc[i][0], acc[i][1]), fmaxf(acc[i][2], acc[i][3]));
        #pragma unroll
        for (int m2=1; m2<16; m2<<=1){
            pm[0] = fmaxf(pm[0], __shfl_xor(pm[0], m2));
            pm[1] = fmaxf(pm[1], __shfl_xor(pm[1], m2));
        }
        #pragma unroll
        for (int i=0;i<2;++i){
            mn[i] = fmaxf(m_r[i], pm[i]);
            scl[i] = __expf(m_r[i] - mn[i]);
            m_r[i] = mn[i];
            ps[i] = 0.f;
            #pragma unroll
            for (int j=0;j<4;++j){
                acc[i][j] = __expf(acc[i][j] - mn[i]);
                ps[i] += acc[i][j];
            }
        }
        #pragma unroll
        for (int m2=1; m2<16; m2<<=1){
            ps[0] += __shfl_xor(ps[0], m2);
            ps[1] += __shfl_xor(ps[1], m2);
        }
        #pragma unroll
        for (int i=0;i<2;++i){
            l_r[i] = l_r[i]*scl[i] + ps[i];
            #pragma unroll
            for (int j=0;j<4;++j) oacc[i][j] *= scl[i];
        }
        #pragma unroll
        for (int i=0;i<2;++i)
            #pragma unroll
            for (int j=0;j<4;++j)
                ps_l[(tp*2+i)*68 + sq + 16*j] = acc[i][j];
        __syncthreads();
        const float* p0r = &ps_l[(tp*2+0)*68];
        const float* p1r = &ps_l[(tp*2+1)*68];
        #pragma unroll 8
        for (int sl=0; sl<64; ++sl){
            float p0 = p0r[sl], p1 = p1r[sl];
            float4 vv = *(const float4*)(&vs[sl*68 + sq*4]);
            oacc[0][0] += p0*vv.x; oacc[0][1] += p0*vv.y; oacc[0][2] += p0*vv.z; oacc[0][3] += p0*vv.w;
            oacc[1][0] += p1*vv.x; oacc[1][1] += p1*vv.y; oacc[1][2] += p1*vv.z; oacc[1][3] += p1*vv.w;
        }
    }
    #pragma unroll
    for (int i=0;i<2;++i){
        int t = t0 + tp*2 + i;
        float inv = 1.0f / l_r[i];
        float4 o4 = make_float4(oacc[i][0]*inv, oacc[i][1]*inv, oacc[i][2]*inv, oacc[i][3]*inv);
        *(float4*)(&outb[((size_t)(b*TT + t))*LATD + h*64 + sq*4]) = o4;
    }
}

// ---------------- generic tiled GEMM: C = act(A) @ W + bias (+res) ----------------
template<bool ACT_SILU>
__global__ __launch_bounds__(256) void gemm_kernel(
    const float* __restrict__ A, const float* __restrict__ W,
    const float* __restrict__ bias, const float* __restrict__ res,
    float* __restrict__ C, int Mr, int Nr, int Kr)
{
    __shared__ __align__(16) float As[32*68];   // [k][m]
    __shared__ __align__(16) float Ws[32*68];   // [k][n]
    int tid = threadIdx.x;
    int row0 = blockIdx.x*64, col0 = blockIdx.y*64;
    int tr = tid >> 4, tc = tid & 15;
    float acc[4][4] = {};
    for (int k0=0; k0<Kr; k0+=32){
        __syncthreads();
        for (int i=tid; i<64*32; i+=256){
            int m2 = i>>5, k = i&31;
            float v = A[((size_t)(row0+m2))*Kr + k0 + k];
            if (ACT_SILU) v = siluf(v);
            As[k*68 + m2] = v;
        }
        for (int i=tid; i<32*64; i+=256){
            int k = i>>6, n = i&63;
            Ws[k*68 + n] = W[((size_t)(k0+k))*Nr + col0 + n];
        }
        __syncthreads();
        #pragma unroll 8
        for (int k=0;k<32;++k){
            float4 av = *(const float4*)(&As[k*68 + tr*4]);
            float4 wv = *(const float4*)(&Ws[k*68 + tc*4]);
            float a4[4] = {av.x, av.y, av.z, av.w};
            float w4[4] = {wv.x, wv.y, wv.z, wv.w};
            #pragma unroll
            for (int i=0;i<4;++i)
                #pragma unroll
                for (int j=0;j<4;++j) acc[i][j] += a4[i]*w4[j];
        }
    }
    #pragma unroll
    for (int i=0;i<4;++i){
        int r = row0 + tr*4 + i;
        size_t off = (size_t)r*Nr + col0 + tc*4;
        float4 bv = *(const float4*)(&bias[col0 + tc*4]);
        float4 o = make_float4(acc[i][0]+bv.x, acc[i][1]+bv.y, acc[i][2]+bv.z, acc[i][3]+bv.w);
        if (res){
            float4 rv = *(const float4*)(&res[off]);
            o.x += rv.x; o.y += rv.y; o.z += rv.z; o.w += rv.w;
        }
        *(float4*)(&C[off]) = o;
    }
}

// ---------------- modulated LN + silu ----------------
__global__ __launch_bounds__(256) void lnmod_kernel(
    const float* __restrict__ in, const float* __restrict__ g, const float* __restrict__ bb,
    const float* __restrict__ eo, float* __restrict__ out)
{
    int row = blockIdx.x, tid = threadIdx.x;
    __shared__ float xsr[LATD];
    __shared__ float red[256];
    const float* rp = in + (size_t)row*LATD;
    float s = 0.f;
    for (int i=tid;i<LATD;i+=256){ float v = rp[i]; xsr[i]=v; s+=v; }
    red[tid]=s; __syncthreads();
    for (int k=128;k>0;k>>=1){ if (tid<k) red[tid]+=red[tid+k]; __syncthreads(); }
    float mean = red[0]*(1.0f/LATD);
    __syncthreads();
    float vs=0.f;
    for (int i=tid;i<LATD;i+=256){ float d=xsr[i]-mean; vs+=d*d; }
    red[tid]=vs; __syncthreads();
    for (int k=128;k>0;k>>=1){ if (tid<k) red[tid]+=red[tid+k]; __syncthreads(); }
    float rstd = rsqrtf(red[0]*(1.0f/LATD)+1e-5f);
    const float* ep = eo + (size_t)row*(2*LATD);
    float* op = out + (size_t)row*LATD;
    for (int i=tid;i<LATD;i+=256){
        float v = (xsr[i]-mean)*rstd*g[i] + bb[i];
        v = v*(1.0f + ep[i]) + ep[LATD+i];
        op[i] = siluf(v);
    }
}

extern "C" void kernel_launch(void* const* d_in, const int* in_sizes, int n_in,
                              void* d_out, int out_size, void* d_ws, size_t ws_size,
                              hipStream_t stream)
{
    (void)in_sizes; (void)n_in; (void)out_size; (void)ws_size;
    const float* x     = (const float*)d_in[0];
    const float* emb   = (const float*)d_in[1];
    const int*   smask = (const int*)d_in[2];
    const float* tcond = (const float*)d_in[5];
    const float* two   = (const float*)d_in[6];
    const float* ng    = (const float*)d_in[7];
    const float* nb    = (const float*)d_in[8];
    const float* memb  = (const float*)d_in[9];
    const float* m_wg  = (const float*)d_in[10];
    const float* m_w1  = (const float*)d_in[11];
    const float* m_b1  = (const float*)d_in[12];
    const float* m_w2  = (const float*)d_in[13];
    const float* m_b2  = (const float*)d_in[14];
    const float* m_pw  = (const float*)d_in[15];
    const float* m_pb  = (const float*)d_in[16];
    const float* kms   = (const float*)d_in[17];
    const float* sigma = (const float*)d_in[18];
    const float* kdat  = (const float*)d_in[19];
    const float* kds   = (const float*)d_in[20];
    const float* vdat  = (const float*)d_in[21];
    const float* krot  = (const float*)d_in[22];
    const float* krs   = (const float*)d_in[23];
    const float* vrot  = (const float*)d_in[24];
    const float* ntg   = (const float*)d_in[25];
    const float* ntb   = (const float*)d_in[26];
    const float* c_wg  = (const float*)d_in[27];
    const float* c_w1  = (const float*)d_in[28];
    const float* c_b1  = (const float*)d_in[29];
    const float* c_w2  = (const float*)d_in[30];
    const float* c_b2  = (const float*)d_in[31];
    const float* c_pw  = (const float*)d_in[32];
    const float* c_pb  = (const float*)d_in[33];
    const float* kts   = (const float*)d_in[34];
    const float* st_ew = (const float*)d_in[35];
    const float* st_eb = (const float*)d_in[36];
    const float* st_ng = (const float*)d_in[37];
    const float* st_nb = (const float*)d_in[38];
    const float* st_ow = (const float*)d_in[39];
    const float* st_ob = (const float*)d_in[40];

    float* ws = (float*)d_ws;
    float* xh   = ws;                    // 1310720
    float* qB   = xh  + 1310720;         // 1310720
    float* kmB  = qB  + 1310720;         // 1310720
    float* vmB  = kmB + 1310720;         // 1310720
    float* ctB  = vmB + 1310720;         // 197120
    float* ktB  = ctB + 197120;          // 197120
    float* vtB  = ktB + 197120;          // 197120
    float* aout = vtB + 197120;          // 1310720
    float* eoB  = aout + 1310720;        // 2621440
    float* shB  = eoB + 2621440;         // 1310720

    float* yslotM = eoB;
    float* yslotT = shB;
    float* wAm   = aout;
    float* wAt   = wAm + NTOK_M*2;
    int*   cntA  = (int*)(wAt + NTOK_T*2);
    int*   listM = cntA + 16;
    int*   listT = listM + EE*NTOK_M;

    ln_kernel<<<BB*TT, 256, 0, stream>>>(x, ng, nb, memb, xh, TT);
    ln_kernel<<<BB*MM, 256, 0, stream>>>(two, ntg, ntb, nullptr, ctB, MM);
    zero_counts_kernel<<<1, 64, 0, stream>>>(cntA);
    route_kernel<<<(NTOK_M+255)/256, 256, 0, stream>>>(xh, m_wg, NTOK_M, cntA, listM, wAm);
    route_kernel<<<(NTOK_T+255)/256, 256, 0, stream>>>(ctB, c_wg, NTOK_T, cntA+8, listT, wAt);
    moe_ffn_kernel<<<MAXB_M, 256, 0, stream>>>(
        xh, m_w1, m_b1, m_w2, m_b2, cntA, listM, wAm, NTOK_M, yslotM);
    moe_ffn_kernel<<<MAXB_T, 256, 0, stream>>>(
        ctB, c_w1, c_b1, c_w2, c_b2, cntA+8, listT, wAt, NTOK_T, yslotT);
    moe_proj_kernel<192><<<(NTOK_M+63)/64, 256, 0, stream>>>(
        yslotM, m_pw, m_pb, 5*DD, NTOK_M, TT, qB, kmB, vmB);
    moe_proj_kernel<128><<<(NTOK_T+63)/64, 256, 0, stream>>>(
        yslotT, c_pw, c_pb, 2*DD, NTOK_T, MM, ktB, vtB, nullptr);
    attn_kernel<<<BB*HH*16, 256, 0, stream>>>(
        qB, kmB, vmB, ktB, vtB, kdat, vdat, krot, vrot, smask, tcond,
        kms, kds, krs, kts, sigma, aout);
    {
        dim3 g1(2048/64, 1280/64);
        gemm_kernel<true><<<g1, 256, 0, stream>>>(emb, st_ew, st_eb, nullptr, eoB, 2048, 1280, 512);
    }
    lnmod_kernel<<<BB*TT, 256, 0, stream>>>(aout, st_ng, st_nb, eoB, shB);
    {
        dim3 g2(2048/64, 640/64);
        gemm_kernel<false><<<g2, 256, 0, stream>>>(shB, st_ow, st_ob, x, (float*)d_out, 2048, 640, 640);
    }
}

// Round 5
// 364.888 us; speedup vs baseline: 3.2704x; 1.4521x over previous
//
#include <hip/hip_runtime.h>
#include <math.h>

#define BB 4
#define TT 512
#define MM 77
#define HH 10
#define DD 64
#define LATD 640
#define EE 8
#define FFND 256
#define NS 685     // 512 + 48 + 48 + 77
#define NCH 11     // ceil(685/64)
#define NROWS 20480 // B*H*T

#define NTOK_M (BB*TT*HH)   // 20480
#define NTOK_T (BB*MM*HH)   // 3080
#define MAXB_M 647
#define MAXB_T 103

typedef float f32x4 __attribute__((ext_vector_type(4)));
typedef __bf16 bf16x8_t __attribute__((ext_vector_type(8)));

__device__ __forceinline__ float geluf(float x){
    float u = 0.7978845608028654f*(x + 0.044715f*x*x*x);
    u = fminf(fmaxf(u, -15.f), 15.f);
    float e = __expf(2.f*u);
    return 0.5f*x*(1.f + (e-1.f)/(e+1.f));
}
__device__ __forceinline__ float siluf(float x){
    return x / (1.0f + __expf(-x));
}
__device__ __forceinline__ float dot4f(float4 a, float4 b){
    return a.x*b.x + a.y*b.y + a.z*b.z + a.w*b.w;
}
__device__ __forceinline__ unsigned short f2bf(float f){
    unsigned int u = __float_as_uint(f);
    u += 0x7fff + ((u >> 16) & 1);
    return (unsigned short)(u >> 16);
}

// ---------------- LayerNorm (rows of 640), optional additive emb (T,640) ----------------
__global__ __launch_bounds__(256) void ln_kernel(
    const float* __restrict__ in, const float* __restrict__ g, const float* __restrict__ bb,
    const float* __restrict__ addv, float* __restrict__ out, int seqLen)
{
    int row = blockIdx.x, tid = threadIdx.x;
    __shared__ float xsr[LATD];
    __shared__ float red[256];
    const float* rp = in + (size_t)row*LATD;
    float s = 0.f;
    for (int i=tid;i<LATD;i+=256){ float v = rp[i]; xsr[i]=v; s+=v; }
    red[tid]=s; __syncthreads();
    for (int k=128;k>0;k>>=1){ if (tid<k) red[tid]+=red[tid+k]; __syncthreads(); }
    float mean = red[0]*(1.0f/LATD);
    __syncthreads();
    float vs=0.f;
    for (int i=tid;i<LATD;i+=256){ float d=xsr[i]-mean; vs+=d*d; }
    red[tid]=vs; __syncthreads();
    for (int k=128;k>0;k>>=1){ if (tid<k) red[tid]+=red[tid+k]; __syncthreads(); }
    float rstd = rsqrtf(red[0]*(1.0f/LATD)+1e-5f);
    int t = row % seqLen;
    const float* ap = addv ? (addv + (size_t)t*LATD) : nullptr;
    float* op = out + (size_t)row*LATD;
    for (int i=tid;i<LATD;i+=256){
        float v = (xsr[i]-mean)*rstd*g[i] + bb[i];
        if (ap) v += ap[i];
        op[i] = v;
    }
}

// ---------------- MoE routing (block-aggregated atomics) ----------------
__global__ void zero_counts_kernel(int* __restrict__ c){
    if (threadIdx.x < 16) c[threadIdx.x] = 0;
}

__global__ __launch_bounds__(256) void route_kernel(
    const float* __restrict__ xin, const float* __restrict__ wg, int nTok,
    int* __restrict__ counts, int* __restrict__ list, float* __restrict__ wA)
{
    __shared__ int bcnt[EE];
    __shared__ int bbase[EE];
    const int tid = threadIdx.x;
    const int t = blockIdx.x*256 + tid;
    if (tid < EE) bcnt[tid] = 0;
    __syncthreads();

    int e0 = 0, e1 = 0, p0 = 0, p1 = 0;
    bool act = (t < nTok);
    if (act){
        float lg[EE];
        #pragma unroll
        for (int e=0;e<EE;e++) lg[e]=0.f;
        const float4* xp = (const float4*)(xin + (size_t)t*DD);
        #pragma unroll 4
        for (int dq=0; dq<16; ++dq){
            float4 xv = xp[dq];
            const float* w0 = wg + (dq*4+0)*EE;
            const float* w1 = wg + (dq*4+1)*EE;
            const float* w2 = wg + (dq*4+2)*EE;
            const float* w3 = wg + (dq*4+3)*EE;
            #pragma unroll
            for (int e=0;e<EE;e++)
                lg[e] += xv.x*w0[e] + xv.y*w1[e] + xv.z*w2[e] + xv.w*w3[e];
        }
        float mx = lg[0];
        #pragma unroll
        for (int e=1;e<EE;e++) mx = fmaxf(mx, lg[e]);
        float sum = 0.f;
        #pragma unroll
        for (int e=0;e<EE;e++){ lg[e] = __expf(lg[e]-mx); sum += lg[e]; }
        float inv = 1.0f/sum;
        #pragma unroll
        for (int e=0;e<EE;e++) lg[e] *= inv;
        float v0=lg[0];
        #pragma unroll
        for (int e=1;e<EE;e++){ if (lg[e] > v0){ v0 = lg[e]; e0 = e; } }
        float v1=-1e30f; e1 = (e0==0) ? 1 : 0;
        #pragma unroll
        for (int e=0;e<EE;e++){ if (e==e0) continue; if (lg[e] > v1){ v1 = lg[e]; e1 = e; } }
        wA[t*2+0]=v0; wA[t*2+1]=v1;
        p0 = atomicAdd(&bcnt[e0], 1);
        p1 = atomicAdd(&bcnt[e1], 1);
    }
    __syncthreads();
    if (tid < EE){
        bbase[tid] = (bcnt[tid] > 0) ? atomicAdd(&counts[tid], bcnt[tid]) : 0;
    }
    __syncthreads();
    if (act){
        list[(size_t)e0*nTok + bbase[e0] + p0] = t*2;
        list[(size_t)e1*nTok + bbase[e1] + p1] = t*2+1;
    }
}

// ---------------- grouped expert FFN: block = (expert, 64-token tile) ----------------
__global__ __launch_bounds__(256) void moe_ffn_kernel(
    const float* __restrict__ xin,
    const float* __restrict__ w1g,   // (E,64,256)
    const float* __restrict__ b1g,   // (E,256)
    const float* __restrict__ w2g,   // (E,256,64)
    const float* __restrict__ b2g,   // (E,64)
    const int* __restrict__ counts, const int* __restrict__ list,
    const float* __restrict__ wA, int nTok,
    float* __restrict__ yslot)       // (nTok,2,64)
{
    __shared__ __align__(16) float xs_t[DD][68];  // [d][token]
    __shared__ __align__(16) float hs[64][68];    // [token][f within chunk]
    __shared__ int sCnt[EE];
    __shared__ int encs[64];
    __shared__ float wgts[64];
    const int tid = threadIdx.x;
    if (tid < EE) sCnt[tid] = counts[tid];
    __syncthreads();
    int e = -1, tile = 0;
    {
        int acc = 0, bid = blockIdx.x;
        #pragma unroll
        for (int i=0;i<EE;++i){
            int tc = (sCnt[i]+63)>>6;
            if (e < 0 && bid < acc + tc){ e = i; tile = bid - acc; }
            acc += tc;
        }
    }
    if (e < 0) return;
    const int cnt = sCnt[e];
    if (tid < 64){
        int idx = tile*64 + tid;
        int enc = (idx < cnt) ? list[(size_t)e*nTok + idx] : -1;
        encs[tid] = enc;
        wgts[tid] = (enc >= 0) ? wA[enc] : 0.f;
    }
    __syncthreads();
    for (int i=tid; i<64*16; i+=256){
        int c = i>>4, dq = i&15;
        int enc = encs[c];
        float4 xv = make_float4(0.f,0.f,0.f,0.f);
        if (enc >= 0) xv = *(const float4*)(xin + (size_t)(enc>>1)*DD + dq*4);
        xs_t[dq*4+0][c]=xv.x; xs_t[dq*4+1][c]=xv.y; xs_t[dq*4+2][c]=xv.z; xs_t[dq*4+3][c]=xv.w;
    }
    __syncthreads();

    const int tf = tid & 15;
    const int tm = tid >> 4;
    float yacc[4][4] = {};
    const float* w1e = w1g + (size_t)e*DD*FFND;
    const float* w2e = w2g + (size_t)e*FFND*DD;

    for (int fc=0; fc<4; ++fc){
        float acc1[4][4] = {};
        #pragma unroll 8
        for (int d=0; d<DD; ++d){
            float4 wv = *(const float4*)(w1e + d*FFND + fc*64 + tf*4);
            float4 xv = *(const float4*)(&xs_t[d][tm*4]);
            float xa[4] = {xv.x, xv.y, xv.z, xv.w};
            #pragma unroll
            for (int u=0;u<4;++u){
                acc1[u][0] += xa[u]*wv.x;
                acc1[u][1] += xa[u]*wv.y;
                acc1[u][2] += xa[u]*wv.z;
                acc1[u][3] += xa[u]*wv.w;
            }
        }
        float4 b1v = *(const float4*)(b1g + e*FFND + fc*64 + tf*4);
        #pragma unroll
        for (int u=0;u<4;++u){
            float4 hv;
            hv.x = geluf(acc1[u][0]+b1v.x);
            hv.y = geluf(acc1[u][1]+b1v.y);
            hv.z = geluf(acc1[u][2]+b1v.z);
            hv.w = geluf(acc1[u][3]+b1v.w);
            *(float4*)(&hs[tm*4+u][tf*4]) = hv;
        }
        __syncthreads();
        #pragma unroll 8
        for (int fp=0; fp<64; ++fp){
            float4 wv = *(const float4*)(w2e + (size_t)(fc*64+fp)*DD + tf*4);
            float hv0 = hs[tm*4+0][fp];
            float hv1 = hs[tm*4+1][fp];
            float hv2 = hs[tm*4+2][fp];
            float hv3 = hs[tm*4+3][fp];
            yacc[0][0]+=hv0*wv.x; yacc[0][1]+=hv0*wv.y; yacc[0][2]+=hv0*wv.z; yacc[0][3]+=hv0*wv.w;
            yacc[1][0]+=hv1*wv.x; yacc[1][1]+=hv1*wv.y; yacc[1][2]+=hv1*wv.z; yacc[1][3]+=hv1*wv.w;
            yacc[2][0]+=hv2*wv.x; yacc[2][1]+=hv2*wv.y; yacc[2][2]+=hv2*wv.z; yacc[2][3]+=hv2*wv.w;
            yacc[3][0]+=hv3*wv.x; yacc[3][1]+=hv3*wv.y; yacc[3][2]+=hv3*wv.z; yacc[3][3]+=hv3*wv.w;
        }
        __syncthreads();
    }
    float4 b2v = *(const float4*)(b2g + e*DD + tf*4);
    #pragma unroll
    for (int u=0;u<4;++u){
        int enc = encs[tm*4+u];
        if (enc >= 0){
            float w = wgts[tm*4+u];
            float4 o;
            o.x = w*(yacc[u][0]+b2v.x);
            o.y = w*(yacc[u][1]+b2v.y);
            o.z = w*(yacc[u][2]+b2v.z);
            o.w = w*(yacc[u][3]+b2v.w);
            *(float4*)(yslot + (size_t)enc*DD + tf*4) = o;
        }
    }
}

// ---------------- combine slots + gelu + projection + scatter ----------------
template<int NPROJ>
__global__ __launch_bounds__(256) void moe_proj_kernel(
    const float* __restrict__ yslot, const float* __restrict__ pwg, const float* __restrict__ pbg,
    int pwld, int nTok, int seqLen,
    float* __restrict__ out0, float* __restrict__ out1, float* __restrict__ out2)
{
    __shared__ __align__(16) float gs[64][68];
    __shared__ __align__(16) float wb[NPROJ*68];
    int tid = threadIdx.x;
    int base = blockIdx.x*64;
    for (int i=tid; i<64*16; i+=256){
        int c = i>>4, dq = i&15;
        int tok = base + c;
        float4 g4 = make_float4(0.f,0.f,0.f,0.f);
        if (tok < nTok){
            float4 a = *(const float4*)(yslot + (size_t)tok*128 + dq*4);
            float4 b = *(const float4*)(yslot + (size_t)tok*128 + 64 + dq*4);
            g4.x = geluf(a.x+b.x); g4.y = geluf(a.y+b.y);
            g4.z = geluf(a.z+b.z); g4.w = geluf(a.w+b.w);
        }
        *(float4*)(&gs[c][dq*4]) = g4;
    }
    for (int i=tid; i<DD*NPROJ; i+=256){
        int d = i / NPROJ, j = i % NPROJ;
        wb[j*68+d] = pwg[(size_t)d*pwld + j];
    }
    __syncthreads();
    for (int o=tid; o<64*NPROJ; o+=256){
        int c = o / NPROJ, j = o % NPROJ;
        int n = base + c;
        if (n >= nTok) continue;
        float acc = pbg[j];
        const float4* gp = (const float4*)(&gs[c][0]);
        const float4* wp = (const float4*)(&wb[j*68]);
        #pragma unroll
        for (int dq=0; dq<16; ++dq) acc += dot4f(gp[dq], wp[dq]);
        int b = n / (seqLen*HH);
        int r = n % (seqLen*HH);
        int sr = r / HH, h = r % HH;
        int bufi = j >> 6, jd = j & 63;
        float* dst = (bufi==0) ? out0 : (bufi==1) ? out1 : out2;
        dst[(((size_t)b*HH + h)*seqLen + sr)*DD + jd] = acc;
    }
}

// ---------------- Flash attention (split-s): per (b,h,32-row t-tile, s-split) ----------------
__global__ __launch_bounds__(256) void attn_kernel(
    const float* __restrict__ qb,   // (B,H,T,64)
    const float* __restrict__ kmb,  // (B,H,T,64)
    const float* __restrict__ vmb,
    const float* __restrict__ ktb,  // (B,H,M,64)
    const float* __restrict__ vtb,
    const float* __restrict__ kd,   // (NDS,48,H,64) -> [0]
    const float* __restrict__ vd,
    const float* __restrict__ kr,   // (48,H,64)
    const float* __restrict__ vr,
    const int*   __restrict__ smask, // (B,T)
    const float* __restrict__ tcond, // (B,1)
    const float* __restrict__ kms_p, const float* __restrict__ kds_p,
    const float* __restrict__ krs_p, const float* __restrict__ kts_p,
    const float* __restrict__ sigma_p,
    float* __restrict__ po,          // (2, NROWS, 64) unnormalized partial O
    float* __restrict__ pm,          // (2, NROWS)
    float* __restrict__ pl)          // (2, NROWS)
{
    __shared__ __align__(16) float qs[32*68];
    __shared__ __align__(16) float ks[64*68];
    __shared__ __align__(16) float vs[64*68];
    __shared__ __align__(16) float ps_l[32*68];
    __shared__ float madd[64];

    int tid = threadIdx.x;
    int bid = blockIdx.x;
    int split = blockIdx.y;
    int ch_lo = split ? 6 : 0;
    int ch_hi = split ? NCH : 6;
    int ttile = bid & 15;
    int bh = bid >> 4;
    int b = bh / HH, h = bh % HH;
    int t0 = ttile * 32;
    const float sc = 0.125f;
    float kms = kms_p[0]*sc, kds = kds_p[0]*sc, krs = krs_p[0]*sc, kts = kts_p[0]*sc;
    float sg = sigma_p[0];
    float inv2s = 1.0f/(2.0f*sg*sg);
    bool text_on = tcond[b] > 0.f;

    const float* qsrc = qb + (((size_t)bh)*TT + t0)*DD;
    for (int i=tid; i<32*16; i+=256){
        int r = i>>4, dq = i&15;
        *(float4*)(&qs[r*68+dq*4]) = *(const float4*)(&qsrc[r*64+dq*4]);
    }
    int tp = tid >> 4;
    int sq = tid & 15;

    float m_r[2] = {-1e30f, -1e30f};
    float l_r[2] = {0.f, 0.f};
    float oacc[2][4] = {};

    for (int ch=ch_lo; ch<ch_hi; ++ch){
        __syncthreads();
        for (int i=tid; i<64*16; i+=256){
            int r = i>>4, dq = i&15;
            int s = ch*64 + r;
            float4 kv = make_float4(0,0,0,0), vv = make_float4(0,0,0,0);
            if (s < TT){
                kv = *(const float4*)(&kmb[(((size_t)bh)*TT + s)*DD + dq*4]);
                kv.x*=kms; kv.y*=kms; kv.z*=kms; kv.w*=kms;
                vv = *(const float4*)(&vmb[(((size_t)bh)*TT + s)*DD + dq*4]);
            } else if (s < TT+48){
                kv = *(const float4*)(&kd[((size_t)(s-TT)*HH + h)*DD + dq*4]);
                kv.x*=kds; kv.y*=kds; kv.z*=kds; kv.w*=kds;
                vv = *(const float4*)(&vd[((size_t)(s-TT)*HH + h)*DD + dq*4]);
            } else if (s < TT+96){
                kv = *(const float4*)(&kr[((size_t)(s-TT-48)*HH + h)*DD + dq*4]);
                kv.x*=krs; kv.y*=krs; kv.z*=krs; kv.w*=krs;
                vv = *(const float4*)(&vr[((size_t)(s-TT-48)*HH + h)*DD + dq*4]);
            } else if (s < NS){
                kv = *(const float4*)(&ktb[(((size_t)bh)*MM + (s-TT-96))*DD + dq*4]);
                kv.x*=kts; kv.y*=kts; kv.z*=kts; kv.w*=kts;
                vv = *(const float4*)(&vtb[(((size_t)bh)*MM + (s-TT-96))*DD + dq*4]);
            }
            *(float4*)(&ks[r*68+dq*4]) = kv;
            *(float4*)(&vs[r*68+dq*4]) = vv;
        }
        if (tid < 64){
            int s = ch*64 + tid;
            float a;
            if (s < TT)            a = (smask[b*TT + s] == 0) ? -1e9f : 0.f;
            else if (s < TT+96)    a = 0.f;
            else if (s < NS)       a = text_on ? 0.f : -1e9f;
            else                   a = -1e30f;
            madd[tid] = a;
        }
        __syncthreads();

        float acc[2][4] = {};
        const float4* q0 = (const float4*)(&qs[(tp*2+0)*68]);
        const float4* q1 = (const float4*)(&qs[(tp*2+1)*68]);
        #pragma unroll 4
        for (int dq=0; dq<16; ++dq){
            float4 qa = q0[dq], qb4 = q1[dq];
            #pragma unroll
            for (int j=0;j<4;++j){
                float4 kv = *(const float4*)(&ks[(sq + 16*j)*68 + dq*4]);
                acc[0][j] += dot4f(qa, kv);
                acc[1][j] += dot4f(qb4, kv);
            }
        }
        #pragma unroll
        for (int i=0;i<2;++i){
            int t = t0 + tp*2 + i;
            #pragma unroll
            for (int j=0;j<4;++j){
                int sl = sq + 16*j;
                int s = ch*64 + sl;
                float a = madd[sl];
                if (s < TT){ float dt = (float)(t - s); a -= dt*dt*inv2s; }
                acc[i][j] += a;
            }
        }
        float pmv[2], mn[2], scl[2], ps[2];
        #pragma unroll
        for (int i=0;i<2;++i)
            pmv[i] = fmaxf(fmaxf(acc[i][0], acc[i][1]), fmaxf(acc[i][2], acc[i][3]));
        #pragma unroll
        for (int m2=1; m2<16; m2<<=1){
            pmv[0] = fmaxf(pmv[0], __shfl_xor(pmv[0], m2));
            pmv[1] = fmaxf(pmv[1], __shfl_xor(pmv[1], m2));
        }
        #pragma unroll
        for (int i=0;i<2;++i){
            mn[i] = fmaxf(m_r[i], pmv[i]);
            scl[i] = __expf(m_r[i] - mn[i]);
            m_r[i] = mn[i];
            ps[i] = 0.f;
            #pragma unroll
            for (int j=0;j<4;++j){
                acc[i][j] = __expf(acc[i][j] - mn[i]);
                ps[i] += acc[i][j];
            }
        }
        #pragma unroll
        for (int m2=1; m2<16; m2<<=1){
            ps[0] += __shfl_xor(ps[0], m2);
            ps[1] += __shfl_xor(ps[1], m2);
        }
        #pragma unroll
        for (int i=0;i<2;++i){
            l_r[i] = l_r[i]*scl[i] + ps[i];
            #pragma unroll
            for (int j=0;j<4;++j) oacc[i][j] *= scl[i];
        }
        #pragma unroll
        for (int i=0;i<2;++i)
            #pragma unroll
            for (int j=0;j<4;++j)
                ps_l[(tp*2+i)*68 + sq + 16*j] = acc[i][j];
        __syncthreads();
        const float* p0r = &ps_l[(tp*2+0)*68];
        const float* p1r = &ps_l[(tp*2+1)*68];
        #pragma unroll 8
        for (int sl=0; sl<64; ++sl){
            float p0 = p0r[sl], p1 = p1r[sl];
            float4 vv = *(const float4*)(&vs[sl*68 + sq*4]);
            oacc[0][0] += p0*vv.x; oacc[0][1] += p0*vv.y; oacc[0][2] += p0*vv.z; oacc[0][3] += p0*vv.w;
            oacc[1][0] += p1*vv.x; oacc[1][1] += p1*vv.y; oacc[1][2] += p1*vv.z; oacc[1][3] += p1*vv.w;
        }
    }
    #pragma unroll
    for (int i=0;i<2;++i){
        int t = t0 + tp*2 + i;
        size_t off = (size_t)split*NROWS + (size_t)bh*TT + t;
        *(float4*)(po + off*64 + sq*4) =
            make_float4(oacc[i][0], oacc[i][1], oacc[i][2], oacc[i][3]);
        if (sq == 0){ pm[off] = m_r[i]; pl[off] = l_r[i]; }
    }
}

// ---------------- merge the 2 s-splits ----------------
__global__ __launch_bounds__(256) void attn_combine_kernel(
    const float* __restrict__ po, const float* __restrict__ pm, const float* __restrict__ pl,
    float* __restrict__ outb)
{
    int tid = threadIdx.x, bid = blockIdx.x;
    int ttile = bid & 15, bh = bid >> 4;
    int b = bh / HH, h = bh % HH;
    int tp = tid >> 4, sq = tid & 15;
    #pragma unroll
    for (int i=0;i<2;++i){
        int t = ttile*32 + tp*2 + i;
        size_t rowid = (size_t)bh*TT + t;
        float m0 = pm[rowid], m1 = pm[NROWS + rowid];
        float l0 = pl[rowid], l1 = pl[NROWS + rowid];
        float m = fmaxf(m0, m1);
        float s0 = __expf(m0 - m), s1 = __expf(m1 - m);
        float inv = 1.0f / (l0*s0 + l1*s1);
        float4 o0 = *(const float4*)(po + rowid*64 + sq*4);
        float4 o1 = *(const float4*)(po + ((size_t)NROWS + rowid)*64 + sq*4);
        float4 o;
        o.x = (o0.x*s0 + o1.x*s1)*inv;
        o.y = (o0.y*s0 + o1.y*s1)*inv;
        o.z = (o0.z*s0 + o1.z*s1)*inv;
        o.w = (o0.w*s0 + o1.w*s1)*inv;
        *(float4*)(&outb[((size_t)(b*TT + t))*LATD + h*64 + sq*4]) = o;
    }
}

// ---------------- bf16 MFMA GEMM: C = act(A) @ W + bias (+res). 32x64 tile ----------------
template<bool ACT_SILU>
__global__ __launch_bounds__(256) void gemm_mfma_kernel(
    const float* __restrict__ A, const float* __restrict__ W,
    const float* __restrict__ bias, const float* __restrict__ res,
    float* __restrict__ C, int Mr, int Nr, int Kr)
{
    __shared__ __align__(16) unsigned short As[32][40];   // [m][k] bf16
    __shared__ __align__(16) unsigned short Bs[64][40];   // [n][k] bf16 (W transposed)
    int tid = threadIdx.x;
    int row0 = blockIdx.x*32, col0 = blockIdx.y*64;
    int wave = tid >> 6, lane = tid & 63;
    int lr = lane & 15, lk = lane >> 4;

    f32x4 acc[2] = {};   // m-fragments 0,1 for this wave's 16-col slice

    for (int k0 = 0; k0 < Kr; k0 += 32){
        __syncthreads();
        // stage A: 32 rows x 32 k (silu fused), bf16
        {
            int r = tid >> 3, kq = tid & 7;
            float4 v = *(const float4*)(A + (size_t)(row0 + r)*Kr + k0 + kq*4);
            if (ACT_SILU){ v.x=siluf(v.x); v.y=siluf(v.y); v.z=siluf(v.z); v.w=siluf(v.w); }
            unsigned short* dst = &As[r][kq*4];
            dst[0]=f2bf(v.x); dst[1]=f2bf(v.y); dst[2]=f2bf(v.z); dst[3]=f2bf(v.w);
        }
        // stage W transposed: Bs[n][k] from W[k][n]
        #pragma unroll
        for (int it = 0; it < 2; ++it){
            int i = tid + it*256;
            int k = i >> 4, nq = i & 15;
            float4 v = *(const float4*)(W + (size_t)(k0 + k)*Nr + col0 + nq*4);
            Bs[nq*4+0][k] = f2bf(v.x);
            Bs[nq*4+1][k] = f2bf(v.y);
            Bs[nq*4+2][k] = f2bf(v.z);
            Bs[nq*4+3][k] = f2bf(v.w);
        }
        __syncthreads();
        bf16x8_t a0 = *reinterpret_cast<const bf16x8_t*>(&As[lr][lk*8]);
        bf16x8_t a1 = *reinterpret_cast<const bf16x8_t*>(&As[16 + lr][lk*8]);
        bf16x8_t bfr = *reinterpret_cast<const bf16x8_t*>(&Bs[wave*16 + lr][lk*8]);
        acc[0] = __builtin_amdgcn_mfma_f32_16x16x32_bf16(a0, bfr, acc[0], 0, 0, 0);
        acc[1] = __builtin_amdgcn_mfma_f32_16x16x32_bf16(a1, bfr, acc[1], 0, 0, 0);
    }
    // epilogue: D col = lane&15, row = (lane>>4)*4 + reg
    int gc = col0 + wave*16 + lr;
    float bv = bias[gc];
    #pragma unroll
    for (int m=0;m<2;++m){
        #pragma unroll
        for (int r=0;r<4;++r){
            int gr = row0 + m*16 + lk*4 + r;
            float v = acc[m][r] + bv;
            size_t off = (size_t)gr*Nr + gc;
            if (res) v += res[off];
            C[off] = v;
        }
    }
}

// ---------------- modulated LN + silu ----------------
__global__ __launch_bounds__(256) void lnmod_kernel(
    const float* __restrict__ in, const float* __restrict__ g, const float* __restrict__ bb,
    const float* __restrict__ eo, float* __restrict__ out)
{
    int row = blockIdx.x, tid = threadIdx.x;
    __shared__ float xsr[LATD];
    __shared__ float red[256];
    const float* rp = in + (size_t)row*LATD;
    float s = 0.f;
    for (int i=tid;i<LATD;i+=256){ float v = rp[i]; xsr[i]=v; s+=v; }
    red[tid]=s; __syncthreads();
    for (int k=128;k>0;k>>=1){ if (tid<k) red[tid]+=red[tid+k]; __syncthreads(); }
    float mean = red[0]*(1.0f/LATD);
    __syncthreads();
    float vs=0.f;
    for (int i=tid;i<LATD;i+=256){ float d=xsr[i]-mean; vs+=d*d; }
    red[tid]=vs; __syncthreads();
    for (int k=128;k>0;k>>=1){ if (tid<k) red[tid]+=red[tid+k]; __syncthreads(); }
    float rstd = rsqrtf(red[0]*(1.0f/LATD)+1e-5f);
    const float* ep = eo + (size_t)row*(2*LATD);
    float* op = out + (size_t)row*LATD;
    for (int i=tid;i<LATD;i+=256){
        float v = (xsr[i]-mean)*rstd*g[i] + bb[i];
        v = v*(1.0f + ep[i]) + ep[LATD+i];
        op[i] = siluf(v);
    }
}

extern "C" void kernel_launch(void* const* d_in, const int* in_sizes, int n_in,
                              void* d_out, int out_size, void* d_ws, size_t ws_size,
                              hipStream_t stream)
{
    (void)in_sizes; (void)n_in; (void)out_size; (void)ws_size;
    const float* x     = (const float*)d_in[0];
    const float* emb   = (const float*)d_in[1];
    const int*   smask = (const int*)d_in[2];
    const float* tcond = (const float*)d_in[5];
    const float* two   = (const float*)d_in[6];
    const float* ng    = (const float*)d_in[7];
    const float* nb    = (const float*)d_in[8];
    const float* memb  = (const float*)d_in[9];
    const float* m_wg  = (const float*)d_in[10];
    const float* m_w1  = (const float*)d_in[11];
    const float* m_b1  = (const float*)d_in[12];
    const float* m_w2  = (const float*)d_in[13];
    const float* m_b2  = (const float*)d_in[14];
    const float* m_pw  = (const float*)d_in[15];
    const float* m_pb  = (const float*)d_in[16];
    const float* kms   = (const float*)d_in[17];
    const float* sigma = (const float*)d_in[18];
    const float* kdat  = (const float*)d_in[19];
    const float* kds   = (const float*)d_in[20];
    const float* vdat  = (const float*)d_in[21];
    const float* krot  = (const float*)d_in[22];
    const float* krs   = (const float*)d_in[23];
    const float* vrot  = (const float*)d_in[24];
    const float* ntg   = (const float*)d_in[25];
    const float* ntb   = (const float*)d_in[26];
    const float* c_wg  = (const float*)d_in[27];
    const float* c_w1  = (const float*)d_in[28];
    const float* c_b1  = (const float*)d_in[29];
    const float* c_w2  = (const float*)d_in[30];
    const float* c_b2  = (const float*)d_in[31];
    const float* c_pw  = (const float*)d_in[32];
    const float* c_pb  = (const float*)d_in[33];
    const float* kts   = (const float*)d_in[34];
    const float* st_ew = (const float*)d_in[35];
    const float* st_eb = (const float*)d_in[36];
    const float* st_ng = (const float*)d_in[37];
    const float* st_nb = (const float*)d_in[38];
    const float* st_ow = (const float*)d_in[39];
    const float* st_ob = (const float*)d_in[40];

    float* ws = (float*)d_ws;
    float* xh   = ws;                    // 1310720
    float* qB   = xh  + 1310720;         // 1310720
    float* kmB  = qB  + 1310720;         // 1310720
    float* vmB  = kmB + 1310720;         // 1310720
    float* ctB  = vmB + 1310720;         // 197120
    float* ktB  = ctB + 197120;          // 197120
    float* vtB  = ktB + 197120;          // 197120
    float* aout = vtB + 197120;          // 1310720
    float* eoB  = aout + 1310720;        // 2621440
    float* shB  = eoB + 2621440;         // 1310720

    float* yslotM = eoB;                 // dead after moe_proj
    float* yslotT = shB;                 // dead after moe_proj
    float* wAm   = aout;                 // routing scratch (dead after moe_ffn)
    float* wAt   = wAm + NTOK_M*2;
    int*   cntA  = (int*)(wAt + NTOK_T*2);
    int*   listM = cntA + 16;
    int*   listT = listM + EE*NTOK_M;
    // attn partials: po aliases eoB (2*20480*64 = 2621440 exactly); pm/pl alias ctB
    float* poB = eoB;
    float* pmB = ctB;                    // 2*20480 = 40960
    float* plB = ctB + 2*NROWS;          // 40960

    ln_kernel<<<BB*TT, 256, 0, stream>>>(x, ng, nb, memb, xh, TT);
    ln_kernel<<<BB*MM, 256, 0, stream>>>(two, ntg, ntb, nullptr, ctB, MM);
    zero_counts_kernel<<<1, 64, 0, stream>>>(cntA);
    route_kernel<<<(NTOK_M+255)/256, 256, 0, stream>>>(xh, m_wg, NTOK_M, cntA, listM, wAm);
    route_kernel<<<(NTOK_T+255)/256, 256, 0, stream>>>(ctB, c_wg, NTOK_T, cntA+8, listT, wAt);
    moe_ffn_kernel<<<MAXB_M, 256, 0, stream>>>(
        xh, m_w1, m_b1, m_w2, m_b2, cntA, listM, wAm, NTOK_M, yslotM);
    moe_ffn_kernel<<<MAXB_T, 256, 0, stream>>>(
        ctB, c_w1, c_b1, c_w2, c_b2, cntA+8, listT, wAt, NTOK_T, yslotT);
    moe_proj_kernel<192><<<(NTOK_M+63)/64, 256, 0, stream>>>(
        yslotM, m_pw, m_pb, 5*DD, NTOK_M, TT, qB, kmB, vmB);
    moe_proj_kernel<128><<<(NTOK_T+63)/64, 256, 0, stream>>>(
        yslotT, c_pw, c_pb, 2*DD, NTOK_T, MM, ktB, vtB, nullptr);
    // attention: 2 s-splits, then combine
    {
        dim3 ga(BB*HH*16, 2);
        attn_kernel<<<ga, 256, 0, stream>>>(
            qB, kmB, vmB, ktB, vtB, kdat, vdat, krot, vrot, smask, tcond,
            kms, kds, krs, kts, sigma, poB, pmB, plB);
        attn_combine_kernel<<<BB*HH*16, 256, 0, stream>>>(poB, pmB, plB, aout);
    }
    // eo = silu(emb) @ st_emb_w + st_emb_b   (bf16 MFMA)
    {
        dim3 g1(2048/32, 1280/64);
        gemm_mfma_kernel<true><<<g1, 256, 0, stream>>>(emb, st_ew, st_eb, nullptr, eoB, 2048, 1280, 512);
    }
    lnmod_kernel<<<BB*TT, 256, 0, stream>>>(aout, st_ng, st_nb, eoB, shB);
    // out = x + sh @ st_out_w + st_out_b   (bf16 MFMA)
    {
        dim3 g2(2048/32, 640/64);
        gemm_mfma_kernel<false><<<g2, 256, 0, stream>>>(shB, st_ow, st_ob, x, (float*)d_out, 2048, 640, 640);
    }
}

// Round 6
// 292.715 us; speedup vs baseline: 4.0767x; 1.2466x over previous
//
#include <hip/hip_runtime.h>
#include <math.h>

#define BB 4
#define TT 512
#define MM 77
#define HH 10
#define DD 64
#define LATD 640
#define EE 8
#define FFND 256
#define NS 685     // 512 + 48 + 48 + 77
#define NCH 11     // ceil(685/64)
#define NROWS 20480 // B*H*T

#define NTOK_M (BB*TT*HH)   // 20480
#define NTOK_T (BB*MM*HH)   // 3080
#define MAXB_M 647
#define MAXB_T 103

typedef float f32x4 __attribute__((ext_vector_type(4)));
typedef __bf16 bf16x8_t __attribute__((ext_vector_type(8)));
typedef unsigned short u16x8 __attribute__((ext_vector_type(8)));

__device__ __forceinline__ float geluf(float x){
    float u = 0.7978845608028654f*(x + 0.044715f*x*x*x);
    u = fminf(fmaxf(u, -15.f), 15.f);
    float e = __expf(2.f*u);
    return 0.5f*x*(1.f + (e-1.f)/(e+1.f));
}
__device__ __forceinline__ float siluf(float x){
    return x / (1.0f + __expf(-x));
}
__device__ __forceinline__ float dot4f(float4 a, float4 b){
    return a.x*b.x + a.y*b.y + a.z*b.z + a.w*b.w;
}
__device__ __forceinline__ unsigned short f2bf(float f){
    unsigned int u = __float_as_uint(f);
    u += 0x7fff + ((u >> 16) & 1);
    return (unsigned short)(u >> 16);
}
__device__ __forceinline__ uint2 pack4bf(float a, float b, float c, float d){
    uint2 r;
    r.x = (unsigned)f2bf(a) | ((unsigned)f2bf(b)<<16);
    r.y = (unsigned)f2bf(c) | ((unsigned)f2bf(d)<<16);
    return r;
}

// ---------------- LayerNorm (rows of 640), optional additive emb (T,640) ----------------
__global__ __launch_bounds__(256) void ln_kernel(
    const float* __restrict__ in, const float* __restrict__ g, const float* __restrict__ bb,
    const float* __restrict__ addv, float* __restrict__ out, int seqLen)
{
    int row = blockIdx.x, tid = threadIdx.x;
    __shared__ float xsr[LATD];
    __shared__ float red[256];
    const float* rp = in + (size_t)row*LATD;
    float s = 0.f;
    for (int i=tid;i<LATD;i+=256){ float v = rp[i]; xsr[i]=v; s+=v; }
    red[tid]=s; __syncthreads();
    for (int k=128;k>0;k>>=1){ if (tid<k) red[tid]+=red[tid+k]; __syncthreads(); }
    float mean = red[0]*(1.0f/LATD);
    __syncthreads();
    float vs=0.f;
    for (int i=tid;i<LATD;i+=256){ float d=xsr[i]-mean; vs+=d*d; }
    red[tid]=vs; __syncthreads();
    for (int k=128;k>0;k>>=1){ if (tid<k) red[tid]+=red[tid+k]; __syncthreads(); }
    float rstd = rsqrtf(red[0]*(1.0f/LATD)+1e-5f);
    int t = row % seqLen;
    const float* ap = addv ? (addv + (size_t)t*LATD) : nullptr;
    float* op = out + (size_t)row*LATD;
    for (int i=tid;i<LATD;i+=256){
        float v = (xsr[i]-mean)*rstd*g[i] + bb[i];
        if (ap) v += ap[i];
        op[i] = v;
    }
}

// ---------------- MoE routing (block-aggregated atomics) ----------------
__global__ void zero_counts_kernel(int* __restrict__ c){
    if (threadIdx.x < 16) c[threadIdx.x] = 0;
}

__global__ __launch_bounds__(256) void route_kernel(
    const float* __restrict__ xin, const float* __restrict__ wg, int nTok,
    int* __restrict__ counts, int* __restrict__ list, float* __restrict__ wA)
{
    __shared__ int bcnt[EE];
    __shared__ int bbase[EE];
    const int tid = threadIdx.x;
    const int t = blockIdx.x*256 + tid;
    if (tid < EE) bcnt[tid] = 0;
    __syncthreads();

    int e0 = 0, e1 = 0, p0 = 0, p1 = 0;
    bool act = (t < nTok);
    if (act){
        float lg[EE];
        #pragma unroll
        for (int e=0;e<EE;e++) lg[e]=0.f;
        const float4* xp = (const float4*)(xin + (size_t)t*DD);
        #pragma unroll 4
        for (int dq=0; dq<16; ++dq){
            float4 xv = xp[dq];
            const float* w0 = wg + (dq*4+0)*EE;
            const float* w1 = wg + (dq*4+1)*EE;
            const float* w2 = wg + (dq*4+2)*EE;
            const float* w3 = wg + (dq*4+3)*EE;
            #pragma unroll
            for (int e=0;e<EE;e++)
                lg[e] += xv.x*w0[e] + xv.y*w1[e] + xv.z*w2[e] + xv.w*w3[e];
        }
        float mx = lg[0];
        #pragma unroll
        for (int e=1;e<EE;e++) mx = fmaxf(mx, lg[e]);
        float sum = 0.f;
        #pragma unroll
        for (int e=0;e<EE;e++){ lg[e] = __expf(lg[e]-mx); sum += lg[e]; }
        float inv = 1.0f/sum;
        #pragma unroll
        for (int e=0;e<EE;e++) lg[e] *= inv;
        float v0=lg[0];
        #pragma unroll
        for (int e=1;e<EE;e++){ if (lg[e] > v0){ v0 = lg[e]; e0 = e; } }
        float v1=-1e30f; e1 = (e0==0) ? 1 : 0;
        #pragma unroll
        for (int e=0;e<EE;e++){ if (e==e0) continue; if (lg[e] > v1){ v1 = lg[e]; e1 = e; } }
        wA[t*2+0]=v0; wA[t*2+1]=v1;
        p0 = atomicAdd(&bcnt[e0], 1);
        p1 = atomicAdd(&bcnt[e1], 1);
    }
    __syncthreads();
    if (tid < EE){
        bbase[tid] = (bcnt[tid] > 0) ? atomicAdd(&counts[tid], bcnt[tid]) : 0;
    }
    __syncthreads();
    if (act){
        list[(size_t)e0*nTok + bbase[e0] + p0] = t*2;
        list[(size_t)e1*nTok + bbase[e1] + p1] = t*2+1;
    }
}

// ---------------- grouped expert FFN: block = (expert, 64-token tile) ----------------
__global__ __launch_bounds__(256) void moe_ffn_kernel(
    const float* __restrict__ xin,
    const float* __restrict__ w1g,   // (E,64,256)
    const float* __restrict__ b1g,   // (E,256)
    const float* __restrict__ w2g,   // (E,256,64)
    const float* __restrict__ b2g,   // (E,64)
    const int* __restrict__ counts, const int* __restrict__ list,
    const float* __restrict__ wA, int nTok,
    float* __restrict__ yslot)       // (nTok,2,64)
{
    __shared__ __align__(16) float xs_t[DD][68];  // [d][token]
    __shared__ __align__(16) float hs[64][68];    // [token][f within chunk]
    __shared__ int sCnt[EE];
    __shared__ int encs[64];
    __shared__ float wgts[64];
    const int tid = threadIdx.x;
    if (tid < EE) sCnt[tid] = counts[tid];
    __syncthreads();
    int e = -1, tile = 0;
    {
        int acc = 0, bid = blockIdx.x;
        #pragma unroll
        for (int i=0;i<EE;++i){
            int tc = (sCnt[i]+63)>>6;
            if (e < 0 && bid < acc + tc){ e = i; tile = bid - acc; }
            acc += tc;
        }
    }
    if (e < 0) return;
    const int cnt = sCnt[e];
    if (tid < 64){
        int idx = tile*64 + tid;
        int enc = (idx < cnt) ? list[(size_t)e*nTok + idx] : -1;
        encs[tid] = enc;
        wgts[tid] = (enc >= 0) ? wA[enc] : 0.f;
    }
    __syncthreads();
    for (int i=tid; i<64*16; i+=256){
        int c = i>>4, dq = i&15;
        int enc = encs[c];
        float4 xv = make_float4(0.f,0.f,0.f,0.f);
        if (enc >= 0) xv = *(const float4*)(xin + (size_t)(enc>>1)*DD + dq*4);
        xs_t[dq*4+0][c]=xv.x; xs_t[dq*4+1][c]=xv.y; xs_t[dq*4+2][c]=xv.z; xs_t[dq*4+3][c]=xv.w;
    }
    __syncthreads();

    const int tf = tid & 15;
    const int tm = tid >> 4;
    float yacc[4][4] = {};
    const float* w1e = w1g + (size_t)e*DD*FFND;
    const float* w2e = w2g + (size_t)e*FFND*DD;

    for (int fc=0; fc<4; ++fc){
        float acc1[4][4] = {};
        #pragma unroll 8
        for (int d=0; d<DD; ++d){
            float4 wv = *(const float4*)(w1e + d*FFND + fc*64 + tf*4);
            float4 xv = *(const float4*)(&xs_t[d][tm*4]);
            float xa[4] = {xv.x, xv.y, xv.z, xv.w};
            #pragma unroll
            for (int u=0;u<4;++u){
                acc1[u][0] += xa[u]*wv.x;
                acc1[u][1] += xa[u]*wv.y;
                acc1[u][2] += xa[u]*wv.z;
                acc1[u][3] += xa[u]*wv.w;
            }
        }
        float4 b1v = *(const float4*)(b1g + e*FFND + fc*64 + tf*4);
        #pragma unroll
        for (int u=0;u<4;++u){
            float4 hv;
            hv.x = geluf(acc1[u][0]+b1v.x);
            hv.y = geluf(acc1[u][1]+b1v.y);
            hv.z = geluf(acc1[u][2]+b1v.z);
            hv.w = geluf(acc1[u][3]+b1v.w);
            *(float4*)(&hs[tm*4+u][tf*4]) = hv;
        }
        __syncthreads();
        #pragma unroll 8
        for (int fp=0; fp<64; ++fp){
            float4 wv = *(const float4*)(w2e + (size_t)(fc*64+fp)*DD + tf*4);
            float hv0 = hs[tm*4+0][fp];
            float hv1 = hs[tm*4+1][fp];
            float hv2 = hs[tm*4+2][fp];
            float hv3 = hs[tm*4+3][fp];
            yacc[0][0]+=hv0*wv.x; yacc[0][1]+=hv0*wv.y; yacc[0][2]+=hv0*wv.z; yacc[0][3]+=hv0*wv.w;
            yacc[1][0]+=hv1*wv.x; yacc[1][1]+=hv1*wv.y; yacc[1][2]+=hv1*wv.z; yacc[1][3]+=hv1*wv.w;
            yacc[2][0]+=hv2*wv.x; yacc[2][1]+=hv2*wv.y; yacc[2][2]+=hv2*wv.z; yacc[2][3]+=hv2*wv.w;
            yacc[3][0]+=hv3*wv.x; yacc[3][1]+=hv3*wv.y; yacc[3][2]+=hv3*wv.z; yacc[3][3]+=hv3*wv.w;
        }
        __syncthreads();
    }
    float4 b2v = *(const float4*)(b2g + e*DD + tf*4);
    #pragma unroll
    for (int u=0;u<4;++u){
        int enc = encs[tm*4+u];
        if (enc >= 0){
            float w = wgts[tm*4+u];
            float4 o;
            o.x = w*(yacc[u][0]+b2v.x);
            o.y = w*(yacc[u][1]+b2v.y);
            o.z = w*(yacc[u][2]+b2v.z);
            o.w = w*(yacc[u][3]+b2v.w);
            *(float4*)(yslot + (size_t)enc*DD + tf*4) = o;
        }
    }
}

// ---------------- combine slots + gelu + projection + scatter ----------------
template<int NPROJ>
__global__ __launch_bounds__(256) void moe_proj_kernel(
    const float* __restrict__ yslot, const float* __restrict__ pwg, const float* __restrict__ pbg,
    int pwld, int nTok, int seqLen,
    float* __restrict__ out0, float* __restrict__ out1, float* __restrict__ out2)
{
    __shared__ __align__(16) float gs[64][68];
    __shared__ __align__(16) float wb[NPROJ*68];
    int tid = threadIdx.x;
    int base = blockIdx.x*64;
    for (int i=tid; i<64*16; i+=256){
        int c = i>>4, dq = i&15;
        int tok = base + c;
        float4 g4 = make_float4(0.f,0.f,0.f,0.f);
        if (tok < nTok){
            float4 a = *(const float4*)(yslot + (size_t)tok*128 + dq*4);
            float4 b = *(const float4*)(yslot + (size_t)tok*128 + 64 + dq*4);
            g4.x = geluf(a.x+b.x); g4.y = geluf(a.y+b.y);
            g4.z = geluf(a.z+b.z); g4.w = geluf(a.w+b.w);
        }
        *(float4*)(&gs[c][dq*4]) = g4;
    }
    for (int i=tid; i<DD*NPROJ; i+=256){
        int d = i / NPROJ, j = i % NPROJ;
        wb[j*68+d] = pwg[(size_t)d*pwld + j];
    }
    __syncthreads();
    for (int o=tid; o<64*NPROJ; o+=256){
        int c = o / NPROJ, j = o % NPROJ;
        int n = base + c;
        if (n >= nTok) continue;
        float acc = pbg[j];
        const float4* gp = (const float4*)(&gs[c][0]);
        const float4* wp = (const float4*)(&wb[j*68]);
        #pragma unroll
        for (int dq=0; dq<16; ++dq) acc += dot4f(gp[dq], wp[dq]);
        int b = n / (seqLen*HH);
        int r = n % (seqLen*HH);
        int sr = r / HH, h = r % HH;
        int bufi = j >> 6, jd = j & 63;
        float* dst = (bufi==0) ? out0 : (bufi==1) ? out1 : out2;
        dst[(((size_t)b*HH + h)*seqLen + sr)*DD + jd] = acc;
    }
}

// ---------------- MFMA flash attention (split-s): block = (b,h,64-row t-tile), 4 waves ----
// Swapped QK^T: S^T = mfma(K_frag, Q_frag) so softmax q is lane-local (q = lane&15).
__global__ __launch_bounds__(256) void attn_kernel(
    const float* __restrict__ qb,   // (B,H,T,64)
    const float* __restrict__ kmb,  // (B,H,T,64)
    const float* __restrict__ vmb,
    const float* __restrict__ ktb,  // (B,H,M,64)
    const float* __restrict__ vtb,
    const float* __restrict__ kd,   // (NDS,48,H,64) -> [0]
    const float* __restrict__ vd,
    const float* __restrict__ kr,   // (48,H,64)
    const float* __restrict__ vr,
    const int*   __restrict__ smask, // (B,T)
    const float* __restrict__ tcond, // (B,1)
    const float* __restrict__ kms_p, const float* __restrict__ kds_p,
    const float* __restrict__ krs_p, const float* __restrict__ kts_p,
    const float* __restrict__ sigma_p,
    float* __restrict__ po,          // (2, NROWS, 64) unnormalized partial O
    float* __restrict__ pm,          // (2, NROWS)
    float* __restrict__ pl)          // (2, NROWS)
{
    __shared__ __align__(16) unsigned short Ks[64][72];   // [s][d] bf16 (K pre-scaled)
    __shared__ __align__(16) unsigned short Vt[64][72];   // [d][s^swz] bf16
    __shared__ __align__(16) unsigned short Pl[4][16][72];// per-wave [q][s] bf16
    __shared__ float madd[64];

    const int tid  = threadIdx.x;
    const int w    = tid >> 6;        // wave 0..3 -> q rows [w*16, w*16+16)
    const int lane = tid & 63;
    const int lq   = lane & 15;
    const int lg   = lane >> 4;       // 0..3

    const int bid   = blockIdx.x;
    const int split = blockIdx.y;
    const int ch_lo = split ? 6 : 0;
    const int ch_hi = split ? NCH : 6;
    const int ttile = bid & 7;
    const int bh    = bid >> 3;
    const int b = bh / HH, h = bh % HH;
    const int t0 = ttile * 64;

    const float sc = 0.125f;
    const float kms = kms_p[0]*sc, kds = kds_p[0]*sc, krs = krs_p[0]*sc, kts = kts_p[0]*sc;
    const float sg = sigma_p[0];
    const float inv2s = 1.0f/(2.0f*sg*sg);
    const bool text_on = tcond[b] > 0.f;

    // Q fragments in registers: q = t0 + w*16 + lq, k(d) = ks*32 + lg*8 + j
    bf16x8_t qf[2];
    {
        const float* qrow = qb + ((size_t)bh*TT + t0 + w*16 + lq)*DD;
        #pragma unroll
        for (int ks=0; ks<2; ++ks){
            float4 v0 = *(const float4*)(qrow + ks*32 + lg*8);
            float4 v1 = *(const float4*)(qrow + ks*32 + lg*8 + 4);
            u16x8 qt;
            qt[0]=f2bf(v0.x); qt[1]=f2bf(v0.y); qt[2]=f2bf(v0.z); qt[3]=f2bf(v0.w);
            qt[4]=f2bf(v1.x); qt[5]=f2bf(v1.y); qt[6]=f2bf(v1.z); qt[7]=f2bf(v1.w);
            qf[ks] = __builtin_bit_cast(bf16x8_t, qt);
        }
    }

    float m_r = -1e30f, l_r = 0.f;
    f32x4 oacc[4] = {};   // d-slices; lane: d = ds*16+lq, q = w*16 + lg*4 + reg

    const int tgq = t0 + w*16 + lq;   // this lane's softmax q row

    for (int ch=ch_lo; ch<ch_hi; ++ch){
        __syncthreads();
        // ---- stage K [s][d] (scaled, bf16 packed) and V transposed [d][s^swz] ----
        for (int i=tid; i<64*16; i+=256){
            int r = i>>4, dq4 = (i&15)*4;
            int s = ch*64 + r;
            float4 kv = make_float4(0,0,0,0), vv = make_float4(0,0,0,0);
            if (s < TT){
                kv = *(const float4*)(&kmb[(((size_t)bh)*TT + s)*DD + dq4]);
                kv.x*=kms; kv.y*=kms; kv.z*=kms; kv.w*=kms;
                vv = *(const float4*)(&vmb[(((size_t)bh)*TT + s)*DD + dq4]);
            } else if (s < TT+48){
                kv = *(const float4*)(&kd[((size_t)(s-TT)*HH + h)*DD + dq4]);
                kv.x*=kds; kv.y*=kds; kv.z*=kds; kv.w*=kds;
                vv = *(const float4*)(&vd[((size_t)(s-TT)*HH + h)*DD + dq4]);
            } else if (s < TT+96){
                kv = *(const float4*)(&kr[((size_t)(s-TT-48)*HH + h)*DD + dq4]);
                kv.x*=krs; kv.y*=krs; kv.z*=krs; kv.w*=krs;
                vv = *(const float4*)(&vr[((size_t)(s-TT-48)*HH + h)*DD + dq4]);
            } else if (s < NS){
                kv = *(const float4*)(&ktb[(((size_t)bh)*MM + (s-TT-96))*DD + dq4]);
                kv.x*=kts; kv.y*=kts; kv.z*=kts; kv.w*=kts;
                vv = *(const float4*)(&vtb[(((size_t)bh)*MM + (s-TT-96))*DD + dq4]);
            }
            *(uint2*)&Ks[r][dq4] = pack4bf(kv.x, kv.y, kv.z, kv.w);
            int swcol = r ^ (((i&15)&7)<<3);   // (d>>2)&7 == i&15 (mod 8)
            Vt[dq4+0][swcol] = f2bf(vv.x);
            Vt[dq4+1][swcol] = f2bf(vv.y);
            Vt[dq4+2][swcol] = f2bf(vv.z);
            Vt[dq4+3][swcol] = f2bf(vv.w);
        }
        if (tid < 64){
            int s = ch*64 + tid;
            float a;
            if (s < TT)            a = (smask[b*TT + s] == 0) ? -1e9f : 0.f;
            else if (s < TT+96)    a = 0.f;
            else if (s < NS)       a = text_on ? 0.f : -1e9f;
            else                   a = -1e30f;
            madd[tid] = a;
        }
        __syncthreads();

        // ---- QK^T (swapped): sacc[slice] holds S^T: col(lane&15)=q, row(lg*4+reg)=s ----
        f32x4 sacc[4] = {};
        #pragma unroll
        for (int sl=0; sl<4; ++sl){
            #pragma unroll
            for (int ks=0; ks<2; ++ks){
                bf16x8_t kf = *reinterpret_cast<const bf16x8_t*>(&Ks[sl*16 + lq][ks*32 + lg*8]);
                sacc[sl] = __builtin_amdgcn_mfma_f32_16x16x32_bf16(kf, qf[ks], sacc[sl], 0, 0, 0);
            }
        }
        // ---- bias + mask + online softmax (per lane: one q row, 16 s values) ----
        float sv[4][4];
        float pmax = -1e30f;
        #pragma unroll
        for (int sl=0; sl<4; ++sl){
            #pragma unroll
            for (int r=0; r<4; ++r){
                int s_loc = sl*16 + lg*4 + r;
                float a = madd[s_loc];
                if (ch < 8){ float dt = (float)(tgq - (ch*64 + s_loc)); a -= dt*dt*inv2s; }
                float v = sacc[sl][r] + a;
                sv[sl][r] = v;
                pmax = fmaxf(pmax, v);
            }
        }
        pmax = fmaxf(pmax, __shfl_xor(pmax, 16));
        pmax = fmaxf(pmax, __shfl_xor(pmax, 32));
        float mn  = fmaxf(m_r, pmax);
        float scl = __expf(m_r - mn);
        m_r = mn;
        float psum = 0.f;
        #pragma unroll
        for (int sl=0; sl<4; ++sl){
            #pragma unroll
            for (int r=0; r<4; ++r){
                float p = __expf(sv[sl][r] - mn);
                sv[sl][r] = p;
                psum += p;
            }
        }
        psum += __shfl_xor(psum, 16);
        psum += __shfl_xor(psum, 32);
        l_r = l_r*scl + psum;
        // write P (bf16) to this wave's buffer: row q=lq, cols s
        #pragma unroll
        for (int sl=0; sl<4; ++sl)
            *(uint2*)&Pl[w][lq][sl*16 + lg*4] = pack4bf(sv[sl][0], sv[sl][1], sv[sl][2], sv[sl][3]);

        // rescale O by per-q scale (O's q = lg*4+reg; scale lives at lane q)
        #pragma unroll
        for (int r=0; r<4; ++r){
            float so = __shfl(scl, lg*4 + r);
            #pragma unroll
            for (int ds_=0; ds_<4; ++ds_) oacc[ds_][r] *= so;
        }
        // ---- PV: O[q][d] += P[q][s] * V[s][d] ----
        #pragma unroll
        for (int ds_=0; ds_<4; ++ds_){
            int dcol = ds_*16 + lq;
            int swz = (((dcol>>2)&7)<<3);
            #pragma unroll
            for (int ks=0; ks<2; ++ks){
                bf16x8_t pf = *reinterpret_cast<const bf16x8_t*>(&Pl[w][lq][ks*32 + lg*8]);
                bf16x8_t vf = *reinterpret_cast<const bf16x8_t*>(&Vt[dcol][(ks*32 + lg*8) ^ swz]);
                oacc[ds_] = __builtin_amdgcn_mfma_f32_16x16x32_bf16(pf, vf, oacc[ds_], 0, 0, 0);
            }
        }
    }
    // ---- write partials ----
    #pragma unroll
    for (int r=0; r<4; ++r){
        int t = t0 + w*16 + lg*4 + r;
        size_t off = (size_t)split*NROWS + (size_t)bh*TT + t;
        #pragma unroll
        for (int ds_=0; ds_<4; ++ds_)
            po[off*64 + ds_*16 + lq] = oacc[ds_][r];
    }
    if (lg == 0){
        size_t off = (size_t)split*NROWS + (size_t)bh*TT + (t0 + w*16 + lq);
        pm[off] = m_r;
        pl[off] = l_r;
    }
}

// ---------------- merge the 2 s-splits ----------------
__global__ __launch_bounds__(256) void attn_combine_kernel(
    const float* __restrict__ po, const float* __restrict__ pm, const float* __restrict__ pl,
    float* __restrict__ outb)
{
    int tid = threadIdx.x, bid = blockIdx.x;
    int ttile = bid & 15, bh = bid >> 4;
    int b = bh / HH, h = bh % HH;
    int tp = tid >> 4, sq = tid & 15;
    #pragma unroll
    for (int i=0;i<2;++i){
        int t = ttile*32 + tp*2 + i;
        size_t rowid = (size_t)bh*TT + t;
        float m0 = pm[rowid], m1 = pm[NROWS + rowid];
        float l0 = pl[rowid], l1 = pl[NROWS + rowid];
        float m = fmaxf(m0, m1);
        float s0 = __expf(m0 - m), s1 = __expf(m1 - m);
        float inv = 1.0f / (l0*s0 + l1*s1);
        float4 o0 = *(const float4*)(po + rowid*64 + sq*4);
        float4 o1 = *(const float4*)(po + ((size_t)NROWS + rowid)*64 + sq*4);
        float4 o;
        o.x = (o0.x*s0 + o1.x*s1)*inv;
        o.y = (o0.y*s0 + o1.y*s1)*inv;
        o.z = (o0.z*s0 + o1.z*s1)*inv;
        o.w = (o0.w*s0 + o1.w*s1)*inv;
        *(float4*)(&outb[((size_t)(b*TT + t))*LATD + h*64 + sq*4]) = o;
    }
}

// ---------------- bf16 MFMA GEMM: C = act(A) @ W + bias (+res). 32x64 tile ----------------
template<bool ACT_SILU>
__global__ __launch_bounds__(256) void gemm_mfma_kernel(
    const float* __restrict__ A, const float* __restrict__ W,
    const float* __restrict__ bias, const float* __restrict__ res,
    float* __restrict__ C, int Mr, int Nr, int Kr)
{
    __shared__ __align__(16) unsigned short As[32][40];   // [m][k] bf16
    __shared__ __align__(16) unsigned short Bs[64][40];   // [n][k] bf16 (W transposed)
    int tid = threadIdx.x;
    int row0 = blockIdx.x*32, col0 = blockIdx.y*64;
    int wave = tid >> 6, lane = tid & 63;
    int lr = lane & 15, lk = lane >> 4;

    f32x4 acc[2] = {};

    for (int k0 = 0; k0 < Kr; k0 += 32){
        __syncthreads();
        {
            int r = tid >> 3, kq = tid & 7;
            float4 v = *(const float4*)(A + (size_t)(row0 + r)*Kr + k0 + kq*4);
            if (ACT_SILU){ v.x=siluf(v.x); v.y=siluf(v.y); v.z=siluf(v.z); v.w=siluf(v.w); }
            unsigned short* dst = &As[r][kq*4];
            dst[0]=f2bf(v.x); dst[1]=f2bf(v.y); dst[2]=f2bf(v.z); dst[3]=f2bf(v.w);
        }
        #pragma unroll
        for (int it = 0; it < 2; ++it){
            int i = tid + it*256;
            int k = i >> 4, nq = i & 15;
            float4 v = *(const float4*)(W + (size_t)(k0 + k)*Nr + col0 + nq*4);
            Bs[nq*4+0][k] = f2bf(v.x);
            Bs[nq*4+1][k] = f2bf(v.y);
            Bs[nq*4+2][k] = f2bf(v.z);
            Bs[nq*4+3][k] = f2bf(v.w);
        }
        __syncthreads();
        bf16x8_t a0 = *reinterpret_cast<const bf16x8_t*>(&As[lr][lk*8]);
        bf16x8_t a1 = *reinterpret_cast<const bf16x8_t*>(&As[16 + lr][lk*8]);
        bf16x8_t bfr = *reinterpret_cast<const bf16x8_t*>(&Bs[wave*16 + lr][lk*8]);
        acc[0] = __builtin_amdgcn_mfma_f32_16x16x32_bf16(a0, bfr, acc[0], 0, 0, 0);
        acc[1] = __builtin_amdgcn_mfma_f32_16x16x32_bf16(a1, bfr, acc[1], 0, 0, 0);
    }
    int gc = col0 + wave*16 + lr;
    float bv = bias[gc];
    #pragma unroll
    for (int m=0;m<2;++m){
        #pragma unroll
        for (int r=0;r<4;++r){
            int gr = row0 + m*16 + lk*4 + r;
            float v = acc[m][r] + bv;
            size_t off = (size_t)gr*Nr + gc;
            if (res) v += res[off];
            C[off] = v;
        }
    }
}

// ---------------- modulated LN + silu ----------------
__global__ __launch_bounds__(256) void lnmod_kernel(
    const float* __restrict__ in, const float* __restrict__ g, const float* __restrict__ bb,
    const float* __restrict__ eo, float* __restrict__ out)
{
    int row = blockIdx.x, tid = threadIdx.x;
    __shared__ float xsr[LATD];
    __shared__ float red[256];
    const float* rp = in + (size_t)row*LATD;
    float s = 0.f;
    for (int i=tid;i<LATD;i+=256){ float v = rp[i]; xsr[i]=v; s+=v; }
    red[tid]=s; __syncthreads();
    for (int k=128;k>0;k>>=1){ if (tid<k) red[tid]+=red[tid+k]; __syncthreads(); }
    float mean = red[0]*(1.0f/LATD);
    __syncthreads();
    float vs=0.f;
    for (int i=tid;i<LATD;i+=256){ float d=xsr[i]-mean; vs+=d*d; }
    red[tid]=vs; __syncthreads();
    for (int k=128;k>0;k>>=1){ if (tid<k) red[tid]+=red[tid+k]; __syncthreads(); }
    float rstd = rsqrtf(red[0]*(1.0f/LATD)+1e-5f);
    const float* ep = eo + (size_t)row*(2*LATD);
    float* op = out + (size_t)row*LATD;
    for (int i=tid;i<LATD;i+=256){
        float v = (xsr[i]-mean)*rstd*g[i] + bb[i];
        v = v*(1.0f + ep[i]) + ep[LATD+i];
        op[i] = siluf(v);
    }
}

extern "C" void kernel_launch(void* const* d_in, const int* in_sizes, int n_in,
                              void* d_out, int out_size, void* d_ws, size_t ws_size,
                              hipStream_t stream)
{
    (void)in_sizes; (void)n_in; (void)out_size; (void)ws_size;
    const float* x     = (const float*)d_in[0];
    const float* emb   = (const float*)d_in[1];
    const int*   smask = (const int*)d_in[2];
    const float* tcond = (const float*)d_in[5];
    const float* two   = (const float*)d_in[6];
    const float* ng    = (const float*)d_in[7];
    const float* nb    = (const float*)d_in[8];
    const float* memb  = (const float*)d_in[9];
    const float* m_wg  = (const float*)d_in[10];
    const float* m_w1  = (const float*)d_in[11];
    const float* m_b1  = (const float*)d_in[12];
    const float* m_w2  = (const float*)d_in[13];
    const float* m_b2  = (const float*)d_in[14];
    const float* m_pw  = (const float*)d_in[15];
    const float* m_pb  = (const float*)d_in[16];
    const float* kms   = (const float*)d_in[17];
    const float* sigma = (const float*)d_in[18];
    const float* kdat  = (const float*)d_in[19];
    const float* kds   = (const float*)d_in[20];
    const float* vdat  = (const float*)d_in[21];
    const float* krot  = (const float*)d_in[22];
    const float* krs   = (const float*)d_in[23];
    const float* vrot  = (const float*)d_in[24];
    const float* ntg   = (const float*)d_in[25];
    const float* ntb   = (const float*)d_in[26];
    const float* c_wg  = (const float*)d_in[27];
    const float* c_w1  = (const float*)d_in[28];
    const float* c_b1  = (const float*)d_in[29];
    const float* c_w2  = (const float*)d_in[30];
    const float* c_b2  = (const float*)d_in[31];
    const float* c_pw  = (const float*)d_in[32];
    const float* c_pb  = (const float*)d_in[33];
    const float* kts   = (const float*)d_in[34];
    const float* st_ew = (const float*)d_in[35];
    const float* st_eb = (const float*)d_in[36];
    const float* st_ng = (const float*)d_in[37];
    const float* st_nb = (const float*)d_in[38];
    const float* st_ow = (const float*)d_in[39];
    const float* st_ob = (const float*)d_in[40];

    float* ws = (float*)d_ws;
    float* xh   = ws;                    // 1310720
    float* qB   = xh  + 1310720;         // 1310720
    float* kmB  = qB  + 1310720;         // 1310720
    float* vmB  = kmB + 1310720;         // 1310720
    float* ctB  = vmB + 1310720;         // 197120
    float* ktB  = ctB + 197120;          // 197120
    float* vtB  = ktB + 197120;          // 197120
    float* aout = vtB + 197120;          // 1310720
    float* eoB  = aout + 1310720;        // 2621440
    float* shB  = eoB + 2621440;         // 1310720

    float* yslotM = eoB;
    float* yslotT = shB;
    float* wAm   = aout;
    float* wAt   = wAm + NTOK_M*2;
    int*   cntA  = (int*)(wAt + NTOK_T*2);
    int*   listM = cntA + 16;
    int*   listT = listM + EE*NTOK_M;
    float* poB = eoB;                    // 2*20480*64 = 2621440 exactly
    float* pmB = ctB;
    float* plB = ctB + 2*NROWS;

    ln_kernel<<<BB*TT, 256, 0, stream>>>(x, ng, nb, memb, xh, TT);
    ln_kernel<<<BB*MM, 256, 0, stream>>>(two, ntg, ntb, nullptr, ctB, MM);
    zero_counts_kernel<<<1, 64, 0, stream>>>(cntA);
    route_kernel<<<(NTOK_M+255)/256, 256, 0, stream>>>(xh, m_wg, NTOK_M, cntA, listM, wAm);
    route_kernel<<<(NTOK_T+255)/256, 256, 0, stream>>>(ctB, c_wg, NTOK_T, cntA+8, listT, wAt);
    moe_ffn_kernel<<<MAXB_M, 256, 0, stream>>>(
        xh, m_w1, m_b1, m_w2, m_b2, cntA, listM, wAm, NTOK_M, yslotM);
    moe_ffn_kernel<<<MAXB_T, 256, 0, stream>>>(
        ctB, c_w1, c_b1, c_w2, c_b2, cntA+8, listT, wAt, NTOK_T, yslotT);
    moe_proj_kernel<192><<<(NTOK_M+63)/64, 256, 0, stream>>>(
        yslotM, m_pw, m_pb, 5*DD, NTOK_M, TT, qB, kmB, vmB);
    moe_proj_kernel<128><<<(NTOK_T+63)/64, 256, 0, stream>>>(
        yslotT, c_pw, c_pb, 2*DD, NTOK_T, MM, ktB, vtB, nullptr);
    // attention: 2 s-splits (MFMA flash), then combine
    {
        dim3 ga(BB*HH*8, 2);
        attn_kernel<<<ga, 256, 0, stream>>>(
            qB, kmB, vmB, ktB, vtB, kdat, vdat, krot, vrot, smask, tcond,
            kms, kds, krs, kts, sigma, poB, pmB, plB);
        attn_combine_kernel<<<BB*HH*16, 256, 0, stream>>>(poB, pmB, plB, aout);
    }
    {
        dim3 g1(2048/32, 1280/64);
        gemm_mfma_kernel<true><<<g1, 256, 0, stream>>>(emb, st_ew, st_eb, nullptr, eoB, 2048, 1280, 512);
    }
    lnmod_kernel<<<BB*TT, 256, 0, stream>>>(aout, st_ng, st_nb, eoB, shB);
    {
        dim3 g2(2048/32, 640/64);
        gemm_mfma_kernel<false><<<g2, 256, 0, stream>>>(shB, st_ow, st_ob, x, (float*)d_out, 2048, 640, 640);
    }
}

// Round 7
// 232.554 us; speedup vs baseline: 5.1314x; 1.2587x over previous
//
#include <hip/hip_runtime.h>
#include <math.h>

#define BB 4
#define TT 512
#define MM 77
#define HH 10
#define DD 64
#define LATD 640
#define EE 8
#define FFND 256
#define NS 685     // 512 + 48 + 48 + 77
#define NCH 11     // ceil(685/64)
#define NROWS 20480 // B*H*T

#define NTOK_M (BB*TT*HH)   // 20480
#define NTOK_T (BB*MM*HH)   // 3080
#define MAXB_M 647
#define MAXB_T 103

typedef float f32x4 __attribute__((ext_vector_type(4)));
typedef __bf16 bf16x8_t __attribute__((ext_vector_type(8)));
typedef unsigned short u16x8 __attribute__((ext_vector_type(8)));

__device__ __forceinline__ float geluf(float x){
    float u = 0.7978845608028654f*(x + 0.044715f*x*x*x);
    u = fminf(fmaxf(u, -15.f), 15.f);
    float e = __expf(2.f*u);
    return 0.5f*x*(1.f + (e-1.f)/(e+1.f));
}
__device__ __forceinline__ float siluf(float x){
    return x / (1.0f + __expf(-x));
}
__device__ __forceinline__ float dot4f(float4 a, float4 b){
    return a.x*b.x + a.y*b.y + a.z*b.z + a.w*b.w;
}
__device__ __forceinline__ unsigned short f2bf(float f){
    unsigned int u = __float_as_uint(f);
    u += 0x7fff + ((u >> 16) & 1);
    return (unsigned short)(u >> 16);
}
__device__ __forceinline__ uint2 pack4bf(float a, float b, float c, float d){
    uint2 r;
    r.x = (unsigned)f2bf(a) | ((unsigned)f2bf(b)<<16);
    r.y = (unsigned)f2bf(c) | ((unsigned)f2bf(d)<<16);
    return r;
}

// ---------------- tiled transpose + bf16 convert: in f32 [z][R][C] -> out u16 [z][C][R] ----
__global__ __launch_bounds__(256) void transpose_bf16_kernel(
    const float* __restrict__ in, unsigned short* __restrict__ out, int R, int C)
{
    __shared__ float t[64][65];
    const int r0 = blockIdx.x*64, c0 = blockIdx.y*64;
    const size_t base = (size_t)blockIdx.z * R * C;
    const int tid = threadIdx.x;
    #pragma unroll
    for (int p=0; p<16; ++p){
        int i = tid + p*256;
        int r = i>>6, c = i&63;
        t[r][c] = in[base + (size_t)(r0+r)*C + c0 + c];
    }
    __syncthreads();
    #pragma unroll
    for (int p=0; p<16; ++p){
        int i = tid + p*256;
        int c = i>>6, r = i&63;
        out[base + (size_t)(c0+c)*R + r0 + r] = f2bf(t[r][c]);
    }
}

// ---------------- LayerNorm (rows of 640), optional additive emb (T,640) ----------------
__global__ __launch_bounds__(256) void ln_kernel(
    const float* __restrict__ in, const float* __restrict__ g, const float* __restrict__ bb,
    const float* __restrict__ addv, float* __restrict__ out, int seqLen)
{
    int row = blockIdx.x, tid = threadIdx.x;
    __shared__ float xsr[LATD];
    __shared__ float red[256];
    const float* rp = in + (size_t)row*LATD;
    float s = 0.f;
    for (int i=tid;i<LATD;i+=256){ float v = rp[i]; xsr[i]=v; s+=v; }
    red[tid]=s; __syncthreads();
    for (int k=128;k>0;k>>=1){ if (tid<k) red[tid]+=red[tid+k]; __syncthreads(); }
    float mean = red[0]*(1.0f/LATD);
    __syncthreads();
    float vs=0.f;
    for (int i=tid;i<LATD;i+=256){ float d=xsr[i]-mean; vs+=d*d; }
    red[tid]=vs; __syncthreads();
    for (int k=128;k>0;k>>=1){ if (tid<k) red[tid]+=red[tid+k]; __syncthreads(); }
    float rstd = rsqrtf(red[0]*(1.0f/LATD)+1e-5f);
    int t = row % seqLen;
    const float* ap = addv ? (addv + (size_t)t*LATD) : nullptr;
    float* op = out + (size_t)row*LATD;
    for (int i=tid;i<LATD;i+=256){
        float v = (xsr[i]-mean)*rstd*g[i] + bb[i];
        if (ap) v += ap[i];
        op[i] = v;
    }
}

// ---------------- MoE routing (block-aggregated atomics) ----------------
__global__ void zero_counts_kernel(int* __restrict__ c){
    if (threadIdx.x < 16) c[threadIdx.x] = 0;
}

__global__ __launch_bounds__(256) void route_kernel(
    const float* __restrict__ xin, const float* __restrict__ wg, int nTok,
    int* __restrict__ counts, int* __restrict__ list, float* __restrict__ wA)
{
    __shared__ int bcnt[EE];
    __shared__ int bbase[EE];
    const int tid = threadIdx.x;
    const int t = blockIdx.x*256 + tid;
    if (tid < EE) bcnt[tid] = 0;
    __syncthreads();

    int e0 = 0, e1 = 0, p0 = 0, p1 = 0;
    bool act = (t < nTok);
    if (act){
        float lg[EE];
        #pragma unroll
        for (int e=0;e<EE;e++) lg[e]=0.f;
        const float4* xp = (const float4*)(xin + (size_t)t*DD);
        #pragma unroll 4
        for (int dq=0; dq<16; ++dq){
            float4 xv = xp[dq];
            const float* w0 = wg + (dq*4+0)*EE;
            const float* w1 = wg + (dq*4+1)*EE;
            const float* w2 = wg + (dq*4+2)*EE;
            const float* w3 = wg + (dq*4+3)*EE;
            #pragma unroll
            for (int e=0;e<EE;e++)
                lg[e] += xv.x*w0[e] + xv.y*w1[e] + xv.z*w2[e] + xv.w*w3[e];
        }
        float mx = lg[0];
        #pragma unroll
        for (int e=1;e<EE;e++) mx = fmaxf(mx, lg[e]);
        float sum = 0.f;
        #pragma unroll
        for (int e=0;e<EE;e++){ lg[e] = __expf(lg[e]-mx); sum += lg[e]; }
        float inv = 1.0f/sum;
        #pragma unroll
        for (int e=0;e<EE;e++) lg[e] *= inv;
        float v0=lg[0];
        #pragma unroll
        for (int e=1;e<EE;e++){ if (lg[e] > v0){ v0 = lg[e]; e0 = e; } }
        float v1=-1e30f; e1 = (e0==0) ? 1 : 0;
        #pragma unroll
        for (int e=0;e<EE;e++){ if (e==e0) continue; if (lg[e] > v1){ v1 = lg[e]; e1 = e; } }
        wA[t*2+0]=v0; wA[t*2+1]=v1;
        p0 = atomicAdd(&bcnt[e0], 1);
        p1 = atomicAdd(&bcnt[e1], 1);
    }
    __syncthreads();
    if (tid < EE){
        bbase[tid] = (bcnt[tid] > 0) ? atomicAdd(&counts[tid], bcnt[tid]) : 0;
    }
    __syncthreads();
    if (act){
        list[(size_t)e0*nTok + bbase[e0] + p0] = t*2;
        list[(size_t)e1*nTok + bbase[e1] + p1] = t*2+1;
    }
}

// ---------------- grouped expert FFN (MFMA): block = (expert, 64-token tile), 4 waves ----
// w1T: bf16 [E][256 f][64 d]; w2T: bf16 [E][64 d][256 f]
__global__ __launch_bounds__(256) void moe_ffn_kernel(
    const float* __restrict__ xin,
    const unsigned short* __restrict__ w1T,
    const float* __restrict__ b1g,   // (E,256)
    const unsigned short* __restrict__ w2T,
    const float* __restrict__ b2g,   // (E,64)
    const int* __restrict__ counts, const int* __restrict__ list,
    const float* __restrict__ wA, int nTok,
    float* __restrict__ yslot)       // (nTok,2,64)
{
    __shared__ __align__(16) unsigned short xs[64][72];   // [tok][d]
    __shared__ __align__(16) unsigned short w1s[64][72];  // [f_loc][d]
    __shared__ __align__(16) unsigned short w2s[64][72];  // [d][f_loc]
    __shared__ __align__(16) unsigned short hs[64][72];   // [tok][f_loc]
    __shared__ int sCnt[EE];
    __shared__ int encs[64];
    __shared__ float wgts[64];
    const int tid = threadIdx.x;
    if (tid < EE) sCnt[tid] = counts[tid];
    __syncthreads();
    int e = -1, tile = 0;
    {
        int acc = 0, bid = blockIdx.x;
        #pragma unroll
        for (int i=0;i<EE;++i){
            int tc = (sCnt[i]+63)>>6;
            if (e < 0 && bid < acc + tc){ e = i; tile = bid - acc; }
            acc += tc;
        }
    }
    if (e < 0) return;
    const int cnt = sCnt[e];
    if (tid < 64){
        int idx = tile*64 + tid;
        int enc = (idx < cnt) ? list[(size_t)e*nTok + idx] : -1;
        encs[tid] = enc;
        wgts[tid] = (enc >= 0) ? wA[enc] : 0.f;
    }
    __syncthreads();
    // stage x as bf16 [tok][d]
    for (int i=tid; i<64*16; i+=256){
        int r = i>>4, dq4 = (i&15)*4;
        int enc = encs[r];
        float4 xv = make_float4(0.f,0.f,0.f,0.f);
        if (enc >= 0) xv = *(const float4*)(xin + (size_t)(enc>>1)*DD + dq4);
        *(uint2*)&xs[r][dq4] = pack4bf(xv.x, xv.y, xv.z, xv.w);
    }

    const int w    = tid >> 6;       // wave: owns tok rows w*16..w*16+15
    const int lane = tid & 63;
    const int lq   = lane & 15;
    const int lg   = lane >> 4;

    const unsigned short* w1e = w1T + (size_t)e*FFND*DD;
    const unsigned short* w2e = w2T + (size_t)e*DD*FFND;

    f32x4 acc2[4] = {};   // output y: rows tok (lg*4+r), cols d = db*16+lq

    for (int fc=0; fc<4; ++fc){
        __syncthreads();
        // stage w1 chunk [f_loc][d] and w2 chunk [d][f_loc] (both bf16, uint4 copies)
        for (int i=tid; i<512; i+=256){
            int r = i>>3, jq = i&7;
            *(uint4*)&w1s[r][jq*8] = *(const uint4*)(w1e + (size_t)(fc*64+r)*DD + jq*8);
            *(uint4*)&w2s[r][jq*8] = *(const uint4*)(w2e + (size_t)r*FFND + fc*64 + jq*8);
        }
        __syncthreads();
        // GEMM1: h[tok][f] = x @ w1 chunk
        f32x4 acc1[4] = {};
        #pragma unroll
        for (int fb=0; fb<4; ++fb){
            #pragma unroll
            for (int ks=0; ks<2; ++ks){
                bf16x8_t xf = *reinterpret_cast<const bf16x8_t*>(&xs[w*16+lq][ks*32+lg*8]);
                bf16x8_t wf = *reinterpret_cast<const bf16x8_t*>(&w1s[fb*16+lq][ks*32+lg*8]);
                acc1[fb] = __builtin_amdgcn_mfma_f32_16x16x32_bf16(xf, wf, acc1[fb], 0, 0, 0);
            }
        }
        // bias + gelu -> hs (wave-local rows)
        #pragma unroll
        for (int fb=0; fb<4; ++fb){
            float b1v = b1g[e*FFND + fc*64 + fb*16 + lq];
            #pragma unroll
            for (int r=0; r<4; ++r)
                hs[w*16 + lg*4 + r][fb*16 + lq] = f2bf(geluf(acc1[fb][r] + b1v));
        }
        // GEMM2: y[tok][d] += h_chunk @ w2_chunk (contract over f)
        #pragma unroll
        for (int db=0; db<4; ++db){
            #pragma unroll
            for (int ks=0; ks<2; ++ks){
                bf16x8_t hf  = *reinterpret_cast<const bf16x8_t*>(&hs[w*16+lq][ks*32+lg*8]);
                bf16x8_t w2f = *reinterpret_cast<const bf16x8_t*>(&w2s[db*16+lq][ks*32+lg*8]);
                acc2[db] = __builtin_amdgcn_mfma_f32_16x16x32_bf16(hf, w2f, acc2[db], 0, 0, 0);
            }
        }
    }
    // epilogue: gate * (y + b2) scattered per slot
    #pragma unroll
    for (int r=0; r<4; ++r){
        int tok = w*16 + lg*4 + r;
        int enc = encs[tok];
        if (enc >= 0){
            float gw = wgts[tok];
            #pragma unroll
            for (int db=0; db<4; ++db){
                int d = db*16 + lq;
                yslot[(size_t)enc*DD + d] = gw*(acc2[db][r] + b2g[e*DD + d]);
            }
        }
    }
}

// ---------------- combine slots + gelu + projection + scatter ----------------
template<int NPROJ>
__global__ __launch_bounds__(256) void moe_proj_kernel(
    const float* __restrict__ yslot, const float* __restrict__ pwg, const float* __restrict__ pbg,
    int pwld, int nTok, int seqLen,
    float* __restrict__ out0, float* __restrict__ out1, float* __restrict__ out2)
{
    __shared__ __align__(16) float gs[64][68];
    __shared__ __align__(16) float wb[NPROJ*68];
    int tid = threadIdx.x;
    int base = blockIdx.x*64;
    for (int i=tid; i<64*16; i+=256){
        int c = i>>4, dq = i&15;
        int tok = base + c;
        float4 g4 = make_float4(0.f,0.f,0.f,0.f);
        if (tok < nTok){
            float4 a = *(const float4*)(yslot + (size_t)tok*128 + dq*4);
            float4 b = *(const float4*)(yslot + (size_t)tok*128 + 64 + dq*4);
            g4.x = geluf(a.x+b.x); g4.y = geluf(a.y+b.y);
            g4.z = geluf(a.z+b.z); g4.w = geluf(a.w+b.w);
        }
        *(float4*)(&gs[c][dq*4]) = g4;
    }
    for (int i=tid; i<DD*NPROJ; i+=256){
        int d = i / NPROJ, j = i % NPROJ;
        wb[j*68+d] = pwg[(size_t)d*pwld + j];
    }
    __syncthreads();
    for (int o=tid; o<64*NPROJ; o+=256){
        int c = o / NPROJ, j = o % NPROJ;
        int n = base + c;
        if (n >= nTok) continue;
        float acc = pbg[j];
        const float4* gp = (const float4*)(&gs[c][0]);
        const float4* wp = (const float4*)(&wb[j*68]);
        #pragma unroll
        for (int dq=0; dq<16; ++dq) acc += dot4f(gp[dq], wp[dq]);
        int b = n / (seqLen*HH);
        int r = n % (seqLen*HH);
        int sr = r / HH, h = r % HH;
        int bufi = j >> 6, jd = j & 63;
        float* dst = (bufi==0) ? out0 : (bufi==1) ? out1 : out2;
        dst[(((size_t)b*HH + h)*seqLen + sr)*DD + jd] = acc;
    }
}

// ---------------- MFMA flash attention (split-s): block = (b,h,64-row t-tile), 4 waves ----
__global__ __launch_bounds__(256) void attn_kernel(
    const float* __restrict__ qb,   // (B,H,T,64)
    const float* __restrict__ kmb,  // (B,H,T,64)
    const float* __restrict__ vmb,
    const float* __restrict__ ktb,  // (B,H,M,64)
    const float* __restrict__ vtb,
    const float* __restrict__ kd,   // (NDS,48,H,64) -> [0]
    const float* __restrict__ vd,
    const float* __restrict__ kr,   // (48,H,64)
    const float* __restrict__ vr,
    const int*   __restrict__ smask, // (B,T)
    const float* __restrict__ tcond, // (B,1)
    const float* __restrict__ kms_p, const float* __restrict__ kds_p,
    const float* __restrict__ krs_p, const float* __restrict__ kts_p,
    const float* __restrict__ sigma_p,
    float* __restrict__ po,          // (2, NROWS, 64) unnormalized partial O
    float* __restrict__ pm,          // (2, NROWS)
    float* __restrict__ pl)          // (2, NROWS)
{
    __shared__ __align__(16) unsigned short Ks[64][72];   // [s][d] bf16 (K pre-scaled)
    __shared__ __align__(16) unsigned short Vt[64][72];   // [d][s^swz] bf16
    __shared__ __align__(16) unsigned short Pl[4][16][72];// per-wave [q][s] bf16
    __shared__ float madd[64];

    const int tid  = threadIdx.x;
    const int w    = tid >> 6;
    const int lane = tid & 63;
    const int lq   = lane & 15;
    const int lg   = lane >> 4;

    const int bid   = blockIdx.x;
    const int split = blockIdx.y;
    const int ch_lo = split ? 6 : 0;
    const int ch_hi = split ? NCH : 6;
    const int ttile = bid & 7;
    const int bh    = bid >> 3;
    const int b = bh / HH, h = bh % HH;
    const int t0 = ttile * 64;

    const float sc = 0.125f;
    const float kms = kms_p[0]*sc, kds = kds_p[0]*sc, krs = krs_p[0]*sc, kts = kts_p[0]*sc;
    const float sg = sigma_p[0];
    const float inv2s = 1.0f/(2.0f*sg*sg);
    const bool text_on = tcond[b] > 0.f;

    bf16x8_t qf[2];
    {
        const float* qrow = qb + ((size_t)bh*TT + t0 + w*16 + lq)*DD;
        #pragma unroll
        for (int ks=0; ks<2; ++ks){
            float4 v0 = *(const float4*)(qrow + ks*32 + lg*8);
            float4 v1 = *(const float4*)(qrow + ks*32 + lg*8 + 4);
            u16x8 qt;
            qt[0]=f2bf(v0.x); qt[1]=f2bf(v0.y); qt[2]=f2bf(v0.z); qt[3]=f2bf(v0.w);
            qt[4]=f2bf(v1.x); qt[5]=f2bf(v1.y); qt[6]=f2bf(v1.z); qt[7]=f2bf(v1.w);
            qf[ks] = __builtin_bit_cast(bf16x8_t, qt);
        }
    }

    float m_r = -1e30f, l_r = 0.f;
    f32x4 oacc[4] = {};

    const int tgq = t0 + w*16 + lq;

    for (int ch=ch_lo; ch<ch_hi; ++ch){
        __syncthreads();
        for (int i=tid; i<64*16; i+=256){
            int r = i>>4, dq4 = (i&15)*4;
            int s = ch*64 + r;
            float4 kv = make_float4(0,0,0,0), vv = make_float4(0,0,0,0);
            if (s < TT){
                kv = *(const float4*)(&kmb[(((size_t)bh)*TT + s)*DD + dq4]);
                kv.x*=kms; kv.y*=kms; kv.z*=kms; kv.w*=kms;
                vv = *(const float4*)(&vmb[(((size_t)bh)*TT + s)*DD + dq4]);
            } else if (s < TT+48){
                kv = *(const float4*)(&kd[((size_t)(s-TT)*HH + h)*DD + dq4]);
                kv.x*=kds; kv.y*=kds; kv.z*=kds; kv.w*=kds;
                vv = *(const float4*)(&vd[((size_t)(s-TT)*HH + h)*DD + dq4]);
            } else if (s < TT+96){
                kv = *(const float4*)(&kr[((size_t)(s-TT-48)*HH + h)*DD + dq4]);
                kv.x*=krs; kv.y*=krs; kv.z*=krs; kv.w*=krs;
                vv = *(const float4*)(&vr[((size_t)(s-TT-48)*HH + h)*DD + dq4]);
            } else if (s < NS){
                kv = *(const float4*)(&ktb[(((size_t)bh)*MM + (s-TT-96))*DD + dq4]);
                kv.x*=kts; kv.y*=kts; kv.z*=kts; kv.w*=kts;
                vv = *(const float4*)(&vtb[(((size_t)bh)*MM + (s-TT-96))*DD + dq4]);
            }
            *(uint2*)&Ks[r][dq4] = pack4bf(kv.x, kv.y, kv.z, kv.w);
            int swcol = r ^ (((i&15)&7)<<3);
            Vt[dq4+0][swcol] = f2bf(vv.x);
            Vt[dq4+1][swcol] = f2bf(vv.y);
            Vt[dq4+2][swcol] = f2bf(vv.z);
            Vt[dq4+3][swcol] = f2bf(vv.w);
        }
        if (tid < 64){
            int s = ch*64 + tid;
            float a;
            if (s < TT)            a = (smask[b*TT + s] == 0) ? -1e9f : 0.f;
            else if (s < TT+96)    a = 0.f;
            else if (s < NS)       a = text_on ? 0.f : -1e9f;
            else                   a = -1e30f;
            madd[tid] = a;
        }
        __syncthreads();

        f32x4 sacc[4] = {};
        #pragma unroll
        for (int sl=0; sl<4; ++sl){
            #pragma unroll
            for (int ks=0; ks<2; ++ks){
                bf16x8_t kf = *reinterpret_cast<const bf16x8_t*>(&Ks[sl*16 + lq][ks*32 + lg*8]);
                sacc[sl] = __builtin_amdgcn_mfma_f32_16x16x32_bf16(kf, qf[ks], sacc[sl], 0, 0, 0);
            }
        }
        float sv[4][4];
        float pmax = -1e30f;
        #pragma unroll
        for (int sl=0; sl<4; ++sl){
            #pragma unroll
            for (int r=0; r<4; ++r){
                int s_loc = sl*16 + lg*4 + r;
                float a = madd[s_loc];
                if (ch < 8){ float dt = (float)(tgq - (ch*64 + s_loc)); a -= dt*dt*inv2s; }
                float v = sacc[sl][r] + a;
                sv[sl][r] = v;
                pmax = fmaxf(pmax, v);
            }
        }
        pmax = fmaxf(pmax, __shfl_xor(pmax, 16));
        pmax = fmaxf(pmax, __shfl_xor(pmax, 32));
        float mn  = fmaxf(m_r, pmax);
        float scl = __expf(m_r - mn);
        m_r = mn;
        float psum = 0.f;
        #pragma unroll
        for (int sl=0; sl<4; ++sl){
            #pragma unroll
            for (int r=0; r<4; ++r){
                float p = __expf(sv[sl][r] - mn);
                sv[sl][r] = p;
                psum += p;
            }
        }
        psum += __shfl_xor(psum, 16);
        psum += __shfl_xor(psum, 32);
        l_r = l_r*scl + psum;
        #pragma unroll
        for (int sl=0; sl<4; ++sl)
            *(uint2*)&Pl[w][lq][sl*16 + lg*4] = pack4bf(sv[sl][0], sv[sl][1], sv[sl][2], sv[sl][3]);

        #pragma unroll
        for (int r=0; r<4; ++r){
            float so = __shfl(scl, lg*4 + r);
            #pragma unroll
            for (int ds_=0; ds_<4; ++ds_) oacc[ds_][r] *= so;
        }
        #pragma unroll
        for (int ds_=0; ds_<4; ++ds_){
            int dcol = ds_*16 + lq;
            int swz = (((dcol>>2)&7)<<3);
            #pragma unroll
            for (int ks=0; ks<2; ++ks){
                bf16x8_t pf = *reinterpret_cast<const bf16x8_t*>(&Pl[w][lq][ks*32 + lg*8]);
                bf16x8_t vf = *reinterpret_cast<const bf16x8_t*>(&Vt[dcol][(ks*32 + lg*8) ^ swz]);
                oacc[ds_] = __builtin_amdgcn_mfma_f32_16x16x32_bf16(pf, vf, oacc[ds_], 0, 0, 0);
            }
        }
    }
    #pragma unroll
    for (int r=0; r<4; ++r){
        int t = t0 + w*16 + lg*4 + r;
        size_t off = (size_t)split*NROWS + (size_t)bh*TT + t;
        #pragma unroll
        for (int ds_=0; ds_<4; ++ds_)
            po[off*64 + ds_*16 + lq] = oacc[ds_][r];
    }
    if (lg == 0){
        size_t off = (size_t)split*NROWS + (size_t)bh*TT + (t0 + w*16 + lq);
        pm[off] = m_r;
        pl[off] = l_r;
    }
}

// ---------------- merge the 2 s-splits ----------------
__global__ __launch_bounds__(256) void attn_combine_kernel(
    const float* __restrict__ po, const float* __restrict__ pm, const float* __restrict__ pl,
    float* __restrict__ outb)
{
    int tid = threadIdx.x, bid = blockIdx.x;
    int ttile = bid & 15, bh = bid >> 4;
    int b = bh / HH, h = bh % HH;
    int tp = tid >> 4, sq = tid & 15;
    #pragma unroll
    for (int i=0;i<2;++i){
        int t = ttile*32 + tp*2 + i;
        size_t rowid = (size_t)bh*TT + t;
        float m0 = pm[rowid], m1 = pm[NROWS + rowid];
        float l0 = pl[rowid], l1 = pl[NROWS + rowid];
        float m = fmaxf(m0, m1);
        float s0 = __expf(m0 - m), s1 = __expf(m1 - m);
        float inv = 1.0f / (l0*s0 + l1*s1);
        float4 o0 = *(const float4*)(po + rowid*64 + sq*4);
        float4 o1 = *(const float4*)(po + ((size_t)NROWS + rowid)*64 + sq*4);
        float4 o;
        o.x = (o0.x*s0 + o1.x*s1)*inv;
        o.y = (o0.y*s0 + o1.y*s1)*inv;
        o.z = (o0.z*s0 + o1.z*s1)*inv;
        o.w = (o0.w*s0 + o1.w*s1)*inv;
        *(float4*)(&outb[((size_t)(b*TT + t))*LATD + h*64 + sq*4]) = o;
    }
}

// ---------------- bf16 MFMA GEMM: C = act(A) @ W + bias (+res). Wt pre-transposed bf16 [N][K]
template<bool ACT_SILU>
__global__ __launch_bounds__(256) void gemm_mfma_kernel(
    const float* __restrict__ A, const unsigned short* __restrict__ Wt,
    const float* __restrict__ bias, const float* __restrict__ res,
    float* __restrict__ C, int Mr, int Nr, int Kr)
{
    __shared__ __align__(16) unsigned short As[32][40];   // [m][k] bf16
    __shared__ __align__(16) unsigned short Bs[64][40];   // [n][k] bf16
    int tid = threadIdx.x;
    int row0 = blockIdx.x*32, col0 = blockIdx.y*64;
    int wave = tid >> 6, lane = tid & 63;
    int lr = lane & 15, lk = lane >> 4;

    f32x4 acc[2] = {};

    for (int k0 = 0; k0 < Kr; k0 += 32){
        __syncthreads();
        // stage A (fp32->bf16 packed uint2)
        {
            int r = tid >> 3, kq = tid & 7;
            float4 v = *(const float4*)(A + (size_t)(row0 + r)*Kr + k0 + kq*4);
            if (ACT_SILU){ v.x=siluf(v.x); v.y=siluf(v.y); v.z=siluf(v.z); v.w=siluf(v.w); }
            *(uint2*)&As[r][kq*4] = pack4bf(v.x, v.y, v.z, v.w);
        }
        // stage W rows (already bf16 [n][k]) — pure uint4 copies
        {
            int n = tid >> 2, oq = tid & 3;
            *(uint4*)&Bs[n][oq*8] = *(const uint4*)(Wt + (size_t)(col0+n)*Kr + k0 + oq*8);
        }
        __syncthreads();
        bf16x8_t a0 = *reinterpret_cast<const bf16x8_t*>(&As[lr][lk*8]);
        bf16x8_t a1 = *reinterpret_cast<const bf16x8_t*>(&As[16 + lr][lk*8]);
        bf16x8_t bfr = *reinterpret_cast<const bf16x8_t*>(&Bs[wave*16 + lr][lk*8]);
        acc[0] = __builtin_amdgcn_mfma_f32_16x16x32_bf16(a0, bfr, acc[0], 0, 0, 0);
        acc[1] = __builtin_amdgcn_mfma_f32_16x16x32_bf16(a1, bfr, acc[1], 0, 0, 0);
    }
    int gc = col0 + wave*16 + lr;
    float bv = bias[gc];
    #pragma unroll
    for (int m=0;m<2;++m){
        #pragma unroll
        for (int r=0;r<4;++r){
            int gr = row0 + m*16 + lk*4 + r;
            float v = acc[m][r] + bv;
            size_t off = (size_t)gr*Nr + gc;
            if (res) v += res[off];
            C[off] = v;
        }
    }
}

// ---------------- modulated LN + silu ----------------
__global__ __launch_bounds__(256) void lnmod_kernel(
    const float* __restrict__ in, const float* __restrict__ g, const float* __restrict__ bb,
    const float* __restrict__ eo, float* __restrict__ out)
{
    int row = blockIdx.x, tid = threadIdx.x;
    __shared__ float xsr[LATD];
    __shared__ float red[256];
    const float* rp = in + (size_t)row*LATD;
    float s = 0.f;
    for (int i=tid;i<LATD;i+=256){ float v = rp[i]; xsr[i]=v; s+=v; }
    red[tid]=s; __syncthreads();
    for (int k=128;k>0;k>>=1){ if (tid<k) red[tid]+=red[tid+k]; __syncthreads(); }
    float mean = red[0]*(1.0f/LATD);
    __syncthreads();
    float vs=0.f;
    for (int i=tid;i<LATD;i+=256){ float d=xsr[i]-mean; vs+=d*d; }
    red[tid]=vs; __syncthreads();
    for (int k=128;k>0;k>>=1){ if (tid<k) red[tid]+=red[tid+k]; __syncthreads(); }
    float rstd = rsqrtf(red[0]*(1.0f/LATD)+1e-5f);
    const float* ep = eo + (size_t)row*(2*LATD);
    float* op = out + (size_t)row*LATD;
    for (int i=tid;i<LATD;i+=256){
        float v = (xsr[i]-mean)*rstd*g[i] + bb[i];
        v = v*(1.0f + ep[i]) + ep[LATD+i];
        op[i] = siluf(v);
    }
}

extern "C" void kernel_launch(void* const* d_in, const int* in_sizes, int n_in,
                              void* d_out, int out_size, void* d_ws, size_t ws_size,
                              hipStream_t stream)
{
    (void)in_sizes; (void)n_in; (void)out_size; (void)ws_size;
    const float* x     = (const float*)d_in[0];
    const float* emb   = (const float*)d_in[1];
    const int*   smask = (const int*)d_in[2];
    const float* tcond = (const float*)d_in[5];
    const float* two   = (const float*)d_in[6];
    const float* ng    = (const float*)d_in[7];
    const float* nb    = (const float*)d_in[8];
    const float* memb  = (const float*)d_in[9];
    const float* m_wg  = (const float*)d_in[10];
    const float* m_w1  = (const float*)d_in[11];
    const float* m_b1  = (const float*)d_in[12];
    const float* m_w2  = (const float*)d_in[13];
    const float* m_b2  = (const float*)d_in[14];
    const float* m_pw  = (const float*)d_in[15];
    const float* m_pb  = (const float*)d_in[16];
    const float* kms   = (const float*)d_in[17];
    const float* sigma = (const float*)d_in[18];
    const float* kdat  = (const float*)d_in[19];
    const float* kds   = (const float*)d_in[20];
    const float* vdat  = (const float*)d_in[21];
    const float* krot  = (const float*)d_in[22];
    const float* krs   = (const float*)d_in[23];
    const float* vrot  = (const float*)d_in[24];
    const float* ntg   = (const float*)d_in[25];
    const float* ntb   = (const float*)d_in[26];
    const float* c_wg  = (const float*)d_in[27];
    const float* c_w1  = (const float*)d_in[28];
    const float* c_b1  = (const float*)d_in[29];
    const float* c_w2  = (const float*)d_in[30];
    const float* c_b2  = (const float*)d_in[31];
    const float* c_pw  = (const float*)d_in[32];
    const float* c_pb  = (const float*)d_in[33];
    const float* kts   = (const float*)d_in[34];
    const float* st_ew = (const float*)d_in[35];
    const float* st_eb = (const float*)d_in[36];
    const float* st_ng = (const float*)d_in[37];
    const float* st_nb = (const float*)d_in[38];
    const float* st_ow = (const float*)d_in[39];
    const float* st_ob = (const float*)d_in[40];

    float* ws = (float*)d_ws;
    float* xh   = ws;                    // 1310720
    float* qB   = xh  + 1310720;
    float* kmB  = qB  + 1310720;
    float* vmB  = kmB + 1310720;
    float* ctB  = vmB + 1310720;         // 197120
    float* ktB  = ctB + 197120;
    float* vtB  = ktB + 197120;
    float* aout = vtB + 197120;          // 1310720
    float* eoB  = aout + 1310720;        // 2621440
    float* shB  = eoB + 2621440;         // 1310720

    // pre-transposed bf16 weights (persist whole launch)
    unsigned short* w1Tm = (unsigned short*)(shB + 1310720);
    unsigned short* w2Tm = w1Tm + EE*FFND*DD;   // 131072 each
    unsigned short* w1Tt = w2Tm + EE*FFND*DD;
    unsigned short* w2Tt = w1Tt + EE*FFND*DD;
    unsigned short* stewT = w2Tt + EE*FFND*DD;  // 512*1280 = 655360
    unsigned short* stowT = stewT + 512*1280;   // 640*640  = 409600

    float* yslotM = eoB;
    float* yslotT = shB;
    float* wAm   = aout;
    float* wAt   = wAm + NTOK_M*2;
    int*   cntA  = (int*)(wAt + NTOK_T*2);
    int*   listM = cntA + 16;
    int*   listT = listM + EE*NTOK_M;
    float* poB = eoB;
    float* pmB = ctB;
    float* plB = ctB + 2*NROWS;

    // 0. weight prep (transpose + bf16)
    transpose_bf16_kernel<<<dim3(1,4,EE), 256, 0, stream>>>(m_w1, w1Tm, 64, 256);
    transpose_bf16_kernel<<<dim3(4,1,EE), 256, 0, stream>>>(m_w2, w2Tm, 256, 64);
    transpose_bf16_kernel<<<dim3(1,4,EE), 256, 0, stream>>>(c_w1, w1Tt, 64, 256);
    transpose_bf16_kernel<<<dim3(4,1,EE), 256, 0, stream>>>(c_w2, w2Tt, 256, 64);
    transpose_bf16_kernel<<<dim3(8,20,1), 256, 0, stream>>>(st_ew, stewT, 512, 1280);
    transpose_bf16_kernel<<<dim3(10,10,1), 256, 0, stream>>>(st_ow, stowT, 640, 640);

    ln_kernel<<<BB*TT, 256, 0, stream>>>(x, ng, nb, memb, xh, TT);
    ln_kernel<<<BB*MM, 256, 0, stream>>>(two, ntg, ntb, nullptr, ctB, MM);
    zero_counts_kernel<<<1, 64, 0, stream>>>(cntA);
    route_kernel<<<(NTOK_M+255)/256, 256, 0, stream>>>(xh, m_wg, NTOK_M, cntA, listM, wAm);
    route_kernel<<<(NTOK_T+255)/256, 256, 0, stream>>>(ctB, c_wg, NTOK_T, cntA+8, listT, wAt);
    moe_ffn_kernel<<<MAXB_M, 256, 0, stream>>>(
        xh, w1Tm, m_b1, w2Tm, m_b2, cntA, listM, wAm, NTOK_M, yslotM);
    moe_ffn_kernel<<<MAXB_T, 256, 0, stream>>>(
        ctB, w1Tt, c_b1, w2Tt, c_b2, cntA+8, listT, wAt, NTOK_T, yslotT);
    moe_proj_kernel<192><<<(NTOK_M+63)/64, 256, 0, stream>>>(
        yslotM, m_pw, m_pb, 5*DD, NTOK_M, TT, qB, kmB, vmB);
    moe_proj_kernel<128><<<(NTOK_T+63)/64, 256, 0, stream>>>(
        yslotT, c_pw, c_pb, 2*DD, NTOK_T, MM, ktB, vtB, nullptr);
    {
        dim3 ga(BB*HH*8, 2);
        attn_kernel<<<ga, 256, 0, stream>>>(
            qB, kmB, vmB, ktB, vtB, kdat, vdat, krot, vrot, smask, tcond,
            kms, kds, krs, kts, sigma, poB, pmB, plB);
        attn_combine_kernel<<<BB*HH*16, 256, 0, stream>>>(poB, pmB, plB, aout);
    }
    {
        dim3 g1(2048/32, 1280/64);
        gemm_mfma_kernel<true><<<g1, 256, 0, stream>>>(emb, stewT, st_eb, nullptr, eoB, 2048, 1280, 512);
    }
    lnmod_kernel<<<BB*TT, 256, 0, stream>>>(aout, st_ng, st_nb, eoB, shB);
    {
        dim3 g2(2048/32, 640/64);
        gemm_mfma_kernel<false><<<g2, 256, 0, stream>>>(shB, stowT, st_ob, x, (float*)d_out, 2048, 640, 640);
    }
}

// Round 8
// 183.551 us; speedup vs baseline: 6.5013x; 1.2670x over previous
//
#include <hip/hip_runtime.h>
#include <math.h>

#define BB 4
#define TT 512
#define MM 77
#define HH 10
#define DD 64
#define LATD 640
#define EE 8
#define FFND 256
#define NS 685     // 512 + 48 + 48 + 77
#define NCH 11     // ceil(685/64)
#define NROWS 20480 // B*H*T

#define NTOK_M (BB*TT*HH)   // 20480
#define NTOK_T (BB*MM*HH)   // 3080
#define MAXB_M 647
#define MAXB_T 103

typedef float f32x4 __attribute__((ext_vector_type(4)));
typedef __bf16 bf16x8_t __attribute__((ext_vector_type(8)));
typedef unsigned short u16x8 __attribute__((ext_vector_type(8)));

__device__ __forceinline__ float geluf(float x){
    float u = 0.7978845608028654f*(x + 0.044715f*x*x*x);
    u = fminf(fmaxf(u, -15.f), 15.f);
    float e = __expf(2.f*u);
    return 0.5f*x*(1.f + (e-1.f)/(e+1.f));
}
__device__ __forceinline__ float siluf(float x){
    return x / (1.0f + __expf(-x));
}
__device__ __forceinline__ unsigned short f2bf(float f){
    unsigned int u = __float_as_uint(f);
    u += 0x7fff + ((u >> 16) & 1);
    return (unsigned short)(u >> 16);
}
__device__ __forceinline__ uint2 pack4bf(float a, float b, float c, float d){
    uint2 r;
    r.x = (unsigned)f2bf(a) | ((unsigned)f2bf(b)<<16);
    r.y = (unsigned)f2bf(c) | ((unsigned)f2bf(d)<<16);
    return r;
}

// ---------------- tiled transpose + bf16 convert: in f32 [z][R][C] -> out u16 [z][C][R] ----
__global__ __launch_bounds__(256) void transpose_bf16_kernel(
    const float* __restrict__ in, unsigned short* __restrict__ out, int R, int C)
{
    __shared__ float t[64][65];
    const int r0 = blockIdx.x*64, c0 = blockIdx.y*64;
    const size_t base = (size_t)blockIdx.z * R * C;
    const int tid = threadIdx.x;
    #pragma unroll
    for (int p=0; p<16; ++p){
        int i = tid + p*256;
        int r = i>>6, c = i&63;
        t[r][c] = in[base + (size_t)(r0+r)*C + c0 + c];
    }
    __syncthreads();
    #pragma unroll
    for (int p=0; p<16; ++p){
        int i = tid + p*256;
        int c = i>>6, r = i&63;
        out[base + (size_t)(c0+c)*R + r0 + r] = f2bf(t[r][c]);
    }
}

// ---------------- LayerNorm (rows of 640), optional additive emb (T,640) ----------------
__global__ __launch_bounds__(256) void ln_kernel(
    const float* __restrict__ in, const float* __restrict__ g, const float* __restrict__ bb,
    const float* __restrict__ addv, float* __restrict__ out, int seqLen)
{
    int row = blockIdx.x, tid = threadIdx.x;
    __shared__ float xsr[LATD];
    __shared__ float red[256];
    const float* rp = in + (size_t)row*LATD;
    float s = 0.f;
    for (int i=tid;i<LATD;i+=256){ float v = rp[i]; xsr[i]=v; s+=v; }
    red[tid]=s; __syncthreads();
    for (int k=128;k>0;k>>=1){ if (tid<k) red[tid]+=red[tid+k]; __syncthreads(); }
    float mean = red[0]*(1.0f/LATD);
    __syncthreads();
    float vs=0.f;
    for (int i=tid;i<LATD;i+=256){ float d=xsr[i]-mean; vs+=d*d; }
    red[tid]=vs; __syncthreads();
    for (int k=128;k>0;k>>=1){ if (tid<k) red[tid]+=red[tid+k]; __syncthreads(); }
    float rstd = rsqrtf(red[0]*(1.0f/LATD)+1e-5f);
    int t = row % seqLen;
    const float* ap = addv ? (addv + (size_t)t*LATD) : nullptr;
    float* op = out + (size_t)row*LATD;
    for (int i=tid;i<LATD;i+=256){
        float v = (xsr[i]-mean)*rstd*g[i] + bb[i];
        if (ap) v += ap[i];
        op[i] = v;
    }
}

// ---------------- MoE routing (block-aggregated atomics) ----------------
__global__ void zero_counts_kernel(int* __restrict__ c){
    if (threadIdx.x < 16) c[threadIdx.x] = 0;
}

__global__ __launch_bounds__(256) void route_kernel(
    const float* __restrict__ xin, const float* __restrict__ wg, int nTok,
    int* __restrict__ counts, int* __restrict__ list, float* __restrict__ wA)
{
    __shared__ int bcnt[EE];
    __shared__ int bbase[EE];
    const int tid = threadIdx.x;
    const int t = blockIdx.x*256 + tid;
    if (tid < EE) bcnt[tid] = 0;
    __syncthreads();

    int e0 = 0, e1 = 0, p0 = 0, p1 = 0;
    bool act = (t < nTok);
    if (act){
        float lg[EE];
        #pragma unroll
        for (int e=0;e<EE;e++) lg[e]=0.f;
        const float4* xp = (const float4*)(xin + (size_t)t*DD);
        #pragma unroll 4
        for (int dq=0; dq<16; ++dq){
            float4 xv = xp[dq];
            const float* w0 = wg + (dq*4+0)*EE;
            const float* w1 = wg + (dq*4+1)*EE;
            const float* w2 = wg + (dq*4+2)*EE;
            const float* w3 = wg + (dq*4+3)*EE;
            #pragma unroll
            for (int e=0;e<EE;e++)
                lg[e] += xv.x*w0[e] + xv.y*w1[e] + xv.z*w2[e] + xv.w*w3[e];
        }
        float mx = lg[0];
        #pragma unroll
        for (int e=1;e<EE;e++) mx = fmaxf(mx, lg[e]);
        float sum = 0.f;
        #pragma unroll
        for (int e=0;e<EE;e++){ lg[e] = __expf(lg[e]-mx); sum += lg[e]; }
        float inv = 1.0f/sum;
        #pragma unroll
        for (int e=0;e<EE;e++) lg[e] *= inv;
        float v0=lg[0];
        #pragma unroll
        for (int e=1;e<EE;e++){ if (lg[e] > v0){ v0 = lg[e]; e0 = e; } }
        float v1=-1e30f; e1 = (e0==0) ? 1 : 0;
        #pragma unroll
        for (int e=0;e<EE;e++){ if (e==e0) continue; if (lg[e] > v1){ v1 = lg[e]; e1 = e; } }
        wA[t*2+0]=v0; wA[t*2+1]=v1;
        p0 = atomicAdd(&bcnt[e0], 1);
        p1 = atomicAdd(&bcnt[e1], 1);
    }
    __syncthreads();
    if (tid < EE){
        bbase[tid] = (bcnt[tid] > 0) ? atomicAdd(&counts[tid], bcnt[tid]) : 0;
    }
    __syncthreads();
    if (act){
        list[(size_t)e0*nTok + bbase[e0] + p0] = t*2;
        list[(size_t)e1*nTok + bbase[e1] + p1] = t*2+1;
    }
}

// ---------------- grouped expert FFN (MFMA): block = (expert, 64-token tile), 4 waves ----
// w1T: bf16 [E][256 f][64 d]; w2T: bf16 [E][64 d][256 f]
__global__ __launch_bounds__(256) void moe_ffn_kernel(
    const float* __restrict__ xin,
    const unsigned short* __restrict__ w1T,
    const float* __restrict__ b1g,   // (E,256)
    const unsigned short* __restrict__ w2T,
    const float* __restrict__ b2g,   // (E,64)
    const int* __restrict__ counts, const int* __restrict__ list,
    const float* __restrict__ wA, int nTok,
    float* __restrict__ yslot)       // (nTok,2,64)
{
    __shared__ __align__(16) unsigned short xs[64][72];   // [tok][d]
    __shared__ __align__(16) unsigned short w1s[64][72];  // [f_loc][d]
    __shared__ __align__(16) unsigned short w2s[64][72];  // [d][f_loc]
    __shared__ __align__(16) unsigned short hs[64][72];   // [tok][f_loc]
    __shared__ int sCnt[EE];
    __shared__ int encs[64];
    __shared__ float wgts[64];
    const int tid = threadIdx.x;
    if (tid < EE) sCnt[tid] = counts[tid];
    __syncthreads();
    int e = -1, tile = 0;
    {
        int acc = 0, bid = blockIdx.x;
        #pragma unroll
        for (int i=0;i<EE;++i){
            int tc = (sCnt[i]+63)>>6;
            if (e < 0 && bid < acc + tc){ e = i; tile = bid - acc; }
            acc += tc;
        }
    }
    if (e < 0) return;
    const int cnt = sCnt[e];
    if (tid < 64){
        int idx = tile*64 + tid;
        int enc = (idx < cnt) ? list[(size_t)e*nTok + idx] : -1;
        encs[tid] = enc;
        wgts[tid] = (enc >= 0) ? wA[enc] : 0.f;
    }
    __syncthreads();
    for (int i=tid; i<64*16; i+=256){
        int r = i>>4, dq4 = (i&15)*4;
        int enc = encs[r];
        float4 xv = make_float4(0.f,0.f,0.f,0.f);
        if (enc >= 0) xv = *(const float4*)(xin + (size_t)(enc>>1)*DD + dq4);
        *(uint2*)&xs[r][dq4] = pack4bf(xv.x, xv.y, xv.z, xv.w);
    }

    const int w    = tid >> 6;
    const int lane = tid & 63;
    const int lq   = lane & 15;
    const int lg   = lane >> 4;

    const unsigned short* w1e = w1T + (size_t)e*FFND*DD;
    const unsigned short* w2e = w2T + (size_t)e*DD*FFND;

    f32x4 acc2[4] = {};

    for (int fc=0; fc<4; ++fc){
        __syncthreads();
        for (int i=tid; i<512; i+=256){
            int r = i>>3, jq = i&7;
            *(uint4*)&w1s[r][jq*8] = *(const uint4*)(w1e + (size_t)(fc*64+r)*DD + jq*8);
            *(uint4*)&w2s[r][jq*8] = *(const uint4*)(w2e + (size_t)r*FFND + fc*64 + jq*8);
        }
        __syncthreads();
        f32x4 acc1[4] = {};
        #pragma unroll
        for (int fb=0; fb<4; ++fb){
            #pragma unroll
            for (int ks=0; ks<2; ++ks){
                bf16x8_t xf = *reinterpret_cast<const bf16x8_t*>(&xs[w*16+lq][ks*32+lg*8]);
                bf16x8_t wf = *reinterpret_cast<const bf16x8_t*>(&w1s[fb*16+lq][ks*32+lg*8]);
                acc1[fb] = __builtin_amdgcn_mfma_f32_16x16x32_bf16(xf, wf, acc1[fb], 0, 0, 0);
            }
        }
        #pragma unroll
        for (int fb=0; fb<4; ++fb){
            float b1v = b1g[e*FFND + fc*64 + fb*16 + lq];
            #pragma unroll
            for (int r=0; r<4; ++r)
                hs[w*16 + lg*4 + r][fb*16 + lq] = f2bf(geluf(acc1[fb][r] + b1v));
        }
        #pragma unroll
        for (int db=0; db<4; ++db){
            #pragma unroll
            for (int ks=0; ks<2; ++ks){
                bf16x8_t hf  = *reinterpret_cast<const bf16x8_t*>(&hs[w*16+lq][ks*32+lg*8]);
                bf16x8_t w2f = *reinterpret_cast<const bf16x8_t*>(&w2s[db*16+lq][ks*32+lg*8]);
                acc2[db] = __builtin_amdgcn_mfma_f32_16x16x32_bf16(hf, w2f, acc2[db], 0, 0, 0);
            }
        }
    }
    #pragma unroll
    for (int r=0; r<4; ++r){
        int tok = w*16 + lg*4 + r;
        int enc = encs[tok];
        if (enc >= 0){
            float gw = wgts[tok];
            #pragma unroll
            for (int db=0; db<4; ++db){
                int d = db*16 + lq;
                yslot[(size_t)enc*DD + d] = gw*(acc2[db][r] + b2g[e*DD + d]);
            }
        }
    }
}

// ---------------- combine slots + gelu + MFMA projection (token-major output) ----------------
// pwT: bf16 [>=NPROJ][64]. outX buffers are token-major: out[tok*64 + jd].
template<int NPROJ>
__global__ __launch_bounds__(256) void moe_proj_mfma_kernel(
    const float* __restrict__ yslot, const unsigned short* __restrict__ pwT,
    const float* __restrict__ pbg, int nTok,
    float* __restrict__ out0, float* __restrict__ out1, float* __restrict__ out2)
{
    __shared__ __align__(16) unsigned short gs[64][72];
    const int tid = threadIdx.x;
    const int base = blockIdx.x*64;
    for (int i=tid; i<64*16; i+=256){
        int r = i>>4, dq4 = (i&15)*4;
        int tok = base + r;
        float4 g4 = make_float4(0.f,0.f,0.f,0.f);
        if (tok < nTok){
            float4 a = *(const float4*)(yslot + (size_t)tok*128 + dq4);
            float4 b = *(const float4*)(yslot + (size_t)tok*128 + 64 + dq4);
            g4.x = geluf(a.x+b.x); g4.y = geluf(a.y+b.y);
            g4.z = geluf(a.z+b.z); g4.w = geluf(a.w+b.w);
        }
        *(uint2*)&gs[r][dq4] = pack4bf(g4.x, g4.y, g4.z, g4.w);
    }
    __syncthreads();

    const int w    = tid >> 6;
    const int lane = tid & 63;
    const int lq   = lane & 15;
    const int lg   = lane >> 4;
    constexpr int NC = NPROJ/64;        // col-frags per wave (3 or 2)
    const int colbase = w*16*NC;

    // B fragments straight from global (L2-resident weights)
    bf16x8_t wf[NC][2];
    #pragma unroll
    for (int cb=0; cb<NC; ++cb)
        #pragma unroll
        for (int ks=0; ks<2; ++ks)
            wf[cb][ks] = *reinterpret_cast<const bf16x8_t*>(
                pwT + (size_t)(colbase + cb*16 + lq)*DD + ks*32 + lg*8);

    f32x4 acc[4][NC] = {};
    #pragma unroll
    for (int m=0; m<4; ++m){
        #pragma unroll
        for (int ks=0; ks<2; ++ks){
            bf16x8_t af = *reinterpret_cast<const bf16x8_t*>(&gs[m*16+lq][ks*32+lg*8]);
            #pragma unroll
            for (int cb=0; cb<NC; ++cb)
                acc[m][cb] = __builtin_amdgcn_mfma_f32_16x16x32_bf16(af, wf[cb][ks], acc[m][cb], 0, 0, 0);
        }
    }
    #pragma unroll
    for (int m=0; m<4; ++m){
        #pragma unroll
        for (int r=0; r<4; ++r){
            int tok = base + m*16 + lg*4 + r;
            if (tok >= nTok) continue;
            #pragma unroll
            for (int cb=0; cb<NC; ++cb){
                int j = colbase + cb*16 + lq;
                float v = acc[m][cb][r] + pbg[j];
                int bufi = j >> 6, jd = j & 63;
                float* dst = (bufi==0) ? out0 : (bufi==1) ? out1 : out2;
                dst[(size_t)tok*DD + jd] = v;
            }
        }
    }
}

// ---------------- MFMA flash attention (split-s): block = (b,h,64-row t-tile), 4 waves ----
// Q/K/V motion buffers are token-major (B,T,H,64); text buffers (B,M,H,64).
__global__ __launch_bounds__(256) void attn_kernel(
    const float* __restrict__ qb,
    const float* __restrict__ kmb,
    const float* __restrict__ vmb,
    const float* __restrict__ ktb,
    const float* __restrict__ vtb,
    const float* __restrict__ kd,   // (NDS,48,H,64) -> [0]
    const float* __restrict__ vd,
    const float* __restrict__ kr,   // (48,H,64)
    const float* __restrict__ vr,
    const int*   __restrict__ smask, // (B,T)
    const float* __restrict__ tcond, // (B,1)
    const float* __restrict__ kms_p, const float* __restrict__ kds_p,
    const float* __restrict__ krs_p, const float* __restrict__ kts_p,
    const float* __restrict__ sigma_p,
    float* __restrict__ po,          // (2, NROWS, 64)
    float* __restrict__ pm,          // (2, NROWS)
    float* __restrict__ pl)          // (2, NROWS)
{
    __shared__ __align__(16) unsigned short Ks[64][72];
    __shared__ __align__(16) unsigned short Vt[64][72];
    __shared__ __align__(16) unsigned short Pl[4][16][72];
    __shared__ float madd[64];

    const int tid  = threadIdx.x;
    const int w    = tid >> 6;
    const int lane = tid & 63;
    const int lq   = lane & 15;
    const int lg   = lane >> 4;

    const int bid   = blockIdx.x;
    const int split = blockIdx.y;
    const int ch_lo = split ? 6 : 0;
    const int ch_hi = split ? NCH : 6;
    const int ttile = bid & 7;
    const int bh    = bid >> 3;
    const int b = bh / HH, h = bh % HH;
    const int t0 = ttile * 64;

    const float sc = 0.125f;
    const float kms = kms_p[0]*sc, kds = kds_p[0]*sc, krs = krs_p[0]*sc, kts = kts_p[0]*sc;
    const float sg = sigma_p[0];
    const float inv2s = 1.0f/(2.0f*sg*sg);
    const bool text_on = tcond[b] > 0.f;

    bf16x8_t qf[2];
    {
        const float* qrow = qb + ((size_t)(b*TT + t0 + w*16 + lq)*HH + h)*DD;
        #pragma unroll
        for (int ks=0; ks<2; ++ks){
            float4 v0 = *(const float4*)(qrow + ks*32 + lg*8);
            float4 v1 = *(const float4*)(qrow + ks*32 + lg*8 + 4);
            u16x8 qt;
            qt[0]=f2bf(v0.x); qt[1]=f2bf(v0.y); qt[2]=f2bf(v0.z); qt[3]=f2bf(v0.w);
            qt[4]=f2bf(v1.x); qt[5]=f2bf(v1.y); qt[6]=f2bf(v1.z); qt[7]=f2bf(v1.w);
            qf[ks] = __builtin_bit_cast(bf16x8_t, qt);
        }
    }

    float m_r = -1e30f, l_r = 0.f;
    f32x4 oacc[4] = {};

    const int tgq = t0 + w*16 + lq;

    for (int ch=ch_lo; ch<ch_hi; ++ch){
        __syncthreads();
        for (int i=tid; i<64*16; i+=256){
            int r = i>>4, dq4 = (i&15)*4;
            int s = ch*64 + r;
            float4 kv = make_float4(0,0,0,0), vv = make_float4(0,0,0,0);
            if (s < TT){
                size_t o = ((size_t)(b*TT + s)*HH + h)*DD + dq4;
                kv = *(const float4*)(&kmb[o]);
                kv.x*=kms; kv.y*=kms; kv.z*=kms; kv.w*=kms;
                vv = *(const float4*)(&vmb[o]);
            } else if (s < TT+48){
                kv = *(const float4*)(&kd[((size_t)(s-TT)*HH + h)*DD + dq4]);
                kv.x*=kds; kv.y*=kds; kv.z*=kds; kv.w*=kds;
                vv = *(const float4*)(&vd[((size_t)(s-TT)*HH + h)*DD + dq4]);
            } else if (s < TT+96){
                kv = *(const float4*)(&kr[((size_t)(s-TT-48)*HH + h)*DD + dq4]);
                kv.x*=krs; kv.y*=krs; kv.z*=krs; kv.w*=krs;
                vv = *(const float4*)(&vr[((size_t)(s-TT-48)*HH + h)*DD + dq4]);
            } else if (s < NS){
                size_t o = ((size_t)(b*MM + (s-TT-96))*HH + h)*DD + dq4;
                kv = *(const float4*)(&ktb[o]);
                kv.x*=kts; kv.y*=kts; kv.z*=kts; kv.w*=kts;
                vv = *(const float4*)(&vtb[o]);
            }
            *(uint2*)&Ks[r][dq4] = pack4bf(kv.x, kv.y, kv.z, kv.w);
            int swcol = r ^ (((i&15)&7)<<3);
            Vt[dq4+0][swcol] = f2bf(vv.x);
            Vt[dq4+1][swcol] = f2bf(vv.y);
            Vt[dq4+2][swcol] = f2bf(vv.z);
            Vt[dq4+3][swcol] = f2bf(vv.w);
        }
        if (tid < 64){
            int s = ch*64 + tid;
            float a;
            if (s < TT)            a = (smask[b*TT + s] == 0) ? -1e9f : 0.f;
            else if (s < TT+96)    a = 0.f;
            else if (s < NS)       a = text_on ? 0.f : -1e9f;
            else                   a = -1e30f;
            madd[tid] = a;
        }
        __syncthreads();

        f32x4 sacc[4] = {};
        #pragma unroll
        for (int sl=0; sl<4; ++sl){
            #pragma unroll
            for (int ks=0; ks<2; ++ks){
                bf16x8_t kf = *reinterpret_cast<const bf16x8_t*>(&Ks[sl*16 + lq][ks*32 + lg*8]);
                sacc[sl] = __builtin_amdgcn_mfma_f32_16x16x32_bf16(kf, qf[ks], sacc[sl], 0, 0, 0);
            }
        }
        float sv[4][4];
        float pmax = -1e30f;
        #pragma unroll
        for (int sl=0; sl<4; ++sl){
            #pragma unroll
            for (int r=0; r<4; ++r){
                int s_loc = sl*16 + lg*4 + r;
                float a = madd[s_loc];
                if (ch < 8){ float dt = (float)(tgq - (ch*64 + s_loc)); a -= dt*dt*inv2s; }
                float v = sacc[sl][r] + a;
                sv[sl][r] = v;
                pmax = fmaxf(pmax, v);
            }
        }
        pmax = fmaxf(pmax, __shfl_xor(pmax, 16));
        pmax = fmaxf(pmax, __shfl_xor(pmax, 32));
        float mn  = fmaxf(m_r, pmax);
        float scl = __expf(m_r - mn);
        m_r = mn;
        float psum = 0.f;
        #pragma unroll
        for (int sl=0; sl<4; ++sl){
            #pragma unroll
            for (int r=0; r<4; ++r){
                float p = __expf(sv[sl][r] - mn);
                sv[sl][r] = p;
                psum += p;
            }
        }
        psum += __shfl_xor(psum, 16);
        psum += __shfl_xor(psum, 32);
        l_r = l_r*scl + psum;
        #pragma unroll
        for (int sl=0; sl<4; ++sl)
            *(uint2*)&Pl[w][lq][sl*16 + lg*4] = pack4bf(sv[sl][0], sv[sl][1], sv[sl][2], sv[sl][3]);

        #pragma unroll
        for (int r=0; r<4; ++r){
            float so = __shfl(scl, lg*4 + r);
            #pragma unroll
            for (int ds_=0; ds_<4; ++ds_) oacc[ds_][r] *= so;
        }
        #pragma unroll
        for (int ds_=0; ds_<4; ++ds_){
            int dcol = ds_*16 + lq;
            int swz = (((dcol>>2)&7)<<3);
            #pragma unroll
            for (int ks=0; ks<2; ++ks){
                bf16x8_t pf = *reinterpret_cast<const bf16x8_t*>(&Pl[w][lq][ks*32 + lg*8]);
                bf16x8_t vf = *reinterpret_cast<const bf16x8_t*>(&Vt[dcol][(ks*32 + lg*8) ^ swz]);
                oacc[ds_] = __builtin_amdgcn_mfma_f32_16x16x32_bf16(pf, vf, oacc[ds_], 0, 0, 0);
            }
        }
    }
    #pragma unroll
    for (int r=0; r<4; ++r){
        int t = t0 + w*16 + lg*4 + r;
        size_t off = (size_t)split*NROWS + (size_t)bh*TT + t;
        #pragma unroll
        for (int ds_=0; ds_<4; ++ds_)
            po[off*64 + ds_*16 + lq] = oacc[ds_][r];
    }
    if (lg == 0){
        size_t off = (size_t)split*NROWS + (size_t)bh*TT + (t0 + w*16 + lq);
        pm[off] = m_r;
        pl[off] = l_r;
    }
}

// ---------------- merge the 2 s-splits ----------------
__global__ __launch_bounds__(256) void attn_combine_kernel(
    const float* __restrict__ po, const float* __restrict__ pm, const float* __restrict__ pl,
    float* __restrict__ outb)
{
    int tid = threadIdx.x, bid = blockIdx.x;
    int ttile = bid & 15, bh = bid >> 4;
    int b = bh / HH, h = bh % HH;
    int tp = tid >> 4, sq = tid & 15;
    #pragma unroll
    for (int i=0;i<2;++i){
        int t = ttile*32 + tp*2 + i;
        size_t rowid = (size_t)bh*TT + t;
        float m0 = pm[rowid], m1 = pm[NROWS + rowid];
        float l0 = pl[rowid], l1 = pl[NROWS + rowid];
        float m = fmaxf(m0, m1);
        float s0 = __expf(m0 - m), s1 = __expf(m1 - m);
        float inv = 1.0f / (l0*s0 + l1*s1);
        float4 o0 = *(const float4*)(po + rowid*64 + sq*4);
        float4 o1 = *(const float4*)(po + ((size_t)NROWS + rowid)*64 + sq*4);
        float4 o;
        o.x = (o0.x*s0 + o1.x*s1)*inv;
        o.y = (o0.y*s0 + o1.y*s1)*inv;
        o.z = (o0.z*s0 + o1.z*s1)*inv;
        o.w = (o0.w*s0 + o1.w*s1)*inv;
        *(float4*)(&outb[((size_t)(b*TT + t))*LATD + h*64 + sq*4]) = o;
    }
}

// ---------------- bf16 MFMA GEMM: C = act(A) @ W + bias (+res). Wt pre-transposed bf16 [N][K]
template<bool ACT_SILU>
__global__ __launch_bounds__(256) void gemm_mfma_kernel(
    const float* __restrict__ A, const unsigned short* __restrict__ Wt,
    const float* __restrict__ bias, const float* __restrict__ res,
    float* __restrict__ C, int Mr, int Nr, int Kr)
{
    __shared__ __align__(16) unsigned short As[32][40];
    __shared__ __align__(16) unsigned short Bs[64][40];
    int tid = threadIdx.x;
    int row0 = blockIdx.x*32, col0 = blockIdx.y*64;
    int wave = tid >> 6, lane = tid & 63;
    int lr = lane & 15, lk = lane >> 4;

    f32x4 acc[2] = {};

    for (int k0 = 0; k0 < Kr; k0 += 32){
        __syncthreads();
        {
            int r = tid >> 3, kq = tid & 7;
            float4 v = *(const float4*)(A + (size_t)(row0 + r)*Kr + k0 + kq*4);
            if (ACT_SILU){ v.x=siluf(v.x); v.y=siluf(v.y); v.z=siluf(v.z); v.w=siluf(v.w); }
            *(uint2*)&As[r][kq*4] = pack4bf(v.x, v.y, v.z, v.w);
        }
        {
            int n = tid >> 2, oq = tid & 3;
            *(uint4*)&Bs[n][oq*8] = *(const uint4*)(Wt + (size_t)(col0+n)*Kr + k0 + oq*8);
        }
        __syncthreads();
        bf16x8_t a0 = *reinterpret_cast<const bf16x8_t*>(&As[lr][lk*8]);
        bf16x8_t a1 = *reinterpret_cast<const bf16x8_t*>(&As[16 + lr][lk*8]);
        bf16x8_t bfr = *reinterpret_cast<const bf16x8_t*>(&Bs[wave*16 + lr][lk*8]);
        acc[0] = __builtin_amdgcn_mfma_f32_16x16x32_bf16(a0, bfr, acc[0], 0, 0, 0);
        acc[1] = __builtin_amdgcn_mfma_f32_16x16x32_bf16(a1, bfr, acc[1], 0, 0, 0);
    }
    int gc = col0 + wave*16 + lr;
    float bv = bias[gc];
    #pragma unroll
    for (int m=0;m<2;++m){
        #pragma unroll
        for (int r=0;r<4;++r){
            int gr = row0 + m*16 + lk*4 + r;
            float v = acc[m][r] + bv;
            size_t off = (size_t)gr*Nr + gc;
            if (res) v += res[off];
            C[off] = v;
        }
    }
}

// ---------------- modulated LN + silu ----------------
__global__ __launch_bounds__(256) void lnmod_kernel(
    const float* __restrict__ in, const float* __restrict__ g, const float* __restrict__ bb,
    const float* __restrict__ eo, float* __restrict__ out)
{
    int row = blockIdx.x, tid = threadIdx.x;
    __shared__ float xsr[LATD];
    __shared__ float red[256];
    const float* rp = in + (size_t)row*LATD;
    float s = 0.f;
    for (int i=tid;i<LATD;i+=256){ float v = rp[i]; xsr[i]=v; s+=v; }
    red[tid]=s; __syncthreads();
    for (int k=128;k>0;k>>=1){ if (tid<k) red[tid]+=red[tid+k]; __syncthreads(); }
    float mean = red[0]*(1.0f/LATD);
    __syncthreads();
    float vs=0.f;
    for (int i=tid;i<LATD;i+=256){ float d=xsr[i]-mean; vs+=d*d; }
    red[tid]=vs; __syncthreads();
    for (int k=128;k>0;k>>=1){ if (tid<k) red[tid]+=red[tid+k]; __syncthreads(); }
    float rstd = rsqrtf(red[0]*(1.0f/LATD)+1e-5f);
    const float* ep = eo + (size_t)row*(2*LATD);
    float* op = out + (size_t)row*LATD;
    for (int i=tid;i<LATD;i+=256){
        float v = (xsr[i]-mean)*rstd*g[i] + bb[i];
        v = v*(1.0f + ep[i]) + ep[LATD+i];
        op[i] = siluf(v);
    }
}

extern "C" void kernel_launch(void* const* d_in, const int* in_sizes, int n_in,
                              void* d_out, int out_size, void* d_ws, size_t ws_size,
                              hipStream_t stream)
{
    (void)in_sizes; (void)n_in; (void)out_size; (void)ws_size;
    const float* x     = (const float*)d_in[0];
    const float* emb   = (const float*)d_in[1];
    const int*   smask = (const int*)d_in[2];
    const float* tcond = (const float*)d_in[5];
    const float* two   = (const float*)d_in[6];
    const float* ng    = (const float*)d_in[7];
    const float* nb    = (const float*)d_in[8];
    const float* memb  = (const float*)d_in[9];
    const float* m_wg  = (const float*)d_in[10];
    const float* m_w1  = (const float*)d_in[11];
    const float* m_b1  = (const float*)d_in[12];
    const float* m_w2  = (const float*)d_in[13];
    const float* m_b2  = (const float*)d_in[14];
    const float* m_pw  = (const float*)d_in[15];
    const float* m_pb  = (const float*)d_in[16];
    const float* kms   = (const float*)d_in[17];
    const float* sigma = (const float*)d_in[18];
    const float* kdat  = (const float*)d_in[19];
    const float* kds   = (const float*)d_in[20];
    const float* vdat  = (const float*)d_in[21];
    const float* krot  = (const float*)d_in[22];
    const float* krs   = (const float*)d_in[23];
    const float* vrot  = (const float*)d_in[24];
    const float* ntg   = (const float*)d_in[25];
    const float* ntb   = (const float*)d_in[26];
    const float* c_wg  = (const float*)d_in[27];
    const float* c_w1  = (const float*)d_in[28];
    const float* c_b1  = (const float*)d_in[29];
    const float* c_w2  = (const float*)d_in[30];
    const float* c_b2  = (const float*)d_in[31];
    const float* c_pw  = (const float*)d_in[32];
    const float* c_pb  = (const float*)d_in[33];
    const float* kts   = (const float*)d_in[34];
    const float* st_ew = (const float*)d_in[35];
    const float* st_eb = (const float*)d_in[36];
    const float* st_ng = (const float*)d_in[37];
    const float* st_nb = (const float*)d_in[38];
    const float* st_ow = (const float*)d_in[39];
    const float* st_ob = (const float*)d_in[40];

    float* ws = (float*)d_ws;
    float* xh   = ws;                    // 1310720
    float* qB   = xh  + 1310720;         // (B,T,H,64) token-major
    float* kmB  = qB  + 1310720;
    float* vmB  = kmB + 1310720;
    float* ctB  = vmB + 1310720;         // 197120
    float* ktB  = ctB + 197120;          // (B,M,H,64)
    float* vtB  = ktB + 197120;
    float* aout = vtB + 197120;          // 1310720
    float* eoB  = aout + 1310720;        // 2621440
    float* shB  = eoB + 2621440;         // 1310720

    // pre-transposed bf16 weights (persist whole launch)
    unsigned short* w1Tm = (unsigned short*)(shB + 1310720);
    unsigned short* w2Tm = w1Tm + EE*FFND*DD;   // 131072 each
    unsigned short* w1Tt = w2Tm + EE*FFND*DD;
    unsigned short* w2Tt = w1Tt + EE*FFND*DD;
    unsigned short* stewT = w2Tt + EE*FFND*DD;  // 512*1280
    unsigned short* stowT = stewT + 512*1280;   // 640*640
    unsigned short* mpwT  = stowT + 640*640;    // 320*64
    unsigned short* cpwT  = mpwT + 320*64;      // 128*64

    float* yslotM = eoB;
    float* yslotT = shB;
    float* wAm   = aout;
    float* wAt   = wAm + NTOK_M*2;
    int*   cntA  = (int*)(wAt + NTOK_T*2);
    int*   listM = cntA + 16;
    int*   listT = listM + EE*NTOK_M;
    float* poB = eoB;
    float* pmB = ctB;
    float* plB = ctB + 2*NROWS;

    // 0. weight prep (transpose + bf16)
    transpose_bf16_kernel<<<dim3(1,4,EE), 256, 0, stream>>>(m_w1, w1Tm, 64, 256);
    transpose_bf16_kernel<<<dim3(4,1,EE), 256, 0, stream>>>(m_w2, w2Tm, 256, 64);
    transpose_bf16_kernel<<<dim3(1,4,EE), 256, 0, stream>>>(c_w1, w1Tt, 64, 256);
    transpose_bf16_kernel<<<dim3(4,1,EE), 256, 0, stream>>>(c_w2, w2Tt, 256, 64);
    transpose_bf16_kernel<<<dim3(8,20,1), 256, 0, stream>>>(st_ew, stewT, 512, 1280);
    transpose_bf16_kernel<<<dim3(10,10,1), 256, 0, stream>>>(st_ow, stowT, 640, 640);
    transpose_bf16_kernel<<<dim3(1,5,1), 256, 0, stream>>>(m_pw, mpwT, 64, 320);
    transpose_bf16_kernel<<<dim3(1,2,1), 256, 0, stream>>>(c_pw, cpwT, 64, 128);

    ln_kernel<<<BB*TT, 256, 0, stream>>>(x, ng, nb, memb, xh, TT);
    ln_kernel<<<BB*MM, 256, 0, stream>>>(two, ntg, ntb, nullptr, ctB, MM);
    zero_counts_kernel<<<1, 64, 0, stream>>>(cntA);
    route_kernel<<<(NTOK_M+255)/256, 256, 0, stream>>>(xh, m_wg, NTOK_M, cntA, listM, wAm);
    route_kernel<<<(NTOK_T+255)/256, 256, 0, stream>>>(ctB, c_wg, NTOK_T, cntA+8, listT, wAt);
    moe_ffn_kernel<<<MAXB_M, 256, 0, stream>>>(
        xh, w1Tm, m_b1, w2Tm, m_b2, cntA, listM, wAm, NTOK_M, yslotM);
    moe_ffn_kernel<<<MAXB_T, 256, 0, stream>>>(
        ctB, w1Tt, c_b1, w2Tt, c_b2, cntA+8, listT, wAt, NTOK_T, yslotT);
    moe_proj_mfma_kernel<192><<<(NTOK_M+63)/64, 256, 0, stream>>>(
        yslotM, mpwT, m_pb, NTOK_M, qB, kmB, vmB);
    moe_proj_mfma_kernel<128><<<(NTOK_T+63)/64, 256, 0, stream>>>(
        yslotT, cpwT, c_pb, NTOK_T, ktB, vtB, nullptr);
    {
        dim3 ga(BB*HH*8, 2);
        attn_kernel<<<ga, 256, 0, stream>>>(
            qB, kmB, vmB, ktB, vtB, kdat, vdat, krot, vrot, smask, tcond,
            kms, kds, krs, kts, sigma, poB, pmB, plB);
        attn_combine_kernel<<<BB*HH*16, 256, 0, stream>>>(poB, pmB, plB, aout);
    }
    {
        dim3 g1(2048/32, 1280/64);
        gemm_mfma_kernel<true><<<g1, 256, 0, stream>>>(emb, stewT, st_eb, nullptr, eoB, 2048, 1280, 512);
    }
    lnmod_kernel<<<BB*TT, 256, 0, stream>>>(aout, st_ng, st_nb, eoB, shB);
    {
        dim3 g2(2048/32, 640/64);
        gemm_mfma_kernel<false><<<g2, 256, 0, stream>>>(shB, stowT, st_ob, x, (float*)d_out, 2048, 640, 640);
    }
}